// Round 13
// baseline (200.657 us; speedup 1.0000x reference)
//
#include <hip/hip_runtime.h>
#include <hip/hip_fp16.h>

#define NN 50000
#define NE 800000
#define DD 256
#define DE_DIM 16
#define HH 4
#define FF 32
#define HF 128
#define OUTD 32
#define SLOPE 0.2f
#define NB_SCAN ((NN + 255) / 256)   // 196

// MFMA proj tiling
#define BM 64
#define NCOL 272
#define APAD 264
#define BTPAD 40
#define TILE_S8 1088
// node_final MFMA tiling
#define NFB 64
#define FPAD 136

typedef short short8 __attribute__((ext_vector_type(8)));
typedef float f32x4 __attribute__((ext_vector_type(4)));
typedef unsigned short us4 __attribute__((ext_vector_type(4)));

// fp32 -> bf16 bits, round-to-nearest-even
__device__ __forceinline__ unsigned short bf16r(float x) {
  unsigned u = __float_as_uint(x);
  u += 0x7FFFu + ((u >> 16) & 1u);
  return (unsigned short)(u >> 16);
}
__device__ __forceinline__ float bfdec(unsigned short u) {
  return __uint_as_float(((unsigned)u) << 16);
}

// ---- Prep: bf16 weight panel, K-tile-major: Btt[kk][272 cols][32 k] ----
__global__ __launch_bounds__(256) void bt_prep_kernel(
    const float* __restrict__ Wsrc, const float* __restrict__ Wdst,
    const float* __restrict__ Wasrc, const float* __restrict__ Wadst,
    unsigned short* __restrict__ Btt)
{
  int c = blockIdx.x;     // 0..271
  int k = threadIdx.x;    // 0..255
  float v = 0.f;
  if (c < 128)      v = Wsrc[(size_t)k * HF + c];
  else if (c < 256) v = Wdst[(size_t)k * HF + (c - 128)];
  else if (c < 260) v = Wasrc[(size_t)k * HH + (c - 256)];
  else if (c < 264) v = Wadst[(size_t)k * HH + (c - 260)];
  int kk = k >> 5, k5 = k & 31;
  Btt[(size_t)kk * (NCOL * 32) + c * 32 + k5] = bf16r(v);
}

// ---- Prep: transposed bf16 W_agg [128][128] and W_apply [32][128] ----
__global__ __launch_bounds__(128) void wfin_prep_kernel(
    const float* __restrict__ W_agg, const float* __restrict__ W_apply,
    unsigned short* __restrict__ Wagg_t, unsigned short* __restrict__ Wapp_t)
{
  int c = blockIdx.x;     // 0..159
  int k = threadIdx.x;    // 0..127
  if (c < 128) Wagg_t[(size_t)c * HF + k] = bf16r(W_agg[(size_t)k * HF + c]);
  else         Wapp_t[(size_t)(c - 128) * HF + k] = bf16r(W_apply[(size_t)k * OUTD + (c - 128)]);
}

// ---- Kernel 1: MFMA proj; double-buffered staging ----
__global__ __launch_bounds__(512) void mfma_proj_kernel(
    const float* __restrict__ feat, const unsigned short* __restrict__ Btt,
    const float* __restrict__ bdst,
    unsigned short* __restrict__ fcs, unsigned short* __restrict__ fcd,
    float* __restrict__ asrc, float* __restrict__ adst)
{
  __shared__ unsigned short Albuf[BM * APAD];
  __shared__ unsigned short Btbuf[2][NCOL * BTPAD];
  const int tid  = threadIdx.x;
  const int wave = tid >> 6, lane = tid & 63;
  const int m0 = blockIdx.x * BM;

  for (int i = tid; i < BM * 64; i += 512) {
    int r = i >> 6, c4 = i & 63;
    int gr = m0 + r; if (gr >= NN) gr = NN - 1;
    float4 v = *(const float4*)(feat + (size_t)gr * DD + c4 * 4);
    us4 b; b.x = bf16r(v.x); b.y = bf16r(v.y); b.z = bf16r(v.z); b.w = bf16r(v.w);
    *(us4*)&Albuf[r * APAD + c4 * 4] = b;
  }

  const int ch0 = tid, ch1 = tid + 512, ch2 = tid + 1024;
  const short8* Bs8 = (const short8*)Btt;
  short8 st0, st1, st2;

  st0 = Bs8[ch0]; st1 = Bs8[ch1];
  if (ch2 < TILE_S8) st2 = Bs8[ch2];
  {
    int c, q;
    c = ch0 >> 2; q = ch0 & 3; *(short8*)&Btbuf[0][c * BTPAD + q * 8] = st0;
    c = ch1 >> 2; q = ch1 & 3; *(short8*)&Btbuf[0][c * BTPAD + q * 8] = st1;
    if (ch2 < TILE_S8) { c = ch2 >> 2; q = ch2 & 3; *(short8*)&Btbuf[0][c * BTPAD + q * 8] = st2; }
  }
  __syncthreads();

  const int r = wave >> 1, p = wave & 1;
  const int arow = r * 16 + (lane & 15);
  const int koff = (lane >> 4) * 8;
  const int cl = lane & 15;

  f32x4 acc[9];
#pragma unroll
  for (int t = 0; t < 9; ++t) acc[t] = (f32x4){0.f, 0.f, 0.f, 0.f};

  for (int kk = 0; kk < 8; ++kk) {
    const int cur = kk & 1;
    if (kk < 7) {
      const short8* src = Bs8 + (size_t)(kk + 1) * TILE_S8;
      st0 = src[ch0]; st1 = src[ch1];
      if (ch2 < TILE_S8) st2 = src[ch2];
    }
    short8 a = *(const short8*)&Albuf[arow * APAD + kk * 32 + koff];
#pragma unroll
    for (int t = 0; t < 9; ++t) {
      int c0 = p + 2 * t;
      if (c0 < 17) {
        short8 b = *(const short8*)&Btbuf[cur][(c0 * 16 + cl) * BTPAD + koff];
        acc[t] = __builtin_amdgcn_mfma_f32_16x16x32_bf16(a, b, acc[t], 0, 0, 0);
      }
    }
    if (kk < 7) {
      int c, q; const int nb = cur ^ 1;
      c = ch0 >> 2; q = ch0 & 3; *(short8*)&Btbuf[nb][c * BTPAD + q * 8] = st0;
      c = ch1 >> 2; q = ch1 & 3; *(short8*)&Btbuf[nb][c * BTPAD + q * 8] = st1;
      if (ch2 < TILE_S8) { c = ch2 >> 2; q = ch2 & 3; *(short8*)&Btbuf[nb][c * BTPAD + q * 8] = st2; }
    }
    __syncthreads();
  }

  const int rbase = m0 + r * 16 + (lane >> 4) * 4;
#pragma unroll
  for (int t = 0; t < 9; ++t) {
    int c0 = p + 2 * t;
    if (c0 >= 17) break;
    int gcol = c0 * 16 + cl;
#pragma unroll
    for (int j = 0; j < 4; ++j) {
      int grow = rbase + j;
      if (grow >= NN) continue;
      float v = acc[t][j];
      if (gcol < 128)      fcs[(size_t)grow * HF + gcol] = bf16r(v);
      else if (gcol < 256) fcd[(size_t)grow * HF + (gcol - 128)] = bf16r(v + bdst[gcol - 128]);
      else if (gcol < 260) asrc[(size_t)grow * HH + (gcol - 256)] = v;
      else if (gcol < 264) adst[(size_t)grow * HH + (gcol - 260)] = v;
    }
  }
}

// ---- dst-degree histogram + per-edge rank ----
__global__ __launch_bounds__(256) void hist_kernel(
    const int* __restrict__ dst_idx, int* __restrict__ cnt,
    int* __restrict__ rank)
{
  int e = blockIdx.x * 256 + threadIdx.x;
  if (e < NE) rank[e] = atomicAdd(&cnt[dst_idx[e]], 1);
}

// ---- CSR scan ----
__global__ __launch_bounds__(256) void scan_block_kernel(
    const int* __restrict__ cnt, int* __restrict__ offs, int* __restrict__ bsum)
{
  __shared__ int tmp[256];
  int t = threadIdx.x;
  int i = blockIdx.x * 256 + t;
  int v = (i < NN) ? cnt[i] : 0;
  tmp[t] = v;
  __syncthreads();
  for (int ofs = 1; ofs < 256; ofs <<= 1) {
    int add = (t >= ofs) ? tmp[t - ofs] : 0;
    __syncthreads();
    tmp[t] += add;
    __syncthreads();
  }
  if (i < NN) offs[i] = tmp[t] - v;
  if (t == 255) bsum[blockIdx.x] = tmp[255];
}

__global__ __launch_bounds__(256) void scan_bsum_kernel(
    const int* __restrict__ bsum, int* __restrict__ boff)
{
  __shared__ int tmp[256];
  int t = threadIdx.x;
  int v = (t < NB_SCAN) ? bsum[t] : 0;
  tmp[t] = v;
  __syncthreads();
  for (int ofs = 1; ofs < 256; ofs <<= 1) {
    int add = (t >= ofs) ? tmp[t - ofs] : 0;
    __syncthreads();
    tmp[t] += add;
    __syncthreads();
  }
  if (t < NB_SCAN) boff[t] = tmp[t] - v;
}

__global__ __launch_bounds__(256) void scan_final_kernel(
    int* __restrict__ offs, const int* __restrict__ boff)
{
  int i = blockIdx.x * 256 + threadIdx.x;
  if (i < NN) offs[i] += boff[blockIdx.x];
  if (i == 0) offs[NN] = NE;
}

// ---- scatter ONLY 4B: perm[csr_slot] = edge id ----
__global__ __launch_bounds__(256) void scatter_perm_kernel(
    const int* __restrict__ dst_idx, const int* __restrict__ offs,
    const int* __restrict__ rank, int* __restrict__ perm)
{
  int e = blockIdx.x * 256 + threadIdx.x;
  if (e >= NE) return;
  perm[offs[dst_idx[e]] + rank[e]] = e;
}

// ---- build records in CSR order: SEQUENTIAL 16B writes ----
// feat_edge rows are 64B = exactly one cache line -> random gather is
// line-exact (same bytes as a stream).
__global__ __launch_bounds__(256) void build_records_kernel(
    const int* __restrict__ perm,
    const float* __restrict__ feat_edge, const float* __restrict__ Wae,
    const int* __restrict__ src_idx, const int* __restrict__ dst_idx,
    const float* __restrict__ asrc, const float* __restrict__ adst,
    int4* __restrict__ sorted)
{
  int p = blockIdx.x * 256 + threadIdx.x;
  if (p >= NE) return;
  int e = perm[p];
  int s = src_idx[e], d = dst_idx[e];

  float ae[HH] = {0.f, 0.f, 0.f, 0.f};
  const float4* fe4 = (const float4*)(feat_edge + (size_t)e * DE_DIM);
#pragma unroll
  for (int q = 0; q < 4; ++q) {
    float4 x = fe4[q];
    const float xs[4] = {x.x, x.y, x.z, x.w};
#pragma unroll
    for (int kk = 0; kk < 4; ++kk) {
      int k = q * 4 + kk;
#pragma unroll
      for (int h = 0; h < HH; ++h) ae[h] += xs[kk] * Wae[k * HH + h];
    }
  }
  float as[4], ad[4];
  *(float4*)as = *(const float4*)(asrc + (size_t)s * 4);
  *(float4*)ad = *(const float4*)(adst + (size_t)d * 4);

  float ev[4];
#pragma unroll
  for (int h = 0; h < HH; ++h) {
    float v = as[h] + ad[h] + ae[h];
    ev[h] = v >= 0.f ? v : SLOPE * v;
  }
  __half2 p01 = __floats2half2_rn(ev[0], ev[1]);
  __half2 p23 = __floats2half2_rn(ev[2], ev[3]);
  int4 rec;
  rec.x = s;
  rec.y = *(int*)&p01;
  rec.z = *(int*)&p23;
  rec.w = 0;
  sorted[p] = rec;     // sequential, fully coalesced
}

// ---- fused softmax+agg: one wave per dst, no max pass ----
__global__ __launch_bounds__(64) void agg_fused_kernel(
    const int* __restrict__ offs, const int4* __restrict__ sorted,
    const unsigned short* __restrict__ fcs, unsigned short* __restrict__ h_out)
{
  const int d = blockIdx.x;
  const int t = threadIdx.x;        // 0..63
  const int fpair = t << 1;
  const int h = t >> 4;
  const int beg = offs[d], end = offs[d + 1];
  const bool hiw = (h & 1);
  const bool hi2 = (h & 2);

  float ssum = 0.f, accx = 0.f, accy = 0.f;

  auto dec = [&](int4 r) -> float {
    int ew = hi2 ? r.z : r.y;
    __half2 hp = *(__half2*)&ew;
    return hiw ? __high2float(hp) : __low2float(hp);
  };

  int p = beg;
  for (; p + 4 <= end; p += 4) {
    int4 r0 = sorted[p + 0];
    int4 r1 = sorted[p + 1];
    int4 r2 = sorted[p + 2];
    int4 r3 = sorted[p + 3];
    unsigned f0 = *(const unsigned*)&fcs[(size_t)r0.x * HF + fpair];
    unsigned f1 = *(const unsigned*)&fcs[(size_t)r1.x * HF + fpair];
    unsigned f2 = *(const unsigned*)&fcs[(size_t)r2.x * HF + fpair];
    unsigned f3 = *(const unsigned*)&fcs[(size_t)r3.x * HF + fpair];
    float z0 = __expf(dec(r0));
    float z1 = __expf(dec(r1));
    float z2 = __expf(dec(r2));
    float z3 = __expf(dec(r3));
    ssum += (z0 + z1) + (z2 + z3);
    accx += bfdec((unsigned short)(f0 & 0xffff)) * z0
          + bfdec((unsigned short)(f1 & 0xffff)) * z1
          + bfdec((unsigned short)(f2 & 0xffff)) * z2
          + bfdec((unsigned short)(f3 & 0xffff)) * z3;
    accy += bfdec((unsigned short)(f0 >> 16)) * z0
          + bfdec((unsigned short)(f1 >> 16)) * z1
          + bfdec((unsigned short)(f2 >> 16)) * z2
          + bfdec((unsigned short)(f3 >> 16)) * z3;
  }
  for (; p < end; ++p) {
    int4 r0 = sorted[p];
    unsigned f0 = *(const unsigned*)&fcs[(size_t)r0.x * HF + fpair];
    float z = __expf(dec(r0));
    ssum += z;
    accx += bfdec((unsigned short)(f0 & 0xffff)) * z;
    accy += bfdec((unsigned short)(f0 >> 16)) * z;
  }
  float inv = (end > beg) ? 1.f / ssum : 0.f;
  ushort2 st;
  st.x = bf16r(accx * inv);
  st.y = bf16r(accy * inv);
  *(ushort2*)&h_out[(size_t)d * HF + fpair] = st;
}

// ---- Kernel 5: shuffle-free LN + MFMA(W_agg) + residual + MFMA(W_apply) ----
__global__ __launch_bounds__(256) void node_final_mfma_kernel(
    const unsigned short* __restrict__ h_in, const float* __restrict__ scale,
    const float* __restrict__ offset,
    const unsigned short* __restrict__ Wagg_t, const float* __restrict__ b_agg,
    const unsigned short* __restrict__ fcd,
    const unsigned short* __restrict__ Wapp_t, const float* __restrict__ b_apply,
    float* __restrict__ out)
{
  __shared__ unsigned short Abuf[NFB * FPAD];     // 17408 B (also holds A2)
  __shared__ unsigned short Bagg[HF * FPAD];      // 34816 B
  const int tid = threadIdx.x;
  const int wave = tid >> 6, lane = tid & 63;
  const int n0 = blockIdx.x * NFB;

  for (int i = tid; i < HF * 16; i += 256) {
    int c = i >> 4, q = i & 15;
    *(short8*)&Bagg[c * FPAD + q * 8] = *(const short8*)(Wagg_t + (size_t)c * HF + q * 8);
  }

  {
    const int r = tid >> 2, h = tid & 3;
    int node = n0 + r; if (node >= NN) node = NN - 1;
    const short8* hp = (const short8*)(h_in + (size_t)node * HF + h * 32);
    short8 v0 = hp[0], v1 = hp[1], v2 = hp[2], v3 = hp[3];

    float x[32];
#pragma unroll
    for (int j = 0; j < 8; ++j) {
      x[j]      = bfdec((unsigned short)v0[j]);
      x[8 + j]  = bfdec((unsigned short)v1[j]);
      x[16 + j] = bfdec((unsigned short)v2[j]);
      x[24 + j] = bfdec((unsigned short)v3[j]);
    }
    float sum = 0.f;
#pragma unroll
    for (int j = 0; j < 32; ++j) sum += x[j];
    float mean = sum * (1.f / 32.f);
    float sq = 0.f;
#pragma unroll
    for (int j = 0; j < 32; ++j) { float dv = x[j] - mean; sq += dv * dv; }
    float rsig = rsqrtf(sq * (1.f / 32.f) + 1e-9f);

#pragma unroll
    for (int c = 0; c < 4; ++c) {
      float4 s0 = *(const float4*)&scale[h * 32 + c * 8];
      float4 s1 = *(const float4*)&scale[h * 32 + c * 8 + 4];
      float4 o0 = *(const float4*)&offset[h * 32 + c * 8];
      float4 o1 = *(const float4*)&offset[h * 32 + c * 8 + 4];
      const float ss[8] = {s0.x, s0.y, s0.z, s0.w, s1.x, s1.y, s1.z, s1.w};
      const float oo[8] = {o0.x, o0.y, o0.z, o0.w, o1.x, o1.y, o1.z, o1.w};
      short8 w;
#pragma unroll
      for (int j = 0; j < 8; ++j)
        w[j] = (short)bf16r((x[c * 8 + j] - mean) * ss[j] * rsig + oo[j]);
      *(short8*)&Abuf[r * FPAD + h * 32 + c * 8] = w;
    }
  }
  __syncthreads();

  const int arow = wave * 16 + (lane & 15);
  const int koff = (lane >> 4) * 8;
  const int rbase = wave * 16 + (lane >> 4) * 4;
  const int cl = lane & 15;

  f32x4 acc1[8];
#pragma unroll
  for (int c0 = 0; c0 < 8; ++c0) acc1[c0] = (f32x4){0.f, 0.f, 0.f, 0.f};
#pragma unroll
  for (int ks = 0; ks < 4; ++ks) {
    short8 a = *(const short8*)&Abuf[arow * FPAD + ks * 32 + koff];
#pragma unroll
    for (int c0 = 0; c0 < 8; ++c0) {
      short8 b = *(const short8*)&Bagg[(c0 * 16 + cl) * FPAD + ks * 32 + koff];
      acc1[c0] = __builtin_amdgcn_mfma_f32_16x16x32_bf16(a, b, acc1[c0], 0, 0, 0);
    }
  }

#pragma unroll
  for (int c0 = 0; c0 < 8; ++c0) {
    int gcol = c0 * 16 + cl;
    float bg = b_agg[gcol];
#pragma unroll
    for (int j = 0; j < 4; ++j) {
      int row = rbase + j;
      int grow = n0 + row;
      float fd = (grow < NN) ? bfdec(fcd[(size_t)grow * HF + gcol]) : 0.f;
      float r = acc1[c0][j] + bg + fd;
      Abuf[row * FPAD + gcol] = bf16r(r >= 0.f ? r : SLOPE * r);
    }
  }
  // no barrier: Abuf rows are wave-private

  f32x4 acc2[2];
#pragma unroll
  for (int c0 = 0; c0 < 2; ++c0) acc2[c0] = (f32x4){0.f, 0.f, 0.f, 0.f};
#pragma unroll
  for (int ks = 0; ks < 4; ++ks) {
    short8 a = *(const short8*)&Abuf[arow * FPAD + ks * 32 + koff];
#pragma unroll
    for (int c0 = 0; c0 < 2; ++c0) {
      short8 b = *(const short8*)(Wapp_t + (size_t)(c0 * 16 + cl) * HF + ks * 32 + koff);
      acc2[c0] = __builtin_amdgcn_mfma_f32_16x16x32_bf16(a, b, acc2[c0], 0, 0, 0);
    }
  }
#pragma unroll
  for (int c0 = 0; c0 < 2; ++c0) {
    int gcol = c0 * 16 + cl;
    float ba = b_apply[gcol];
#pragma unroll
    for (int j = 0; j < 4; ++j) {
      int grow = n0 + rbase + j;
      if (grow < NN) out[(size_t)grow * OUTD + gcol] = acc2[c0][j] + ba;
    }
  }
}

extern "C" void kernel_launch(void* const* d_in, const int* in_sizes, int n_in,
                              void* d_out, int out_size, void* d_ws, size_t ws_size,
                              hipStream_t stream)
{
  const float* feat_src    = (const float*)d_in[0];
  const float* feat_edge   = (const float*)d_in[1];
  const int*   src_idx     = (const int*)d_in[2];
  const int*   dst_idx     = (const int*)d_in[3];
  const float* W_src       = (const float*)d_in[4];
  const float* W_attn_src  = (const float*)d_in[5];
  const float* W_attn_dst  = (const float*)d_in[6];
  const float* W_attn_edge = (const float*)d_in[7];
  const float* scale       = (const float*)d_in[8];
  const float* offset      = (const float*)d_in[9];
  const float* W_agg       = (const float*)d_in[10];
  const float* b_agg       = (const float*)d_in[11];
  const float* W_dst       = (const float*)d_in[12];
  const float* b_dst       = (const float*)d_in[13];
  const float* W_apply     = (const float*)d_in[14];
  const float* b_apply     = (const float*)d_in[15];
  float* out = (float*)d_out;

  char* ws = (char*)d_ws;
  size_t off = 0;
  auto take = [&](size_t bytes) {
    size_t o = off;
    off = (off + bytes + 255) & ~(size_t)255;
    return o;
  };
  size_t fcs_off    = take((size_t)NN * HF * 2);      // bf16
  size_t fcd_off    = take((size_t)NN * HF * 2);      // bf16 (bias folded)
  size_t asrc_off   = take((size_t)NN * 4 * 4);
  size_t adst_off   = take((size_t)NN * 4 * 4);
  size_t bt_off     = take((size_t)NCOL * DD * 2);
  size_t wagg_off   = take((size_t)HF * HF * 2);
  size_t wapp_off   = take((size_t)OUTD * HF * 2);
  size_t cnt_off    = take((size_t)NN * 4);           // zeroed
  size_t offs_off   = take((size_t)(NN + 1) * 4);
  size_t bsum_off   = take((size_t)NB_SCAN * 4);
  size_t boff_off   = take((size_t)NB_SCAN * 4);
  size_t rank_off   = take((size_t)NE * 4);
  size_t perm_off   = take((size_t)NE * 4);
  size_t sorted_off = take((size_t)NE * 16);
  size_t hout_off   = take((size_t)NN * HF * 2);      // bf16
  if (ws_size < off) return;

  unsigned short* fcs    = (unsigned short*)(ws + fcs_off);
  unsigned short* fcd    = (unsigned short*)(ws + fcd_off);
  float*          asrc   = (float*)(ws + asrc_off);
  float*          adst   = (float*)(ws + adst_off);
  unsigned short* Btt    = (unsigned short*)(ws + bt_off);
  unsigned short* Wagg_t = (unsigned short*)(ws + wagg_off);
  unsigned short* Wapp_t = (unsigned short*)(ws + wapp_off);
  int*            cnt    = (int*)(ws + cnt_off);
  int*            offs   = (int*)(ws + offs_off);
  int*            bsum   = (int*)(ws + bsum_off);
  int*            boff   = (int*)(ws + boff_off);
  int*            rank   = (int*)(ws + rank_off);
  int*            perm   = (int*)(ws + perm_off);
  int4*           sorted = (int4*)(ws + sorted_off);
  unsigned short* h_out  = (unsigned short*)(ws + hout_off);

  hipMemsetAsync(ws + cnt_off, 0, (size_t)NN * 4, stream);

  bt_prep_kernel<<<NCOL, 256, 0, stream>>>(W_src, W_dst, W_attn_src, W_attn_dst, Btt);
  wfin_prep_kernel<<<160, 128, 0, stream>>>(W_agg, W_apply, Wagg_t, Wapp_t);

  hist_kernel<<<(NE + 255) / 256, 256, 0, stream>>>(dst_idx, cnt, rank);

  scan_block_kernel<<<NB_SCAN, 256, 0, stream>>>(cnt, offs, bsum);
  scan_bsum_kernel<<<1, 256, 0, stream>>>(bsum, boff);
  scan_final_kernel<<<NB_SCAN, 256, 0, stream>>>(offs, boff);

  scatter_perm_kernel<<<(NE + 255) / 256, 256, 0, stream>>>(
      dst_idx, offs, rank, perm);

  mfma_proj_kernel<<<(NN + BM - 1) / BM, 512, 0, stream>>>(
      feat_src, Btt, b_dst, fcs, fcd, asrc, adst);

  build_records_kernel<<<(NE + 255) / 256, 256, 0, stream>>>(
      perm, feat_edge, W_attn_edge, src_idx, dst_idx, asrc, adst, sorted);

  agg_fused_kernel<<<NN, 64, 0, stream>>>(offs, sorted, fcs, h_out);

  node_final_mfma_kernel<<<(NN + NFB - 1) / NFB, 256, 0, stream>>>(
      h_out, scale, offset, Wagg_t, b_agg, fcd, Wapp_t, b_apply, out);
}

// Round 14
// 193.550 us; speedup vs baseline: 1.0367x; 1.0367x over previous
//
#include <hip/hip_runtime.h>
#include <hip/hip_fp16.h>

#define NN 50000
#define NE 800000
#define DD 256
#define DE_DIM 16
#define HH 4
#define FF 32
#define HF 128
#define OUTD 32
#define SLOPE 0.2f
#define NB_SCAN ((NN + 255) / 256)   // 196

// MFMA proj tiling
#define BM 64
#define NCOL 272
#define BTPAD 40
#define TILE_S8 1088
// node_final MFMA tiling
#define NFB 64
#define FPAD 136

typedef short short8 __attribute__((ext_vector_type(8)));
typedef float f32x4 __attribute__((ext_vector_type(4)));
typedef unsigned short us4 __attribute__((ext_vector_type(4)));

// fp32 -> bf16 bits, round-to-nearest-even
__device__ __forceinline__ unsigned short bf16r(float x) {
  unsigned u = __float_as_uint(x);
  u += 0x7FFFu + ((u >> 16) & 1u);
  return (unsigned short)(u >> 16);
}
__device__ __forceinline__ float bfdec(unsigned short u) {
  return __uint_as_float(((unsigned)u) << 16);
}

// ---- Prep: bf16 weight panel, K-tile-major: Btt[kk][272 cols][32 k] ----
__global__ __launch_bounds__(256) void bt_prep_kernel(
    const float* __restrict__ Wsrc, const float* __restrict__ Wdst,
    const float* __restrict__ Wasrc, const float* __restrict__ Wadst,
    unsigned short* __restrict__ Btt)
{
  int c = blockIdx.x;     // 0..271
  int k = threadIdx.x;    // 0..255
  float v = 0.f;
  if (c < 128)      v = Wsrc[(size_t)k * HF + c];
  else if (c < 256) v = Wdst[(size_t)k * HF + (c - 128)];
  else if (c < 260) v = Wasrc[(size_t)k * HH + (c - 256)];
  else if (c < 264) v = Wadst[(size_t)k * HH + (c - 260)];
  int kk = k >> 5, k5 = k & 31;
  Btt[(size_t)kk * (NCOL * 32) + c * 32 + k5] = bf16r(v);
}

// ---- Prep: transposed bf16 W_agg [128][128] and W_apply [32][128] ----
__global__ __launch_bounds__(128) void wfin_prep_kernel(
    const float* __restrict__ W_agg, const float* __restrict__ W_apply,
    unsigned short* __restrict__ Wagg_t, unsigned short* __restrict__ Wapp_t)
{
  int c = blockIdx.x;     // 0..159
  int k = threadIdx.x;    // 0..127
  if (c < 128) Wagg_t[(size_t)c * HF + k] = bf16r(W_agg[(size_t)k * HF + c]);
  else         Wapp_t[(size_t)(c - 128) * HF + k] = bf16r(W_apply[(size_t)k * OUTD + (c - 128)]);
}

// ---- Kernel 1: MFMA proj; A direct global->reg, B LDS double-buffered ----
// LDS = 2x17.4KB only -> 4 blocks/CU (32 waves/CU). A-fragment = contiguous
// 32B read; lanes {l,l+16,l+32,l+48} share one 128B line (line-exact).
__global__ __launch_bounds__(512) void mfma_proj_kernel(
    const float* __restrict__ feat, const unsigned short* __restrict__ Btt,
    const float* __restrict__ bdst,
    unsigned short* __restrict__ fcs, unsigned short* __restrict__ fcd,
    float* __restrict__ asrc, float* __restrict__ adst)
{
  __shared__ unsigned short Btbuf[2][NCOL * BTPAD];    // 2 x 21760 B
  const int tid  = threadIdx.x;
  const int wave = tid >> 6, lane = tid & 63;
  const int m0 = blockIdx.x * BM;
  const int r = wave >> 1, p = wave & 1;
  const int koff = (lane >> 4) * 8;
  const int cl = lane & 15;

  // A fragments: 8 K-steps x 8 bf16, loaded direct from global, converted once
  short8 afrag[8];
  {
    int grow = m0 + r * 16 + (lane & 15);
    if (grow >= NN) grow = NN - 1;
    const float* arow_p = feat + (size_t)grow * DD + koff;
#pragma unroll
    for (int kk = 0; kk < 8; ++kk) {
      float4 v0 = *(const float4*)(arow_p + kk * 32);
      float4 v1 = *(const float4*)(arow_p + kk * 32 + 4);
      short8 a;
      a[0] = (short)bf16r(v0.x); a[1] = (short)bf16r(v0.y);
      a[2] = (short)bf16r(v0.z); a[3] = (short)bf16r(v0.w);
      a[4] = (short)bf16r(v1.x); a[5] = (short)bf16r(v1.y);
      a[6] = (short)bf16r(v1.z); a[7] = (short)bf16r(v1.w);
      afrag[kk] = a;
    }
  }

  // B staging chunk ownership (short8 units within one 272x32 tile: 1088)
  const int ch0 = tid, ch1 = tid + 512, ch2 = tid + 1024;  // ch2 valid iff tid < 64
  const short8* Bs8 = (const short8*)Btt;
  short8 st0, st1, st2;

  // prologue: tile 0 -> buf 0
  st0 = Bs8[ch0]; st1 = Bs8[ch1];
  if (ch2 < TILE_S8) st2 = Bs8[ch2];
  {
    int c, q;
    c = ch0 >> 2; q = ch0 & 3; *(short8*)&Btbuf[0][c * BTPAD + q * 8] = st0;
    c = ch1 >> 2; q = ch1 & 3; *(short8*)&Btbuf[0][c * BTPAD + q * 8] = st1;
    if (ch2 < TILE_S8) { c = ch2 >> 2; q = ch2 & 3; *(short8*)&Btbuf[0][c * BTPAD + q * 8] = st2; }
  }
  __syncthreads();

  f32x4 acc[9];
#pragma unroll
  for (int t = 0; t < 9; ++t) acc[t] = (f32x4){0.f, 0.f, 0.f, 0.f};

  for (int kk = 0; kk < 8; ++kk) {
    const int cur = kk & 1;
    if (kk < 7) {                      // issue next tile's loads early
      const short8* src = Bs8 + (size_t)(kk + 1) * TILE_S8;
      st0 = src[ch0]; st1 = src[ch1];
      if (ch2 < TILE_S8) st2 = src[ch2];
    }
#pragma unroll
    for (int t = 0; t < 9; ++t) {
      int c0 = p + 2 * t;
      if (c0 < 17) {
        short8 b = *(const short8*)&Btbuf[cur][(c0 * 16 + cl) * BTPAD + koff];
        acc[t] = __builtin_amdgcn_mfma_f32_16x16x32_bf16(afrag[kk], b, acc[t], 0, 0, 0);
      }
    }
    if (kk < 7) {                      // write-late into the other buffer
      int c, q; const int nb = cur ^ 1;
      c = ch0 >> 2; q = ch0 & 3; *(short8*)&Btbuf[nb][c * BTPAD + q * 8] = st0;
      c = ch1 >> 2; q = ch1 & 3; *(short8*)&Btbuf[nb][c * BTPAD + q * 8] = st1;
      if (ch2 < TILE_S8) { c = ch2 >> 2; q = ch2 & 3; *(short8*)&Btbuf[nb][c * BTPAD + q * 8] = st2; }
    }
    __syncthreads();
  }

  const int rbase = m0 + r * 16 + (lane >> 4) * 4;
#pragma unroll
  for (int t = 0; t < 9; ++t) {
    int c0 = p + 2 * t;
    if (c0 >= 17) break;
    int gcol = c0 * 16 + cl;
#pragma unroll
    for (int j = 0; j < 4; ++j) {
      int grow = rbase + j;
      if (grow >= NN) continue;
      float v = acc[t][j];
      if (gcol < 128)      fcs[(size_t)grow * HF + gcol] = bf16r(v);
      else if (gcol < 256) fcd[(size_t)grow * HF + (gcol - 128)] = bf16r(v + bdst[gcol - 128]);
      else if (gcol < 260) asrc[(size_t)grow * HH + (gcol - 256)] = v;
      else if (gcol < 264) adst[(size_t)grow * HH + (gcol - 260)] = v;
    }
  }
}

// ---- dst-degree histogram + per-edge rank ----
__global__ __launch_bounds__(256) void hist_kernel(
    const int* __restrict__ dst_idx, int* __restrict__ cnt,
    int* __restrict__ rank)
{
  int e = blockIdx.x * 256 + threadIdx.x;
  if (e < NE) rank[e] = atomicAdd(&cnt[dst_idx[e]], 1);
}

// ---- CSR scan ----
__global__ __launch_bounds__(256) void scan_block_kernel(
    const int* __restrict__ cnt, int* __restrict__ offs, int* __restrict__ bsum)
{
  __shared__ int tmp[256];
  int t = threadIdx.x;
  int i = blockIdx.x * 256 + t;
  int v = (i < NN) ? cnt[i] : 0;
  tmp[t] = v;
  __syncthreads();
  for (int ofs = 1; ofs < 256; ofs <<= 1) {
    int add = (t >= ofs) ? tmp[t - ofs] : 0;
    __syncthreads();
    tmp[t] += add;
    __syncthreads();
  }
  if (i < NN) offs[i] = tmp[t] - v;
  if (t == 255) bsum[blockIdx.x] = tmp[255];
}

__global__ __launch_bounds__(256) void scan_bsum_kernel(
    const int* __restrict__ bsum, int* __restrict__ boff)
{
  __shared__ int tmp[256];
  int t = threadIdx.x;
  int v = (t < NB_SCAN) ? bsum[t] : 0;
  tmp[t] = v;
  __syncthreads();
  for (int ofs = 1; ofs < 256; ofs <<= 1) {
    int add = (t >= ofs) ? tmp[t - ofs] : 0;
    __syncthreads();
    tmp[t] += add;
    __syncthreads();
  }
  if (t < NB_SCAN) boff[t] = tmp[t] - v;
}

__global__ __launch_bounds__(256) void scan_final_kernel(
    int* __restrict__ offs, const int* __restrict__ boff)
{
  int i = blockIdx.x * 256 + threadIdx.x;
  if (i < NN) offs[i] += boff[blockIdx.x];
  if (i == 0) offs[NN] = NE;
}

// ---- fused logits + scatter of ONE 16B record {src, e01_h2, e23_h2, 0} ----
__global__ __launch_bounds__(256) void scatter_logits_kernel(
    const float* __restrict__ feat_edge, const float* __restrict__ Wae,
    const int* __restrict__ src_idx, const int* __restrict__ dst_idx,
    const float* __restrict__ asrc, const float* __restrict__ adst,
    const int* __restrict__ offs, const int* __restrict__ rank,
    int4* __restrict__ sorted)
{
  int e = blockIdx.x * 256 + threadIdx.x;
  if (e >= NE) return;
  int s = src_idx[e], d = dst_idx[e];

  float ae[HH] = {0.f, 0.f, 0.f, 0.f};
  const float4* fe4 = (const float4*)(feat_edge + (size_t)e * DE_DIM);
#pragma unroll
  for (int q = 0; q < 4; ++q) {
    float4 x = fe4[q];
    const float xs[4] = {x.x, x.y, x.z, x.w};
#pragma unroll
    for (int kk = 0; kk < 4; ++kk) {
      int k = q * 4 + kk;
#pragma unroll
      for (int h = 0; h < HH; ++h) ae[h] += xs[kk] * Wae[k * HH + h];
    }
  }
  float as[4], ad[4];
  *(float4*)as = *(const float4*)(asrc + (size_t)s * 4);
  *(float4*)ad = *(const float4*)(adst + (size_t)d * 4);

  float ev[4];
#pragma unroll
  for (int h = 0; h < HH; ++h) {
    float v = as[h] + ad[h] + ae[h];
    ev[h] = v >= 0.f ? v : SLOPE * v;
  }
  __half2 p01 = __floats2half2_rn(ev[0], ev[1]);
  __half2 p23 = __floats2half2_rn(ev[2], ev[3]);
  int4 rec;
  rec.x = s;
  rec.y = *(int*)&p01;
  rec.z = *(int*)&p23;
  rec.w = 0;
  sorted[offs[d] + rank[e]] = rec;
}

// ---- fused softmax+agg: one wave per dst, no max pass ----
__global__ __launch_bounds__(64) void agg_fused_kernel(
    const int* __restrict__ offs, const int4* __restrict__ sorted,
    const unsigned short* __restrict__ fcs, unsigned short* __restrict__ h_out)
{
  const int d = blockIdx.x;
  const int t = threadIdx.x;        // 0..63
  const int fpair = t << 1;
  const int h = t >> 4;
  const int beg = offs[d], end = offs[d + 1];
  const bool hiw = (h & 1);
  const bool hi2 = (h & 2);

  float ssum = 0.f, accx = 0.f, accy = 0.f;

  auto dec = [&](int4 r) -> float {
    int ew = hi2 ? r.z : r.y;
    __half2 hp = *(__half2*)&ew;
    return hiw ? __high2float(hp) : __low2float(hp);
  };

  int p = beg;
  for (; p + 4 <= end; p += 4) {
    int4 r0 = sorted[p + 0];
    int4 r1 = sorted[p + 1];
    int4 r2 = sorted[p + 2];
    int4 r3 = sorted[p + 3];
    unsigned f0 = *(const unsigned*)&fcs[(size_t)r0.x * HF + fpair];
    unsigned f1 = *(const unsigned*)&fcs[(size_t)r1.x * HF + fpair];
    unsigned f2 = *(const unsigned*)&fcs[(size_t)r2.x * HF + fpair];
    unsigned f3 = *(const unsigned*)&fcs[(size_t)r3.x * HF + fpair];
    float z0 = __expf(dec(r0));
    float z1 = __expf(dec(r1));
    float z2 = __expf(dec(r2));
    float z3 = __expf(dec(r3));
    ssum += (z0 + z1) + (z2 + z3);
    accx += bfdec((unsigned short)(f0 & 0xffff)) * z0
          + bfdec((unsigned short)(f1 & 0xffff)) * z1
          + bfdec((unsigned short)(f2 & 0xffff)) * z2
          + bfdec((unsigned short)(f3 & 0xffff)) * z3;
    accy += bfdec((unsigned short)(f0 >> 16)) * z0
          + bfdec((unsigned short)(f1 >> 16)) * z1
          + bfdec((unsigned short)(f2 >> 16)) * z2
          + bfdec((unsigned short)(f3 >> 16)) * z3;
  }
  for (; p < end; ++p) {
    int4 r0 = sorted[p];
    unsigned f0 = *(const unsigned*)&fcs[(size_t)r0.x * HF + fpair];
    float z = __expf(dec(r0));
    ssum += z;
    accx += bfdec((unsigned short)(f0 & 0xffff)) * z;
    accy += bfdec((unsigned short)(f0 >> 16)) * z;
  }
  float inv = (end > beg) ? 1.f / ssum : 0.f;
  ushort2 st;
  st.x = bf16r(accx * inv);
  st.y = bf16r(accy * inv);
  *(ushort2*)&h_out[(size_t)d * HF + fpair] = st;
}

// ---- Kernel 5: shuffle-free LN + MFMA(W_agg) + residual + MFMA(W_apply) ----
__global__ __launch_bounds__(256) void node_final_mfma_kernel(
    const unsigned short* __restrict__ h_in, const float* __restrict__ scale,
    const float* __restrict__ offset,
    const unsigned short* __restrict__ Wagg_t, const float* __restrict__ b_agg,
    const unsigned short* __restrict__ fcd,
    const unsigned short* __restrict__ Wapp_t, const float* __restrict__ b_apply,
    float* __restrict__ out)
{
  __shared__ unsigned short Abuf[NFB * FPAD];     // 17408 B (also holds A2)
  __shared__ unsigned short Bagg[HF * FPAD];      // 34816 B
  const int tid = threadIdx.x;
  const int wave = tid >> 6, lane = tid & 63;
  const int n0 = blockIdx.x * NFB;

  for (int i = tid; i < HF * 16; i += 256) {
    int c = i >> 4, q = i & 15;
    *(short8*)&Bagg[c * FPAD + q * 8] = *(const short8*)(Wagg_t + (size_t)c * HF + q * 8);
  }

  {
    const int r = tid >> 2, h = tid & 3;
    int node = n0 + r; if (node >= NN) node = NN - 1;
    const short8* hp = (const short8*)(h_in + (size_t)node * HF + h * 32);
    short8 v0 = hp[0], v1 = hp[1], v2 = hp[2], v3 = hp[3];

    float x[32];
#pragma unroll
    for (int j = 0; j < 8; ++j) {
      x[j]      = bfdec((unsigned short)v0[j]);
      x[8 + j]  = bfdec((unsigned short)v1[j]);
      x[16 + j] = bfdec((unsigned short)v2[j]);
      x[24 + j] = bfdec((unsigned short)v3[j]);
    }
    float sum = 0.f;
#pragma unroll
    for (int j = 0; j < 32; ++j) sum += x[j];
    float mean = sum * (1.f / 32.f);
    float sq = 0.f;
#pragma unroll
    for (int j = 0; j < 32; ++j) { float dv = x[j] - mean; sq += dv * dv; }
    float rsig = rsqrtf(sq * (1.f / 32.f) + 1e-9f);

#pragma unroll
    for (int c = 0; c < 4; ++c) {
      float4 s0 = *(const float4*)&scale[h * 32 + c * 8];
      float4 s1 = *(const float4*)&scale[h * 32 + c * 8 + 4];
      float4 o0 = *(const float4*)&offset[h * 32 + c * 8];
      float4 o1 = *(const float4*)&offset[h * 32 + c * 8 + 4];
      const float ss[8] = {s0.x, s0.y, s0.z, s0.w, s1.x, s1.y, s1.z, s1.w};
      const float oo[8] = {o0.x, o0.y, o0.z, o0.w, o1.x, o1.y, o1.z, o1.w};
      short8 w;
#pragma unroll
      for (int j = 0; j < 8; ++j)
        w[j] = (short)bf16r((x[c * 8 + j] - mean) * ss[j] * rsig + oo[j]);
      *(short8*)&Abuf[r * FPAD + h * 32 + c * 8] = w;
    }
  }
  __syncthreads();

  const int arow = wave * 16 + (lane & 15);
  const int koff = (lane >> 4) * 8;
  const int rbase = wave * 16 + (lane >> 4) * 4;
  const int cl = lane & 15;

  f32x4 acc1[8];
#pragma unroll
  for (int c0 = 0; c0 < 8; ++c0) acc1[c0] = (f32x4){0.f, 0.f, 0.f, 0.f};
#pragma unroll
  for (int ks = 0; ks < 4; ++ks) {
    short8 a = *(const short8*)&Abuf[arow * FPAD + ks * 32 + koff];
#pragma unroll
    for (int c0 = 0; c0 < 8; ++c0) {
      short8 b = *(const short8*)&Bagg[(c0 * 16 + cl) * FPAD + ks * 32 + koff];
      acc1[c0] = __builtin_amdgcn_mfma_f32_16x16x32_bf16(a, b, acc1[c0], 0, 0, 0);
    }
  }

#pragma unroll
  for (int c0 = 0; c0 < 8; ++c0) {
    int gcol = c0 * 16 + cl;
    float bg = b_agg[gcol];
#pragma unroll
    for (int j = 0; j < 4; ++j) {
      int row = rbase + j;
      int grow = n0 + row;
      float fd = (grow < NN) ? bfdec(fcd[(size_t)grow * HF + gcol]) : 0.f;
      float r = acc1[c0][j] + bg + fd;
      Abuf[row * FPAD + gcol] = bf16r(r >= 0.f ? r : SLOPE * r);
    }
  }
  // no barrier: Abuf rows are wave-private

  f32x4 acc2[2];
#pragma unroll
  for (int c0 = 0; c0 < 2; ++c0) acc2[c0] = (f32x4){0.f, 0.f, 0.f, 0.f};
#pragma unroll
  for (int ks = 0; ks < 4; ++ks) {
    short8 a = *(const short8*)&Abuf[arow * FPAD + ks * 32 + koff];
#pragma unroll
    for (int c0 = 0; c0 < 2; ++c0) {
      short8 b = *(const short8*)(Wapp_t + (size_t)(c0 * 16 + cl) * HF + ks * 32 + koff);
      acc2[c0] = __builtin_amdgcn_mfma_f32_16x16x32_bf16(a, b, acc2[c0], 0, 0, 0);
    }
  }
#pragma unroll
  for (int c0 = 0; c0 < 2; ++c0) {
    int gcol = c0 * 16 + cl;
    float ba = b_apply[gcol];
#pragma unroll
    for (int j = 0; j < 4; ++j) {
      int grow = n0 + rbase + j;
      if (grow < NN) out[(size_t)grow * OUTD + gcol] = acc2[c0][j] + ba;
    }
  }
}

extern "C" void kernel_launch(void* const* d_in, const int* in_sizes, int n_in,
                              void* d_out, int out_size, void* d_ws, size_t ws_size,
                              hipStream_t stream)
{
  const float* feat_src    = (const float*)d_in[0];
  const float* feat_edge   = (const float*)d_in[1];
  const int*   src_idx     = (const int*)d_in[2];
  const int*   dst_idx     = (const int*)d_in[3];
  const float* W_src       = (const float*)d_in[4];
  const float* W_attn_src  = (const float*)d_in[5];
  const float* W_attn_dst  = (const float*)d_in[6];
  const float* W_attn_edge = (const float*)d_in[7];
  const float* scale       = (const float*)d_in[8];
  const float* offset      = (const float*)d_in[9];
  const float* W_agg       = (const float*)d_in[10];
  const float* b_agg       = (const float*)d_in[11];
  const float* W_dst       = (const float*)d_in[12];
  const float* b_dst       = (const float*)d_in[13];
  const float* W_apply     = (const float*)d_in[14];
  const float* b_apply     = (const float*)d_in[15];
  float* out = (float*)d_out;

  char* ws = (char*)d_ws;
  size_t off = 0;
  auto take = [&](size_t bytes) {
    size_t o = off;
    off = (off + bytes + 255) & ~(size_t)255;
    return o;
  };
  size_t fcs_off    = take((size_t)NN * HF * 2);      // bf16
  size_t fcd_off    = take((size_t)NN * HF * 2);      // bf16 (bias folded)
  size_t asrc_off   = take((size_t)NN * 4 * 4);
  size_t adst_off   = take((size_t)NN * 4 * 4);
  size_t bt_off     = take((size_t)NCOL * DD * 2);
  size_t wagg_off   = take((size_t)HF * HF * 2);
  size_t wapp_off   = take((size_t)OUTD * HF * 2);
  size_t cnt_off    = take((size_t)NN * 4);           // zeroed
  size_t offs_off   = take((size_t)(NN + 1) * 4);
  size_t bsum_off   = take((size_t)NB_SCAN * 4);
  size_t boff_off   = take((size_t)NB_SCAN * 4);
  size_t rank_off   = take((size_t)NE * 4);
  size_t sorted_off = take((size_t)NE * 16);
  size_t hout_off   = take((size_t)NN * HF * 2);      // bf16
  if (ws_size < off) return;

  unsigned short* fcs    = (unsigned short*)(ws + fcs_off);
  unsigned short* fcd    = (unsigned short*)(ws + fcd_off);
  float*          asrc   = (float*)(ws + asrc_off);
  float*          adst   = (float*)(ws + adst_off);
  unsigned short* Btt    = (unsigned short*)(ws + bt_off);
  unsigned short* Wagg_t = (unsigned short*)(ws + wagg_off);
  unsigned short* Wapp_t = (unsigned short*)(ws + wapp_off);
  int*            cnt    = (int*)(ws + cnt_off);
  int*            offs   = (int*)(ws + offs_off);
  int*            bsum   = (int*)(ws + bsum_off);
  int*            boff   = (int*)(ws + boff_off);
  int*            rank   = (int*)(ws + rank_off);
  int4*           sorted = (int4*)(ws + sorted_off);
  unsigned short* h_out  = (unsigned short*)(ws + hout_off);

  hipMemsetAsync(ws + cnt_off, 0, (size_t)NN * 4, stream);

  bt_prep_kernel<<<NCOL, 256, 0, stream>>>(W_src, W_dst, W_attn_src, W_attn_dst, Btt);
  wfin_prep_kernel<<<160, 128, 0, stream>>>(W_agg, W_apply, Wagg_t, Wapp_t);

  hist_kernel<<<(NE + 255) / 256, 256, 0, stream>>>(dst_idx, cnt, rank);

  mfma_proj_kernel<<<(NN + BM - 1) / BM, 512, 0, stream>>>(
      feat_src, Btt, b_dst, fcs, fcd, asrc, adst);

  scan_block_kernel<<<NB_SCAN, 256, 0, stream>>>(cnt, offs, bsum);
  scan_bsum_kernel<<<1, 256, 0, stream>>>(bsum, boff);
  scan_final_kernel<<<NB_SCAN, 256, 0, stream>>>(offs, boff);

  scatter_logits_kernel<<<(NE + 255) / 256, 256, 0, stream>>>(
      feat_edge, W_attn_edge, src_idx, dst_idx, asrc, adst,
      offs, rank, sorted);

  agg_fused_kernel<<<NN, 64, 0, stream>>>(offs, sorted, fcs, h_out);

  node_final_mfma_kernel<<<(NN + NFB - 1) / NFB, 256, 0, stream>>>(
      h_out, scale, offset, Wagg_t, b_agg, fcd, Wapp_t, b_apply, out);
}

// Round 15
// 181.968 us; speedup vs baseline: 1.1027x; 1.0636x over previous
//
#include <hip/hip_runtime.h>
#include <hip/hip_fp16.h>

#define NN 50000
#define NE 800000
#define DD 256
#define DE_DIM 16
#define HH 4
#define FF 32
#define HF 128
#define OUTD 32
#define SLOPE 0.2f
#define NB_SCAN ((NN + 255) / 256)   // 196

// MFMA proj tiling
#define BM 64
#define NCOL 272
#define APAD 264
#define BTPAD 40
#define TILE_S8 1088
// node_final MFMA tiling
#define NFB 64
#define FPAD 136

typedef short short8 __attribute__((ext_vector_type(8)));
typedef float f32x4 __attribute__((ext_vector_type(4)));
typedef unsigned short us4 __attribute__((ext_vector_type(4)));
typedef int i32x4 __attribute__((ext_vector_type(4)));

// fp32 -> bf16 bits, round-to-nearest-even
__device__ __forceinline__ unsigned short bf16r(float x) {
  unsigned u = __float_as_uint(x);
  u += 0x7FFFu + ((u >> 16) & 1u);
  return (unsigned short)(u >> 16);
}
__device__ __forceinline__ float bfdec(unsigned short u) {
  return __uint_as_float(((unsigned)u) << 16);
}

// ---- Prep: bf16 weight panel, K-tile-major: Btt[kk][272 cols][32 k] ----
__global__ __launch_bounds__(256) void bt_prep_kernel(
    const float* __restrict__ Wsrc, const float* __restrict__ Wdst,
    const float* __restrict__ Wasrc, const float* __restrict__ Wadst,
    unsigned short* __restrict__ Btt)
{
  int c = blockIdx.x;     // 0..271
  int k = threadIdx.x;    // 0..255
  float v = 0.f;
  if (c < 128)      v = Wsrc[(size_t)k * HF + c];
  else if (c < 256) v = Wdst[(size_t)k * HF + (c - 128)];
  else if (c < 260) v = Wasrc[(size_t)k * HH + (c - 256)];
  else if (c < 264) v = Wadst[(size_t)k * HH + (c - 260)];
  int kk = k >> 5, k5 = k & 31;
  Btt[(size_t)kk * (NCOL * 32) + c * 32 + k5] = bf16r(v);
}

// ---- Prep: transposed bf16 W_agg [128][128] and W_apply [32][128] ----
__global__ __launch_bounds__(128) void wfin_prep_kernel(
    const float* __restrict__ W_agg, const float* __restrict__ W_apply,
    unsigned short* __restrict__ Wagg_t, unsigned short* __restrict__ Wapp_t)
{
  int c = blockIdx.x;     // 0..159
  int k = threadIdx.x;    // 0..127
  if (c < 128) Wagg_t[(size_t)c * HF + k] = bf16r(W_agg[(size_t)k * HF + c]);
  else         Wapp_t[(size_t)(c - 128) * HF + k] = bf16r(W_apply[(size_t)k * OUTD + (c - 128)]);
}

// ---- Kernel 1: MFMA proj; Albuf + double-buffered B staging (R12-verified) ----
__global__ __launch_bounds__(512) void mfma_proj_kernel(
    const float* __restrict__ feat, const unsigned short* __restrict__ Btt,
    const float* __restrict__ bdst,
    unsigned short* __restrict__ fcs, unsigned short* __restrict__ fcd,
    float* __restrict__ asrc, float* __restrict__ adst)
{
  __shared__ unsigned short Albuf[BM * APAD];
  __shared__ unsigned short Btbuf[2][NCOL * BTPAD];
  const int tid  = threadIdx.x;
  const int wave = tid >> 6, lane = tid & 63;
  const int m0 = blockIdx.x * BM;

  for (int i = tid; i < BM * 64; i += 512) {
    int r = i >> 6, c4 = i & 63;
    int gr = m0 + r; if (gr >= NN) gr = NN - 1;
    float4 v = *(const float4*)(feat + (size_t)gr * DD + c4 * 4);
    us4 b; b.x = bf16r(v.x); b.y = bf16r(v.y); b.z = bf16r(v.z); b.w = bf16r(v.w);
    *(us4*)&Albuf[r * APAD + c4 * 4] = b;
  }

  const int ch0 = tid, ch1 = tid + 512, ch2 = tid + 1024;
  const short8* Bs8 = (const short8*)Btt;
  short8 st0, st1, st2;

  st0 = Bs8[ch0]; st1 = Bs8[ch1];
  if (ch2 < TILE_S8) st2 = Bs8[ch2];
  {
    int c, q;
    c = ch0 >> 2; q = ch0 & 3; *(short8*)&Btbuf[0][c * BTPAD + q * 8] = st0;
    c = ch1 >> 2; q = ch1 & 3; *(short8*)&Btbuf[0][c * BTPAD + q * 8] = st1;
    if (ch2 < TILE_S8) { c = ch2 >> 2; q = ch2 & 3; *(short8*)&Btbuf[0][c * BTPAD + q * 8] = st2; }
  }
  __syncthreads();

  const int r = wave >> 1, p = wave & 1;
  const int arow = r * 16 + (lane & 15);
  const int koff = (lane >> 4) * 8;
  const int cl = lane & 15;

  f32x4 acc[9];
#pragma unroll
  for (int t = 0; t < 9; ++t) acc[t] = (f32x4){0.f, 0.f, 0.f, 0.f};

  for (int kk = 0; kk < 8; ++kk) {
    const int cur = kk & 1;
    if (kk < 7) {
      const short8* src = Bs8 + (size_t)(kk + 1) * TILE_S8;
      st0 = src[ch0]; st1 = src[ch1];
      if (ch2 < TILE_S8) st2 = src[ch2];
    }
    short8 a = *(const short8*)&Albuf[arow * APAD + kk * 32 + koff];
#pragma unroll
    for (int t = 0; t < 9; ++t) {
      int c0 = p + 2 * t;
      if (c0 < 17) {
        short8 b = *(const short8*)&Btbuf[cur][(c0 * 16 + cl) * BTPAD + koff];
        acc[t] = __builtin_amdgcn_mfma_f32_16x16x32_bf16(a, b, acc[t], 0, 0, 0);
      }
    }
    if (kk < 7) {
      int c, q; const int nb = cur ^ 1;
      c = ch0 >> 2; q = ch0 & 3; *(short8*)&Btbuf[nb][c * BTPAD + q * 8] = st0;
      c = ch1 >> 2; q = ch1 & 3; *(short8*)&Btbuf[nb][c * BTPAD + q * 8] = st1;
      if (ch2 < TILE_S8) { c = ch2 >> 2; q = ch2 & 3; *(short8*)&Btbuf[nb][c * BTPAD + q * 8] = st2; }
    }
    __syncthreads();
  }

  const int rbase = m0 + r * 16 + (lane >> 4) * 4;
#pragma unroll
  for (int t = 0; t < 9; ++t) {
    int c0 = p + 2 * t;
    if (c0 >= 17) break;
    int gcol = c0 * 16 + cl;
#pragma unroll
    for (int j = 0; j < 4; ++j) {
      int grow = rbase + j;
      if (grow >= NN) continue;
      float v = acc[t][j];
      if (gcol < 128)      fcs[(size_t)grow * HF + gcol] = bf16r(v);
      else if (gcol < 256) fcd[(size_t)grow * HF + (gcol - 128)] = bf16r(v + bdst[gcol - 128]);
      else if (gcol < 260) asrc[(size_t)grow * HH + (gcol - 256)] = v;
      else if (gcol < 264) adst[(size_t)grow * HH + (gcol - 260)] = v;
    }
  }
}

// ---- dst-degree histogram + per-edge rank ----
__global__ __launch_bounds__(256) void hist_kernel(
    const int* __restrict__ dst_idx, int* __restrict__ cnt,
    int* __restrict__ rank)
{
  int e = blockIdx.x * 256 + threadIdx.x;
  if (e < NE) rank[e] = atomicAdd(&cnt[dst_idx[e]], 1);
}

// ---- CSR scan ----
__global__ __launch_bounds__(256) void scan_block_kernel(
    const int* __restrict__ cnt, int* __restrict__ offs, int* __restrict__ bsum)
{
  __shared__ int tmp[256];
  int t = threadIdx.x;
  int i = blockIdx.x * 256 + t;
  int v = (i < NN) ? cnt[i] : 0;
  tmp[t] = v;
  __syncthreads();
  for (int ofs = 1; ofs < 256; ofs <<= 1) {
    int add = (t >= ofs) ? tmp[t - ofs] : 0;
    __syncthreads();
    tmp[t] += add;
    __syncthreads();
  }
  if (i < NN) offs[i] = tmp[t] - v;
  if (t == 255) bsum[blockIdx.x] = tmp[255];
}

__global__ __launch_bounds__(256) void scan_bsum_kernel(
    const int* __restrict__ bsum, int* __restrict__ boff)
{
  __shared__ int tmp[256];
  int t = threadIdx.x;
  int v = (t < NB_SCAN) ? bsum[t] : 0;
  tmp[t] = v;
  __syncthreads();
  for (int ofs = 1; ofs < 256; ofs <<= 1) {
    int add = (t >= ofs) ? tmp[t - ofs] : 0;
    __syncthreads();
    tmp[t] += add;
    __syncthreads();
  }
  if (t < NB_SCAN) boff[t] = tmp[t] - v;
}

__global__ __launch_bounds__(256) void scan_final_kernel(
    int* __restrict__ offs, const int* __restrict__ boff)
{
  int i = blockIdx.x * 256 + threadIdx.x;
  if (i < NN) offs[i] += boff[blockIdx.x];
  if (i == 0) offs[NN] = NE;
}

// ---- fused logits + scatter of ONE 16B record; NON-TEMPORAL store ----
__global__ __launch_bounds__(256) void scatter_logits_kernel(
    const float* __restrict__ feat_edge, const float* __restrict__ Wae,
    const int* __restrict__ src_idx, const int* __restrict__ dst_idx,
    const float* __restrict__ asrc, const float* __restrict__ adst,
    const int* __restrict__ offs, const int* __restrict__ rank,
    int* __restrict__ sorted)
{
  int e = blockIdx.x * 256 + threadIdx.x;
  if (e >= NE) return;
  int s = src_idx[e], d = dst_idx[e];

  float ae[HH] = {0.f, 0.f, 0.f, 0.f};
  const float4* fe4 = (const float4*)(feat_edge + (size_t)e * DE_DIM);
#pragma unroll
  for (int q = 0; q < 4; ++q) {
    float4 x = fe4[q];
    const float xs[4] = {x.x, x.y, x.z, x.w};
#pragma unroll
    for (int kk = 0; kk < 4; ++kk) {
      int k = q * 4 + kk;
#pragma unroll
      for (int h = 0; h < HH; ++h) ae[h] += xs[kk] * Wae[k * HH + h];
    }
  }
  float as[4], ad[4];
  *(float4*)as = *(const float4*)(asrc + (size_t)s * 4);
  *(float4*)ad = *(const float4*)(adst + (size_t)d * 4);

  float ev[4];
#pragma unroll
  for (int h = 0; h < HH; ++h) {
    float v = as[h] + ad[h] + ae[h];
    ev[h] = v >= 0.f ? v : SLOPE * v;
  }
  __half2 p01 = __floats2half2_rn(ev[0], ev[1]);
  __half2 p23 = __floats2half2_rn(ev[2], ev[3]);
  i32x4 rec;
  rec.x = s;
  rec.y = *(int*)&p01;
  rec.z = *(int*)&p23;
  rec.w = 0;
  __builtin_nontemporal_store(rec, (i32x4*)(sorted + (size_t)(offs[d] + rank[e]) * 4));
}

// ---- fused softmax+agg: one wave per dst, no max pass ----
__global__ __launch_bounds__(64) void agg_fused_kernel(
    const int* __restrict__ offs, const int4* __restrict__ sorted,
    const unsigned short* __restrict__ fcs, unsigned short* __restrict__ h_out)
{
  const int d = blockIdx.x;
  const int t = threadIdx.x;        // 0..63
  const int fpair = t << 1;
  const int h = t >> 4;
  const int beg = offs[d], end = offs[d + 1];
  const bool hiw = (h & 1);
  const bool hi2 = (h & 2);

  float ssum = 0.f, accx = 0.f, accy = 0.f;

  auto dec = [&](int4 r) -> float {
    int ew = hi2 ? r.z : r.y;
    __half2 hp = *(__half2*)&ew;
    return hiw ? __high2float(hp) : __low2float(hp);
  };

  int p = beg;
  for (; p + 4 <= end; p += 4) {
    int4 r0 = sorted[p + 0];
    int4 r1 = sorted[p + 1];
    int4 r2 = sorted[p + 2];
    int4 r3 = sorted[p + 3];
    unsigned f0 = *(const unsigned*)&fcs[(size_t)r0.x * HF + fpair];
    unsigned f1 = *(const unsigned*)&fcs[(size_t)r1.x * HF + fpair];
    unsigned f2 = *(const unsigned*)&fcs[(size_t)r2.x * HF + fpair];
    unsigned f3 = *(const unsigned*)&fcs[(size_t)r3.x * HF + fpair];
    float z0 = __expf(dec(r0));
    float z1 = __expf(dec(r1));
    float z2 = __expf(dec(r2));
    float z3 = __expf(dec(r3));
    ssum += (z0 + z1) + (z2 + z3);
    accx += bfdec((unsigned short)(f0 & 0xffff)) * z0
          + bfdec((unsigned short)(f1 & 0xffff)) * z1
          + bfdec((unsigned short)(f2 & 0xffff)) * z2
          + bfdec((unsigned short)(f3 & 0xffff)) * z3;
    accy += bfdec((unsigned short)(f0 >> 16)) * z0
          + bfdec((unsigned short)(f1 >> 16)) * z1
          + bfdec((unsigned short)(f2 >> 16)) * z2
          + bfdec((unsigned short)(f3 >> 16)) * z3;
  }
  for (; p < end; ++p) {
    int4 r0 = sorted[p];
    unsigned f0 = *(const unsigned*)&fcs[(size_t)r0.x * HF + fpair];
    float z = __expf(dec(r0));
    ssum += z;
    accx += bfdec((unsigned short)(f0 & 0xffff)) * z;
    accy += bfdec((unsigned short)(f0 >> 16)) * z;
  }
  float inv = (end > beg) ? 1.f / ssum : 0.f;
  ushort2 st;
  st.x = bf16r(accx * inv);
  st.y = bf16r(accy * inv);
  *(ushort2*)&h_out[(size_t)d * HF + fpair] = st;
}

// ---- Kernel 5: shuffle-free LN + MFMA(W_agg) + residual + MFMA(W_apply) ----
__global__ __launch_bounds__(256) void node_final_mfma_kernel(
    const unsigned short* __restrict__ h_in, const float* __restrict__ scale,
    const float* __restrict__ offset,
    const unsigned short* __restrict__ Wagg_t, const float* __restrict__ b_agg,
    const unsigned short* __restrict__ fcd,
    const unsigned short* __restrict__ Wapp_t, const float* __restrict__ b_apply,
    float* __restrict__ out)
{
  __shared__ unsigned short Abuf[NFB * FPAD];     // 17408 B (also holds A2)
  __shared__ unsigned short Bagg[HF * FPAD];      // 34816 B
  const int tid = threadIdx.x;
  const int wave = tid >> 6, lane = tid & 63;
  const int n0 = blockIdx.x * NFB;

  for (int i = tid; i < HF * 16; i += 256) {
    int c = i >> 4, q = i & 15;
    *(short8*)&Bagg[c * FPAD + q * 8] = *(const short8*)(Wagg_t + (size_t)c * HF + q * 8);
  }

  {
    const int r = tid >> 2, h = tid & 3;
    int node = n0 + r; if (node >= NN) node = NN - 1;
    const short8* hp = (const short8*)(h_in + (size_t)node * HF + h * 32);
    short8 v0 = hp[0], v1 = hp[1], v2 = hp[2], v3 = hp[3];

    float x[32];
#pragma unroll
    for (int j = 0; j < 8; ++j) {
      x[j]      = bfdec((unsigned short)v0[j]);
      x[8 + j]  = bfdec((unsigned short)v1[j]);
      x[16 + j] = bfdec((unsigned short)v2[j]);
      x[24 + j] = bfdec((unsigned short)v3[j]);
    }
    float sum = 0.f;
#pragma unroll
    for (int j = 0; j < 32; ++j) sum += x[j];
    float mean = sum * (1.f / 32.f);
    float sq = 0.f;
#pragma unroll
    for (int j = 0; j < 32; ++j) { float dv = x[j] - mean; sq += dv * dv; }
    float rsig = rsqrtf(sq * (1.f / 32.f) + 1e-9f);

#pragma unroll
    for (int c = 0; c < 4; ++c) {
      float4 s0 = *(const float4*)&scale[h * 32 + c * 8];
      float4 s1 = *(const float4*)&scale[h * 32 + c * 8 + 4];
      float4 o0 = *(const float4*)&offset[h * 32 + c * 8];
      float4 o1 = *(const float4*)&offset[h * 32 + c * 8 + 4];
      const float ss[8] = {s0.x, s0.y, s0.z, s0.w, s1.x, s1.y, s1.z, s1.w};
      const float oo[8] = {o0.x, o0.y, o0.z, o0.w, o1.x, o1.y, o1.z, o1.w};
      short8 w;
#pragma unroll
      for (int j = 0; j < 8; ++j)
        w[j] = (short)bf16r((x[c * 8 + j] - mean) * ss[j] * rsig + oo[j]);
      *(short8*)&Abuf[r * FPAD + h * 32 + c * 8] = w;
    }
  }
  __syncthreads();

  const int arow = wave * 16 + (lane & 15);
  const int koff = (lane >> 4) * 8;
  const int rbase = wave * 16 + (lane >> 4) * 4;
  const int cl = lane & 15;

  f32x4 acc1[8];
#pragma unroll
  for (int c0 = 0; c0 < 8; ++c0) acc1[c0] = (f32x4){0.f, 0.f, 0.f, 0.f};
#pragma unroll
  for (int ks = 0; ks < 4; ++ks) {
    short8 a = *(const short8*)&Abuf[arow * FPAD + ks * 32 + koff];
#pragma unroll
    for (int c0 = 0; c0 < 8; ++c0) {
      short8 b = *(const short8*)&Bagg[(c0 * 16 + cl) * FPAD + ks * 32 + koff];
      acc1[c0] = __builtin_amdgcn_mfma_f32_16x16x32_bf16(a, b, acc1[c0], 0, 0, 0);
    }
  }

#pragma unroll
  for (int c0 = 0; c0 < 8; ++c0) {
    int gcol = c0 * 16 + cl;
    float bg = b_agg[gcol];
#pragma unroll
    for (int j = 0; j < 4; ++j) {
      int row = rbase + j;
      int grow = n0 + row;
      float fd = (grow < NN) ? bfdec(fcd[(size_t)grow * HF + gcol]) : 0.f;
      float r = acc1[c0][j] + bg + fd;
      Abuf[row * FPAD + gcol] = bf16r(r >= 0.f ? r : SLOPE * r);
    }
  }
  // no barrier: Abuf rows are wave-private

  f32x4 acc2[2];
#pragma unroll
  for (int c0 = 0; c0 < 2; ++c0) acc2[c0] = (f32x4){0.f, 0.f, 0.f, 0.f};
#pragma unroll
  for (int ks = 0; ks < 4; ++ks) {
    short8 a = *(const short8*)&Abuf[arow * FPAD + ks * 32 + koff];
#pragma unroll
    for (int c0 = 0; c0 < 2; ++c0) {
      short8 b = *(const short8*)(Wapp_t + (size_t)(c0 * 16 + cl) * HF + ks * 32 + koff);
      acc2[c0] = __builtin_amdgcn_mfma_f32_16x16x32_bf16(a, b, acc2[c0], 0, 0, 0);
    }
  }
#pragma unroll
  for (int c0 = 0; c0 < 2; ++c0) {
    int gcol = c0 * 16 + cl;
    float ba = b_apply[gcol];
#pragma unroll
    for (int j = 0; j < 4; ++j) {
      int grow = n0 + rbase + j;
      if (grow < NN) out[(size_t)grow * OUTD + gcol] = acc2[c0][j] + ba;
    }
  }
}

extern "C" void kernel_launch(void* const* d_in, const int* in_sizes, int n_in,
                              void* d_out, int out_size, void* d_ws, size_t ws_size,
                              hipStream_t stream)
{
  const float* feat_src    = (const float*)d_in[0];
  const float* feat_edge   = (const float*)d_in[1];
  const int*   src_idx     = (const int*)d_in[2];
  const int*   dst_idx     = (const int*)d_in[3];
  const float* W_src       = (const float*)d_in[4];
  const float* W_attn_src  = (const float*)d_in[5];
  const float* W_attn_dst  = (const float*)d_in[6];
  const float* W_attn_edge = (const float*)d_in[7];
  const float* scale       = (const float*)d_in[8];
  const float* offset      = (const float*)d_in[9];
  const float* W_agg       = (const float*)d_in[10];
  const float* b_agg       = (const float*)d_in[11];
  const float* W_dst       = (const float*)d_in[12];
  const float* b_dst       = (const float*)d_in[13];
  const float* W_apply     = (const float*)d_in[14];
  const float* b_apply     = (const float*)d_in[15];
  float* out = (float*)d_out;

  char* ws = (char*)d_ws;
  size_t off = 0;
  auto take = [&](size_t bytes) {
    size_t o = off;
    off = (off + bytes + 255) & ~(size_t)255;
    return o;
  };
  size_t fcs_off    = take((size_t)NN * HF * 2);      // bf16
  size_t fcd_off    = take((size_t)NN * HF * 2);      // bf16 (bias folded)
  size_t asrc_off   = take((size_t)NN * 4 * 4);
  size_t adst_off   = take((size_t)NN * 4 * 4);
  size_t bt_off     = take((size_t)NCOL * DD * 2);
  size_t wagg_off   = take((size_t)HF * HF * 2);
  size_t wapp_off   = take((size_t)OUTD * HF * 2);
  size_t cnt_off    = take((size_t)NN * 4);           // zeroed
  size_t offs_off   = take((size_t)(NN + 1) * 4);
  size_t bsum_off   = take((size_t)NB_SCAN * 4);
  size_t boff_off   = take((size_t)NB_SCAN * 4);
  size_t rank_off   = take((size_t)NE * 4);
  size_t sorted_off = take((size_t)NE * 16);
  size_t hout_off   = take((size_t)NN * HF * 2);      // bf16
  if (ws_size < off) return;

  unsigned short* fcs    = (unsigned short*)(ws + fcs_off);
  unsigned short* fcd    = (unsigned short*)(ws + fcd_off);
  float*          asrc   = (float*)(ws + asrc_off);
  float*          adst   = (float*)(ws + adst_off);
  unsigned short* Btt    = (unsigned short*)(ws + bt_off);
  unsigned short* Wagg_t = (unsigned short*)(ws + wagg_off);
  unsigned short* Wapp_t = (unsigned short*)(ws + wapp_off);
  int*            cnt    = (int*)(ws + cnt_off);
  int*            offs   = (int*)(ws + offs_off);
  int*            bsum   = (int*)(ws + bsum_off);
  int*            boff   = (int*)(ws + boff_off);
  int*            rank   = (int*)(ws + rank_off);
  int*            sorted = (int*)(ws + sorted_off);
  unsigned short* h_out  = (unsigned short*)(ws + hout_off);

  hipMemsetAsync(ws + cnt_off, 0, (size_t)NN * 4, stream);

  bt_prep_kernel<<<NCOL, 256, 0, stream>>>(W_src, W_dst, W_attn_src, W_attn_dst, Btt);
  wfin_prep_kernel<<<160, 128, 0, stream>>>(W_agg, W_apply, Wagg_t, Wapp_t);

  hist_kernel<<<(NE + 255) / 256, 256, 0, stream>>>(dst_idx, cnt, rank);

  mfma_proj_kernel<<<(NN + BM - 1) / BM, 512, 0, stream>>>(
      feat_src, Btt, b_dst, fcs, fcd, asrc, adst);

  scan_block_kernel<<<NB_SCAN, 256, 0, stream>>>(cnt, offs, bsum);
  scan_bsum_kernel<<<1, 256, 0, stream>>>(bsum, boff);
  scan_final_kernel<<<NB_SCAN, 256, 0, stream>>>(offs, boff);

  scatter_logits_kernel<<<(NE + 255) / 256, 256, 0, stream>>>(
      feat_edge, W_attn_edge, src_idx, dst_idx, asrc, adst,
      offs, rank, sorted);

  agg_fused_kernel<<<NN, 64, 0, stream>>>(
      offs, (const int4*)sorted, fcs, h_out);

  node_final_mfma_kernel<<<(NN + NFB - 1) / NFB, 256, 0, stream>>>(
      h_out, scale, offset, Wagg_t, b_agg, fcd, Wapp_t, b_apply, out);
}

// Round 16
// 180.206 us; speedup vs baseline: 1.1135x; 1.0098x over previous
//
#include <hip/hip_runtime.h>
#include <hip/hip_fp16.h>

#define NN 50000
#define NE 800000
#define DD 256
#define DE_DIM 16
#define HH 4
#define FF 32
#define HF 128
#define OUTD 32
#define SLOPE 0.2f
#define NB_SCAN ((NN + 255) / 256)   // 196

// MFMA proj tiling
#define BM 64
#define NCOL 272
#define APAD 264
#define BTPAD 40
#define TILE_S8 1088
// node_final MFMA tiling
#define NFB 64
#define FPAD 136

typedef short short8 __attribute__((ext_vector_type(8)));
typedef float f32x4 __attribute__((ext_vector_type(4)));
typedef unsigned short us4 __attribute__((ext_vector_type(4)));

// fp32 -> bf16 bits, round-to-nearest-even
__device__ __forceinline__ unsigned short bf16r(float x) {
  unsigned u = __float_as_uint(x);
  u += 0x7FFFu + ((u >> 16) & 1u);
  return (unsigned short)(u >> 16);
}
__device__ __forceinline__ float bfdec(unsigned short u) {
  return __uint_as_float(((unsigned)u) << 16);
}

// ---- Prep: bf16 weight panel, K-tile-major: Btt[kk][272 cols][32 k] ----
__global__ __launch_bounds__(256) void bt_prep_kernel(
    const float* __restrict__ Wsrc, const float* __restrict__ Wdst,
    const float* __restrict__ Wasrc, const float* __restrict__ Wadst,
    unsigned short* __restrict__ Btt)
{
  int c = blockIdx.x;     // 0..271
  int k = threadIdx.x;    // 0..255
  float v = 0.f;
  if (c < 128)      v = Wsrc[(size_t)k * HF + c];
  else if (c < 256) v = Wdst[(size_t)k * HF + (c - 128)];
  else if (c < 260) v = Wasrc[(size_t)k * HH + (c - 256)];
  else if (c < 264) v = Wadst[(size_t)k * HH + (c - 260)];
  int kk = k >> 5, k5 = k & 31;
  Btt[(size_t)kk * (NCOL * 32) + c * 32 + k5] = bf16r(v);
}

// ---- Prep: transposed bf16 W_agg [128][128] and W_apply [32][128] ----
__global__ __launch_bounds__(128) void wfin_prep_kernel(
    const float* __restrict__ W_agg, const float* __restrict__ W_apply,
    unsigned short* __restrict__ Wagg_t, unsigned short* __restrict__ Wapp_t)
{
  int c = blockIdx.x;     // 0..159
  int k = threadIdx.x;    // 0..127
  if (c < 128) Wagg_t[(size_t)c * HF + k] = bf16r(W_agg[(size_t)k * HF + c]);
  else         Wapp_t[(size_t)(c - 128) * HF + k] = bf16r(W_apply[(size_t)k * OUTD + (c - 128)]);
}

// ---- Kernel 1: MFMA proj; Albuf + double-buffered B staging (R12-verified) ----
__global__ __launch_bounds__(512) void mfma_proj_kernel(
    const float* __restrict__ feat, const unsigned short* __restrict__ Btt,
    const float* __restrict__ bdst,
    unsigned short* __restrict__ fcs, unsigned short* __restrict__ fcd,
    float* __restrict__ asrc, float* __restrict__ adst)
{
  __shared__ unsigned short Albuf[BM * APAD];
  __shared__ unsigned short Btbuf[2][NCOL * BTPAD];
  const int tid  = threadIdx.x;
  const int wave = tid >> 6, lane = tid & 63;
  const int m0 = blockIdx.x * BM;

  for (int i = tid; i < BM * 64; i += 512) {
    int r = i >> 6, c4 = i & 63;
    int gr = m0 + r; if (gr >= NN) gr = NN - 1;
    float4 v = *(const float4*)(feat + (size_t)gr * DD + c4 * 4);
    us4 b; b.x = bf16r(v.x); b.y = bf16r(v.y); b.z = bf16r(v.z); b.w = bf16r(v.w);
    *(us4*)&Albuf[r * APAD + c4 * 4] = b;
  }

  const int ch0 = tid, ch1 = tid + 512, ch2 = tid + 1024;
  const short8* Bs8 = (const short8*)Btt;
  short8 st0, st1, st2;

  st0 = Bs8[ch0]; st1 = Bs8[ch1];
  if (ch2 < TILE_S8) st2 = Bs8[ch2];
  {
    int c, q;
    c = ch0 >> 2; q = ch0 & 3; *(short8*)&Btbuf[0][c * BTPAD + q * 8] = st0;
    c = ch1 >> 2; q = ch1 & 3; *(short8*)&Btbuf[0][c * BTPAD + q * 8] = st1;
    if (ch2 < TILE_S8) { c = ch2 >> 2; q = ch2 & 3; *(short8*)&Btbuf[0][c * BTPAD + q * 8] = st2; }
  }
  __syncthreads();

  const int r = wave >> 1, p = wave & 1;
  const int arow = r * 16 + (lane & 15);
  const int koff = (lane >> 4) * 8;
  const int cl = lane & 15;

  f32x4 acc[9];
#pragma unroll
  for (int t = 0; t < 9; ++t) acc[t] = (f32x4){0.f, 0.f, 0.f, 0.f};

  for (int kk = 0; kk < 8; ++kk) {
    const int cur = kk & 1;
    if (kk < 7) {
      const short8* src = Bs8 + (size_t)(kk + 1) * TILE_S8;
      st0 = src[ch0]; st1 = src[ch1];
      if (ch2 < TILE_S8) st2 = src[ch2];
    }
    short8 a = *(const short8*)&Albuf[arow * APAD + kk * 32 + koff];
#pragma unroll
    for (int t = 0; t < 9; ++t) {
      int c0 = p + 2 * t;
      if (c0 < 17) {
        short8 b = *(const short8*)&Btbuf[cur][(c0 * 16 + cl) * BTPAD + koff];
        acc[t] = __builtin_amdgcn_mfma_f32_16x16x32_bf16(a, b, acc[t], 0, 0, 0);
      }
    }
    if (kk < 7) {
      int c, q; const int nb = cur ^ 1;
      c = ch0 >> 2; q = ch0 & 3; *(short8*)&Btbuf[nb][c * BTPAD + q * 8] = st0;
      c = ch1 >> 2; q = ch1 & 3; *(short8*)&Btbuf[nb][c * BTPAD + q * 8] = st1;
      if (ch2 < TILE_S8) { c = ch2 >> 2; q = ch2 & 3; *(short8*)&Btbuf[nb][c * BTPAD + q * 8] = st2; }
    }
    __syncthreads();
  }

  const int rbase = m0 + r * 16 + (lane >> 4) * 4;
#pragma unroll
  for (int t = 0; t < 9; ++t) {
    int c0 = p + 2 * t;
    if (c0 >= 17) break;
    int gcol = c0 * 16 + cl;
#pragma unroll
    for (int j = 0; j < 4; ++j) {
      int grow = rbase + j;
      if (grow >= NN) continue;
      float v = acc[t][j];
      if (gcol < 128)      fcs[(size_t)grow * HF + gcol] = bf16r(v);
      else if (gcol < 256) fcd[(size_t)grow * HF + (gcol - 128)] = bf16r(v + bdst[gcol - 128]);
      else if (gcol < 260) asrc[(size_t)grow * HH + (gcol - 256)] = v;
      else if (gcol < 264) adst[(size_t)grow * HH + (gcol - 260)] = v;
    }
  }
}

// ---- dst-degree histogram + per-edge rank ----
__global__ __launch_bounds__(256) void hist_kernel(
    const int* __restrict__ dst_idx, int* __restrict__ cnt,
    int* __restrict__ rank)
{
  int e = blockIdx.x * 256 + threadIdx.x;
  if (e < NE) rank[e] = atomicAdd(&cnt[dst_idx[e]], 1);
}

// ---- CSR scan ----
__global__ __launch_bounds__(256) void scan_block_kernel(
    const int* __restrict__ cnt, int* __restrict__ offs, int* __restrict__ bsum)
{
  __shared__ int tmp[256];
  int t = threadIdx.x;
  int i = blockIdx.x * 256 + t;
  int v = (i < NN) ? cnt[i] : 0;
  tmp[t] = v;
  __syncthreads();
  for (int ofs = 1; ofs < 256; ofs <<= 1) {
    int add = (t >= ofs) ? tmp[t - ofs] : 0;
    __syncthreads();
    tmp[t] += add;
    __syncthreads();
  }
  if (i < NN) offs[i] = tmp[t] - v;
  if (t == 255) bsum[blockIdx.x] = tmp[255];
}

__global__ __launch_bounds__(256) void scan_bsum_kernel(
    const int* __restrict__ bsum, int* __restrict__ boff)
{
  __shared__ int tmp[256];
  int t = threadIdx.x;
  int v = (t < NB_SCAN) ? bsum[t] : 0;
  tmp[t] = v;
  __syncthreads();
  for (int ofs = 1; ofs < 256; ofs <<= 1) {
    int add = (t >= ofs) ? tmp[t - ofs] : 0;
    __syncthreads();
    tmp[t] += add;
    __syncthreads();
  }
  if (t < NB_SCAN) boff[t] = tmp[t] - v;
}

__global__ __launch_bounds__(256) void scan_final_kernel(
    int* __restrict__ offs, const int* __restrict__ boff)
{
  int i = blockIdx.x * 256 + threadIdx.x;
  if (i < NN) offs[i] += boff[blockIdx.x];
  if (i == 0) offs[NN] = NE;
}

// ---- fused logits + scatter of ONE 16B record (plain store; nt hurt) ----
__global__ __launch_bounds__(256) void scatter_logits_kernel(
    const float* __restrict__ feat_edge, const float* __restrict__ Wae,
    const int* __restrict__ src_idx, const int* __restrict__ dst_idx,
    const float* __restrict__ asrc, const float* __restrict__ adst,
    const int* __restrict__ offs, const int* __restrict__ rank,
    int4* __restrict__ sorted)
{
  int e = blockIdx.x * 256 + threadIdx.x;
  if (e >= NE) return;
  int s = src_idx[e], d = dst_idx[e];

  float ae[HH] = {0.f, 0.f, 0.f, 0.f};
  const float4* fe4 = (const float4*)(feat_edge + (size_t)e * DE_DIM);
#pragma unroll
  for (int q = 0; q < 4; ++q) {
    float4 x = fe4[q];
    const float xs[4] = {x.x, x.y, x.z, x.w};
#pragma unroll
    for (int kk = 0; kk < 4; ++kk) {
      int k = q * 4 + kk;
#pragma unroll
      for (int h = 0; h < HH; ++h) ae[h] += xs[kk] * Wae[k * HH + h];
    }
  }
  float as[4], ad[4];
  *(float4*)as = *(const float4*)(asrc + (size_t)s * 4);
  *(float4*)ad = *(const float4*)(adst + (size_t)d * 4);

  float ev[4];
#pragma unroll
  for (int h = 0; h < HH; ++h) {
    float v = as[h] + ad[h] + ae[h];
    ev[h] = v >= 0.f ? v : SLOPE * v;
  }
  __half2 p01 = __floats2half2_rn(ev[0], ev[1]);
  __half2 p23 = __floats2half2_rn(ev[2], ev[3]);
  int4 rec;
  rec.x = s;
  rec.y = *(int*)&p01;
  rec.z = *(int*)&p23;
  rec.w = 0;
  sorted[offs[d] + rank[e]] = rec;
}

// ---- fused softmax+agg: TWO dsts per wave (32 lanes / 4 features each) ----
// Two independent segment walks per wave -> 2x memory-level parallelism.
__global__ __launch_bounds__(64) void agg_fused_kernel(
    const int* __restrict__ offs, const int4* __restrict__ sorted,
    const unsigned short* __restrict__ fcs, unsigned short* __restrict__ h_out)
{
  const int t = threadIdx.x;        // 0..63
  const int half = t >> 5;          // 0/1 -> which dst
  const int t2 = t & 31;
  const int d = blockIdx.x * 2 + half;
  const int f0 = t2 << 2;           // 4 features per lane
  const int h = t2 >> 3;            // head
  const bool hiw = (h & 1);
  const bool hi2 = (h & 2);
  const int beg = offs[d], end = offs[d + 1];

  auto dec = [&](int4 r) -> float {
    int ew = hi2 ? r.z : r.y;
    __half2 hp = *(__half2*)&ew;
    return hiw ? __high2float(hp) : __low2float(hp);
  };

  float ssum = 0.f, a0 = 0.f, a1 = 0.f, a2 = 0.f, a3 = 0.f;

  int p = beg;
  for (; p + 2 <= end; p += 2) {
    int4 r0 = sorted[p + 0];
    int4 r1 = sorted[p + 1];
    uint2 q0 = *(const uint2*)&fcs[(size_t)r0.x * HF + f0];
    uint2 q1 = *(const uint2*)&fcs[(size_t)r1.x * HF + f0];
    float z0 = __expf(dec(r0));
    float z1 = __expf(dec(r1));
    ssum += z0 + z1;
    a0 += bfdec((unsigned short)(q0.x & 0xffff)) * z0
        + bfdec((unsigned short)(q1.x & 0xffff)) * z1;
    a1 += bfdec((unsigned short)(q0.x >> 16)) * z0
        + bfdec((unsigned short)(q1.x >> 16)) * z1;
    a2 += bfdec((unsigned short)(q0.y & 0xffff)) * z0
        + bfdec((unsigned short)(q1.y & 0xffff)) * z1;
    a3 += bfdec((unsigned short)(q0.y >> 16)) * z0
        + bfdec((unsigned short)(q1.y >> 16)) * z1;
  }
  if (p < end) {
    int4 r0 = sorted[p];
    uint2 q0 = *(const uint2*)&fcs[(size_t)r0.x * HF + f0];
    float z = __expf(dec(r0));
    ssum += z;
    a0 += bfdec((unsigned short)(q0.x & 0xffff)) * z;
    a1 += bfdec((unsigned short)(q0.x >> 16)) * z;
    a2 += bfdec((unsigned short)(q0.y & 0xffff)) * z;
    a3 += bfdec((unsigned short)(q0.y >> 16)) * z;
  }
  float inv = (end > beg) ? 1.f / ssum : 0.f;
  us4 st;
  st.x = bf16r(a0 * inv);
  st.y = bf16r(a1 * inv);
  st.z = bf16r(a2 * inv);
  st.w = bf16r(a3 * inv);
  *(us4*)&h_out[(size_t)d * HF + f0] = st;
}

// ---- Kernel 5: shuffle-free LN + MFMA(W_agg) + residual + MFMA(W_apply) ----
__global__ __launch_bounds__(256) void node_final_mfma_kernel(
    const unsigned short* __restrict__ h_in, const float* __restrict__ scale,
    const float* __restrict__ offset,
    const unsigned short* __restrict__ Wagg_t, const float* __restrict__ b_agg,
    const unsigned short* __restrict__ fcd,
    const unsigned short* __restrict__ Wapp_t, const float* __restrict__ b_apply,
    float* __restrict__ out)
{
  __shared__ unsigned short Abuf[NFB * FPAD];     // 17408 B (also holds A2)
  __shared__ unsigned short Bagg[HF * FPAD];      // 34816 B
  const int tid = threadIdx.x;
  const int wave = tid >> 6, lane = tid & 63;
  const int n0 = blockIdx.x * NFB;

  for (int i = tid; i < HF * 16; i += 256) {
    int c = i >> 4, q = i & 15;
    *(short8*)&Bagg[c * FPAD + q * 8] = *(const short8*)(Wagg_t + (size_t)c * HF + q * 8);
  }

  {
    const int r = tid >> 2, h = tid & 3;
    int node = n0 + r; if (node >= NN) node = NN - 1;
    const short8* hp = (const short8*)(h_in + (size_t)node * HF + h * 32);
    short8 v0 = hp[0], v1 = hp[1], v2 = hp[2], v3 = hp[3];

    float x[32];
#pragma unroll
    for (int j = 0; j < 8; ++j) {
      x[j]      = bfdec((unsigned short)v0[j]);
      x[8 + j]  = bfdec((unsigned short)v1[j]);
      x[16 + j] = bfdec((unsigned short)v2[j]);
      x[24 + j] = bfdec((unsigned short)v3[j]);
    }
    float sum = 0.f;
#pragma unroll
    for (int j = 0; j < 32; ++j) sum += x[j];
    float mean = sum * (1.f / 32.f);
    float sq = 0.f;
#pragma unroll
    for (int j = 0; j < 32; ++j) { float dv = x[j] - mean; sq += dv * dv; }
    float rsig = rsqrtf(sq * (1.f / 32.f) + 1e-9f);

#pragma unroll
    for (int c = 0; c < 4; ++c) {
      float4 s0 = *(const float4*)&scale[h * 32 + c * 8];
      float4 s1 = *(const float4*)&scale[h * 32 + c * 8 + 4];
      float4 o0 = *(const float4*)&offset[h * 32 + c * 8];
      float4 o1 = *(const float4*)&offset[h * 32 + c * 8 + 4];
      const float ss[8] = {s0.x, s0.y, s0.z, s0.w, s1.x, s1.y, s1.z, s1.w};
      const float oo[8] = {o0.x, o0.y, o0.z, o0.w, o1.x, o1.y, o1.z, o1.w};
      short8 w;
#pragma unroll
      for (int j = 0; j < 8; ++j)
        w[j] = (short)bf16r((x[c * 8 + j] - mean) * ss[j] * rsig + oo[j]);
      *(short8*)&Abuf[r * FPAD + h * 32 + c * 8] = w;
    }
  }
  __syncthreads();

  const int arow = wave * 16 + (lane & 15);
  const int koff = (lane >> 4) * 8;
  const int rbase = wave * 16 + (lane >> 4) * 4;
  const int cl = lane & 15;

  f32x4 acc1[8];
#pragma unroll
  for (int c0 = 0; c0 < 8; ++c0) acc1[c0] = (f32x4){0.f, 0.f, 0.f, 0.f};
#pragma unroll
  for (int ks = 0; ks < 4; ++ks) {
    short8 a = *(const short8*)&Abuf[arow * FPAD + ks * 32 + koff];
#pragma unroll
    for (int c0 = 0; c0 < 8; ++c0) {
      short8 b = *(const short8*)&Bagg[(c0 * 16 + cl) * FPAD + ks * 32 + koff];
      acc1[c0] = __builtin_amdgcn_mfma_f32_16x16x32_bf16(a, b, acc1[c0], 0, 0, 0);
    }
  }

#pragma unroll
  for (int c0 = 0; c0 < 8; ++c0) {
    int gcol = c0 * 16 + cl;
    float bg = b_agg[gcol];
#pragma unroll
    for (int j = 0; j < 4; ++j) {
      int row = rbase + j;
      int grow = n0 + row;
      float fd = (grow < NN) ? bfdec(fcd[(size_t)grow * HF + gcol]) : 0.f;
      float r = acc1[c0][j] + bg + fd;
      Abuf[row * FPAD + gcol] = bf16r(r >= 0.f ? r : SLOPE * r);
    }
  }
  // no barrier: Abuf rows are wave-private

  f32x4 acc2[2];
#pragma unroll
  for (int c0 = 0; c0 < 2; ++c0) acc2[c0] = (f32x4){0.f, 0.f, 0.f, 0.f};
#pragma unroll
  for (int ks = 0; ks < 4; ++ks) {
    short8 a = *(const short8*)&Abuf[arow * FPAD + ks * 32 + koff];
#pragma unroll
    for (int c0 = 0; c0 < 2; ++c0) {
      short8 b = *(const short8*)(Wapp_t + (size_t)(c0 * 16 + cl) * HF + ks * 32 + koff);
      acc2[c0] = __builtin_amdgcn_mfma_f32_16x16x32_bf16(a, b, acc2[c0], 0, 0, 0);
    }
  }
#pragma unroll
  for (int c0 = 0; c0 < 2; ++c0) {
    int gcol = c0 * 16 + cl;
    float ba = b_apply[gcol];
#pragma unroll
    for (int j = 0; j < 4; ++j) {
      int grow = n0 + rbase + j;
      if (grow < NN) out[(size_t)grow * OUTD + gcol] = acc2[c0][j] + ba;
    }
  }
}

extern "C" void kernel_launch(void* const* d_in, const int* in_sizes, int n_in,
                              void* d_out, int out_size, void* d_ws, size_t ws_size,
                              hipStream_t stream)
{
  const float* feat_src    = (const float*)d_in[0];
  const float* feat_edge   = (const float*)d_in[1];
  const int*   src_idx     = (const int*)d_in[2];
  const int*   dst_idx     = (const int*)d_in[3];
  const float* W_src       = (const float*)d_in[4];
  const float* W_attn_src  = (const float*)d_in[5];
  const float* W_attn_dst  = (const float*)d_in[6];
  const float* W_attn_edge = (const float*)d_in[7];
  const float* scale       = (const float*)d_in[8];
  const float* offset      = (const float*)d_in[9];
  const float* W_agg       = (const float*)d_in[10];
  const float* b_agg       = (const float*)d_in[11];
  const float* W_dst       = (const float*)d_in[12];
  const float* b_dst       = (const float*)d_in[13];
  const float* W_apply     = (const float*)d_in[14];
  const float* b_apply     = (const float*)d_in[15];
  float* out = (float*)d_out;

  char* ws = (char*)d_ws;
  size_t off = 0;
  auto take = [&](size_t bytes) {
    size_t o = off;
    off = (off + bytes + 255) & ~(size_t)255;
    return o;
  };
  size_t fcs_off    = take((size_t)NN * HF * 2);      // bf16
  size_t fcd_off    = take((size_t)NN * HF * 2);      // bf16 (bias folded)
  size_t asrc_off   = take((size_t)NN * 4 * 4);
  size_t adst_off   = take((size_t)NN * 4 * 4);
  size_t bt_off     = take((size_t)NCOL * DD * 2);
  size_t wagg_off   = take((size_t)HF * HF * 2);
  size_t wapp_off   = take((size_t)OUTD * HF * 2);
  size_t cnt_off    = take((size_t)NN * 4);           // zeroed
  size_t offs_off   = take((size_t)(NN + 1) * 4);
  size_t bsum_off   = take((size_t)NB_SCAN * 4);
  size_t boff_off   = take((size_t)NB_SCAN * 4);
  size_t rank_off   = take((size_t)NE * 4);
  size_t sorted_off = take((size_t)NE * 16);
  size_t hout_off   = take((size_t)NN * HF * 2);      // bf16
  if (ws_size < off) return;

  unsigned short* fcs    = (unsigned short*)(ws + fcs_off);
  unsigned short* fcd    = (unsigned short*)(ws + fcd_off);
  float*          asrc   = (float*)(ws + asrc_off);
  float*          adst   = (float*)(ws + adst_off);
  unsigned short* Btt    = (unsigned short*)(ws + bt_off);
  unsigned short* Wagg_t = (unsigned short*)(ws + wagg_off);
  unsigned short* Wapp_t = (unsigned short*)(ws + wapp_off);
  int*            cnt    = (int*)(ws + cnt_off);
  int*            offs   = (int*)(ws + offs_off);
  int*            bsum   = (int*)(ws + bsum_off);
  int*            boff   = (int*)(ws + boff_off);
  int*            rank   = (int*)(ws + rank_off);
  int4*           sorted = (int4*)(ws + sorted_off);
  unsigned short* h_out  = (unsigned short*)(ws + hout_off);

  hipMemsetAsync(ws + cnt_off, 0, (size_t)NN * 4, stream);

  bt_prep_kernel<<<NCOL, 256, 0, stream>>>(W_src, W_dst, W_attn_src, W_attn_dst, Btt);
  wfin_prep_kernel<<<160, 128, 0, stream>>>(W_agg, W_apply, Wagg_t, Wapp_t);

  hist_kernel<<<(NE + 255) / 256, 256, 0, stream>>>(dst_idx, cnt, rank);

  mfma_proj_kernel<<<(NN + BM - 1) / BM, 512, 0, stream>>>(
      feat_src, Btt, b_dst, fcs, fcd, asrc, adst);

  scan_block_kernel<<<NB_SCAN, 256, 0, stream>>>(cnt, offs, bsum);
  scan_bsum_kernel<<<1, 256, 0, stream>>>(bsum, boff);
  scan_final_kernel<<<NB_SCAN, 256, 0, stream>>>(offs, boff);

  scatter_logits_kernel<<<(NE + 255) / 256, 256, 0, stream>>>(
      feat_edge, W_attn_edge, src_idx, dst_idx, asrc, adst,
      offs, rank, sorted);

  agg_fused_kernel<<<NN / 2, 64, 0, stream>>>(offs, sorted, fcs, h_out);

  node_final_mfma_kernel<<<(NN + NFB - 1) / NFB, 256, 0, stream>>>(
      h_out, scale, offset, Wagg_t, b_agg, fcd, Wapp_t, b_apply, out);
}

// Round 17
// 171.246 us; speedup vs baseline: 1.1717x; 1.0523x over previous
//
#include <hip/hip_runtime.h>
#include <hip/hip_fp16.h>

#define NN 50000
#define NE 800000
#define DD 256
#define DE_DIM 16
#define HH 4
#define FF 32
#define HF 128
#define OUTD 32
#define SLOPE 0.2f
#define NB_SCAN ((NN + 255) / 256)   // 196

// MFMA proj tiling
#define BM 64
#define NCOL 272
#define APAD 264
#define BTPAD 40
#define TILE_S8 1088
// node_final MFMA tiling
#define NFB 64
#define FPAD 136

typedef short short8 __attribute__((ext_vector_type(8)));
typedef float f32x4 __attribute__((ext_vector_type(4)));
typedef unsigned short us4 __attribute__((ext_vector_type(4)));

// fp32 -> bf16 bits, round-to-nearest-even
__device__ __forceinline__ unsigned short bf16r(float x) {
  unsigned u = __float_as_uint(x);
  u += 0x7FFFu + ((u >> 16) & 1u);
  return (unsigned short)(u >> 16);
}
__device__ __forceinline__ float bfdec(unsigned short u) {
  return __uint_as_float(((unsigned)u) << 16);
}

// ---- Prep: bf16 weight panel, K-tile-major: Btt[kk][272 cols][32 k] ----
__global__ __launch_bounds__(256) void bt_prep_kernel(
    const float* __restrict__ Wsrc, const float* __restrict__ Wdst,
    const float* __restrict__ Wasrc, const float* __restrict__ Wadst,
    unsigned short* __restrict__ Btt)
{
  int c = blockIdx.x;     // 0..271
  int k = threadIdx.x;    // 0..255
  float v = 0.f;
  if (c < 128)      v = Wsrc[(size_t)k * HF + c];
  else if (c < 256) v = Wdst[(size_t)k * HF + (c - 128)];
  else if (c < 260) v = Wasrc[(size_t)k * HH + (c - 256)];
  else if (c < 264) v = Wadst[(size_t)k * HH + (c - 260)];
  int kk = k >> 5, k5 = k & 31;
  Btt[(size_t)kk * (NCOL * 32) + c * 32 + k5] = bf16r(v);
}

// ---- Prep: transposed bf16 W_agg [128][128] and W_apply [32][128] ----
__global__ __launch_bounds__(128) void wfin_prep_kernel(
    const float* __restrict__ W_agg, const float* __restrict__ W_apply,
    unsigned short* __restrict__ Wagg_t, unsigned short* __restrict__ Wapp_t)
{
  int c = blockIdx.x;     // 0..159
  int k = threadIdx.x;    // 0..127
  if (c < 128) Wagg_t[(size_t)c * HF + k] = bf16r(W_agg[(size_t)k * HF + c]);
  else         Wapp_t[(size_t)(c - 128) * HF + k] = bf16r(W_apply[(size_t)k * OUTD + (c - 128)]);
}

// ---- Kernel 1: MFMA proj; Albuf + double-buffered B staging (R12-verified) ----
__global__ __launch_bounds__(512) void mfma_proj_kernel(
    const float* __restrict__ feat, const unsigned short* __restrict__ Btt,
    const float* __restrict__ bdst,
    unsigned short* __restrict__ fcs, unsigned short* __restrict__ fcd,
    float* __restrict__ asrc, float* __restrict__ adst)
{
  __shared__ unsigned short Albuf[BM * APAD];
  __shared__ unsigned short Btbuf[2][NCOL * BTPAD];
  const int tid  = threadIdx.x;
  const int wave = tid >> 6, lane = tid & 63;
  const int m0 = blockIdx.x * BM;

  for (int i = tid; i < BM * 64; i += 512) {
    int r = i >> 6, c4 = i & 63;
    int gr = m0 + r; if (gr >= NN) gr = NN - 1;
    float4 v = *(const float4*)(feat + (size_t)gr * DD + c4 * 4);
    us4 b; b.x = bf16r(v.x); b.y = bf16r(v.y); b.z = bf16r(v.z); b.w = bf16r(v.w);
    *(us4*)&Albuf[r * APAD + c4 * 4] = b;
  }

  const int ch0 = tid, ch1 = tid + 512, ch2 = tid + 1024;
  const short8* Bs8 = (const short8*)Btt;
  short8 st0, st1, st2;

  st0 = Bs8[ch0]; st1 = Bs8[ch1];
  if (ch2 < TILE_S8) st2 = Bs8[ch2];
  {
    int c, q;
    c = ch0 >> 2; q = ch0 & 3; *(short8*)&Btbuf[0][c * BTPAD + q * 8] = st0;
    c = ch1 >> 2; q = ch1 & 3; *(short8*)&Btbuf[0][c * BTPAD + q * 8] = st1;
    if (ch2 < TILE_S8) { c = ch2 >> 2; q = ch2 & 3; *(short8*)&Btbuf[0][c * BTPAD + q * 8] = st2; }
  }
  __syncthreads();

  const int r = wave >> 1, p = wave & 1;
  const int arow = r * 16 + (lane & 15);
  const int koff = (lane >> 4) * 8;
  const int cl = lane & 15;

  f32x4 acc[9];
#pragma unroll
  for (int t = 0; t < 9; ++t) acc[t] = (f32x4){0.f, 0.f, 0.f, 0.f};

  for (int kk = 0; kk < 8; ++kk) {
    const int cur = kk & 1;
    if (kk < 7) {
      const short8* src = Bs8 + (size_t)(kk + 1) * TILE_S8;
      st0 = src[ch0]; st1 = src[ch1];
      if (ch2 < TILE_S8) st2 = src[ch2];
    }
    short8 a = *(const short8*)&Albuf[arow * APAD + kk * 32 + koff];
#pragma unroll
    for (int t = 0; t < 9; ++t) {
      int c0 = p + 2 * t;
      if (c0 < 17) {
        short8 b = *(const short8*)&Btbuf[cur][(c0 * 16 + cl) * BTPAD + koff];
        acc[t] = __builtin_amdgcn_mfma_f32_16x16x32_bf16(a, b, acc[t], 0, 0, 0);
      }
    }
    if (kk < 7) {
      int c, q; const int nb = cur ^ 1;
      c = ch0 >> 2; q = ch0 & 3; *(short8*)&Btbuf[nb][c * BTPAD + q * 8] = st0;
      c = ch1 >> 2; q = ch1 & 3; *(short8*)&Btbuf[nb][c * BTPAD + q * 8] = st1;
      if (ch2 < TILE_S8) { c = ch2 >> 2; q = ch2 & 3; *(short8*)&Btbuf[nb][c * BTPAD + q * 8] = st2; }
    }
    __syncthreads();
  }

  const int rbase = m0 + r * 16 + (lane >> 4) * 4;
#pragma unroll
  for (int t = 0; t < 9; ++t) {
    int c0 = p + 2 * t;
    if (c0 >= 17) break;
    int gcol = c0 * 16 + cl;
#pragma unroll
    for (int j = 0; j < 4; ++j) {
      int grow = rbase + j;
      if (grow >= NN) continue;
      float v = acc[t][j];
      if (gcol < 128)      fcs[(size_t)grow * HF + gcol] = bf16r(v);
      else if (gcol < 256) fcd[(size_t)grow * HF + (gcol - 128)] = bf16r(v + bdst[gcol - 128]);
      else if (gcol < 260) asrc[(size_t)grow * HH + (gcol - 256)] = v;
      else if (gcol < 264) adst[(size_t)grow * HH + (gcol - 260)] = v;
    }
  }
}

// ---- fused edge-prepass: ae = feat_edge @ Wae (fp16x4, sequential) + rank ----
__global__ __launch_bounds__(256) void edge_pre_kernel(
    const float* __restrict__ feat_edge, const float* __restrict__ Wae, // [16,4]
    const int* __restrict__ dst_idx, int* __restrict__ cnt,
    int* __restrict__ rank, uint2* __restrict__ aebuf)
{
  int e = blockIdx.x * 256 + threadIdx.x;
  if (e >= NE) return;

  float ae[HH] = {0.f, 0.f, 0.f, 0.f};
  const float4* fe4 = (const float4*)(feat_edge + (size_t)e * DE_DIM);
#pragma unroll
  for (int q = 0; q < 4; ++q) {
    float4 x = fe4[q];
    const float xs[4] = {x.x, x.y, x.z, x.w};
#pragma unroll
    for (int kk = 0; kk < 4; ++kk) {
      int k = q * 4 + kk;
#pragma unroll
      for (int h = 0; h < HH; ++h) ae[h] += xs[kk] * Wae[k * HH + h];
    }
  }
  __half2 a01 = __floats2half2_rn(ae[0], ae[1]);
  __half2 a23 = __floats2half2_rn(ae[2], ae[3]);
  uint2 u; u.x = *(unsigned*)&a01; u.y = *(unsigned*)&a23;
  aebuf[e] = u;
  rank[e] = atomicAdd(&cnt[dst_idx[e]], 1);
}

// ---- CSR scan ----
__global__ __launch_bounds__(256) void scan_block_kernel(
    const int* __restrict__ cnt, int* __restrict__ offs, int* __restrict__ bsum)
{
  __shared__ int tmp[256];
  int t = threadIdx.x;
  int i = blockIdx.x * 256 + t;
  int v = (i < NN) ? cnt[i] : 0;
  tmp[t] = v;
  __syncthreads();
  for (int ofs = 1; ofs < 256; ofs <<= 1) {
    int add = (t >= ofs) ? tmp[t - ofs] : 0;
    __syncthreads();
    tmp[t] += add;
    __syncthreads();
  }
  if (i < NN) offs[i] = tmp[t] - v;
  if (t == 255) bsum[blockIdx.x] = tmp[255];
}

__global__ __launch_bounds__(256) void scan_bsum_kernel(
    const int* __restrict__ bsum, int* __restrict__ boff)
{
  __shared__ int tmp[256];
  int t = threadIdx.x;
  int v = (t < NB_SCAN) ? bsum[t] : 0;
  tmp[t] = v;
  __syncthreads();
  for (int ofs = 1; ofs < 256; ofs <<= 1) {
    int add = (t >= ofs) ? tmp[t - ofs] : 0;
    __syncthreads();
    tmp[t] += add;
    __syncthreads();
  }
  if (t < NB_SCAN) boff[t] = tmp[t] - v;
}

__global__ __launch_bounds__(256) void scan_final_kernel(
    int* __restrict__ offs, const int* __restrict__ boff)
{
  int i = blockIdx.x * 256 + threadIdx.x;
  if (i < NN) offs[i] += boff[blockIdx.x];
  if (i == 0) offs[NN] = NE;
}

// ---- scatter record: all reads streamed or L2/L3-resident; only the
// 16B record store is random ----
__global__ __launch_bounds__(256) void scatter_rec_kernel(
    const int* __restrict__ src_idx, const int* __restrict__ dst_idx,
    const float* __restrict__ asrc, const float* __restrict__ adst,
    const int* __restrict__ offs, const int* __restrict__ rank,
    const uint2* __restrict__ aebuf, int4* __restrict__ sorted)
{
  int e = blockIdx.x * 256 + threadIdx.x;
  if (e >= NE) return;
  int s = src_idx[e], d = dst_idx[e];

  uint2 u = aebuf[e];
  __half2 a01 = *(__half2*)&u.x;
  __half2 a23 = *(__half2*)&u.y;
  float ae[4];
  ae[0] = __low2float(a01); ae[1] = __high2float(a01);
  ae[2] = __low2float(a23); ae[3] = __high2float(a23);

  float as[4], ad[4];
  *(float4*)as = *(const float4*)(asrc + (size_t)s * 4);
  *(float4*)ad = *(const float4*)(adst + (size_t)d * 4);

  float ev[4];
#pragma unroll
  for (int h = 0; h < HH; ++h) {
    float v = as[h] + ad[h] + ae[h];
    ev[h] = v >= 0.f ? v : SLOPE * v;
  }
  __half2 p01 = __floats2half2_rn(ev[0], ev[1]);
  __half2 p23 = __floats2half2_rn(ev[2], ev[3]);
  int4 rec;
  rec.x = s;
  rec.y = *(int*)&p01;
  rec.z = *(int*)&p23;
  rec.w = 0;
  sorted[offs[d] + rank[e]] = rec;
}

// ---- fused softmax+agg: one wave per dst, no max pass (R12-verified) ----
__global__ __launch_bounds__(64) void agg_fused_kernel(
    const int* __restrict__ offs, const int4* __restrict__ sorted,
    const unsigned short* __restrict__ fcs, unsigned short* __restrict__ h_out)
{
  const int d = blockIdx.x;
  const int t = threadIdx.x;        // 0..63
  const int fpair = t << 1;
  const int h = t >> 4;
  const int beg = offs[d], end = offs[d + 1];
  const bool hiw = (h & 1);
  const bool hi2 = (h & 2);

  float ssum = 0.f, accx = 0.f, accy = 0.f;

  auto dec = [&](int4 r) -> float {
    int ew = hi2 ? r.z : r.y;
    __half2 hp = *(__half2*)&ew;
    return hiw ? __high2float(hp) : __low2float(hp);
  };

  int p = beg;
  for (; p + 4 <= end; p += 4) {
    int4 r0 = sorted[p + 0];
    int4 r1 = sorted[p + 1];
    int4 r2 = sorted[p + 2];
    int4 r3 = sorted[p + 3];
    unsigned f0 = *(const unsigned*)&fcs[(size_t)r0.x * HF + fpair];
    unsigned f1 = *(const unsigned*)&fcs[(size_t)r1.x * HF + fpair];
    unsigned f2 = *(const unsigned*)&fcs[(size_t)r2.x * HF + fpair];
    unsigned f3 = *(const unsigned*)&fcs[(size_t)r3.x * HF + fpair];
    float z0 = __expf(dec(r0));
    float z1 = __expf(dec(r1));
    float z2 = __expf(dec(r2));
    float z3 = __expf(dec(r3));
    ssum += (z0 + z1) + (z2 + z3);
    accx += bfdec((unsigned short)(f0 & 0xffff)) * z0
          + bfdec((unsigned short)(f1 & 0xffff)) * z1
          + bfdec((unsigned short)(f2 & 0xffff)) * z2
          + bfdec((unsigned short)(f3 & 0xffff)) * z3;
    accy += bfdec((unsigned short)(f0 >> 16)) * z0
          + bfdec((unsigned short)(f1 >> 16)) * z1
          + bfdec((unsigned short)(f2 >> 16)) * z2
          + bfdec((unsigned short)(f3 >> 16)) * z3;
  }
  for (; p < end; ++p) {
    int4 r0 = sorted[p];
    unsigned f0 = *(const unsigned*)&fcs[(size_t)r0.x * HF + fpair];
    float z = __expf(dec(r0));
    ssum += z;
    accx += bfdec((unsigned short)(f0 & 0xffff)) * z;
    accy += bfdec((unsigned short)(f0 >> 16)) * z;
  }
  float inv = (end > beg) ? 1.f / ssum : 0.f;
  ushort2 st;
  st.x = bf16r(accx * inv);
  st.y = bf16r(accy * inv);
  *(ushort2*)&h_out[(size_t)d * HF + fpair] = st;
}

// ---- Kernel 5: shuffle-free LN + MFMA(W_agg) + residual + MFMA(W_apply) ----
__global__ __launch_bounds__(256) void node_final_mfma_kernel(
    const unsigned short* __restrict__ h_in, const float* __restrict__ scale,
    const float* __restrict__ offset,
    const unsigned short* __restrict__ Wagg_t, const float* __restrict__ b_agg,
    const unsigned short* __restrict__ fcd,
    const unsigned short* __restrict__ Wapp_t, const float* __restrict__ b_apply,
    float* __restrict__ out)
{
  __shared__ unsigned short Abuf[NFB * FPAD];     // 17408 B (also holds A2)
  __shared__ unsigned short Bagg[HF * FPAD];      // 34816 B
  const int tid = threadIdx.x;
  const int wave = tid >> 6, lane = tid & 63;
  const int n0 = blockIdx.x * NFB;

  for (int i = tid; i < HF * 16; i += 256) {
    int c = i >> 4, q = i & 15;
    *(short8*)&Bagg[c * FPAD + q * 8] = *(const short8*)(Wagg_t + (size_t)c * HF + q * 8);
  }

  {
    const int r = tid >> 2, h = tid & 3;
    int node = n0 + r; if (node >= NN) node = NN - 1;
    const short8* hp = (const short8*)(h_in + (size_t)node * HF + h * 32);
    short8 v0 = hp[0], v1 = hp[1], v2 = hp[2], v3 = hp[3];

    float x[32];
#pragma unroll
    for (int j = 0; j < 8; ++j) {
      x[j]      = bfdec((unsigned short)v0[j]);
      x[8 + j]  = bfdec((unsigned short)v1[j]);
      x[16 + j] = bfdec((unsigned short)v2[j]);
      x[24 + j] = bfdec((unsigned short)v3[j]);
    }
    float sum = 0.f;
#pragma unroll
    for (int j = 0; j < 32; ++j) sum += x[j];
    float mean = sum * (1.f / 32.f);
    float sq = 0.f;
#pragma unroll
    for (int j = 0; j < 32; ++j) { float dv = x[j] - mean; sq += dv * dv; }
    float rsig = rsqrtf(sq * (1.f / 32.f) + 1e-9f);

#pragma unroll
    for (int c = 0; c < 4; ++c) {
      float4 s0 = *(const float4*)&scale[h * 32 + c * 8];
      float4 s1 = *(const float4*)&scale[h * 32 + c * 8 + 4];
      float4 o0 = *(const float4*)&offset[h * 32 + c * 8];
      float4 o1 = *(const float4*)&offset[h * 32 + c * 8 + 4];
      const float ss[8] = {s0.x, s0.y, s0.z, s0.w, s1.x, s1.y, s1.z, s1.w};
      const float oo[8] = {o0.x, o0.y, o0.z, o0.w, o1.x, o1.y, o1.z, o1.w};
      short8 w;
#pragma unroll
      for (int j = 0; j < 8; ++j)
        w[j] = (short)bf16r((x[c * 8 + j] - mean) * ss[j] * rsig + oo[j]);
      *(short8*)&Abuf[r * FPAD + h * 32 + c * 8] = w;
    }
  }
  __syncthreads();

  const int arow = wave * 16 + (lane & 15);
  const int koff = (lane >> 4) * 8;
  const int rbase = wave * 16 + (lane >> 4) * 4;
  const int cl = lane & 15;

  f32x4 acc1[8];
#pragma unroll
  for (int c0 = 0; c0 < 8; ++c0) acc1[c0] = (f32x4){0.f, 0.f, 0.f, 0.f};
#pragma unroll
  for (int ks = 0; ks < 4; ++ks) {
    short8 a = *(const short8*)&Abuf[arow * FPAD + ks * 32 + koff];
#pragma unroll
    for (int c0 = 0; c0 < 8; ++c0) {
      short8 b = *(const short8*)&Bagg[(c0 * 16 + cl) * FPAD + ks * 32 + koff];
      acc1[c0] = __builtin_amdgcn_mfma_f32_16x16x32_bf16(a, b, acc1[c0], 0, 0, 0);
    }
  }

#pragma unroll
  for (int c0 = 0; c0 < 8; ++c0) {
    int gcol = c0 * 16 + cl;
    float bg = b_agg[gcol];
#pragma unroll
    for (int j = 0; j < 4; ++j) {
      int row = rbase + j;
      int grow = n0 + row;
      float fd = (grow < NN) ? bfdec(fcd[(size_t)grow * HF + gcol]) : 0.f;
      float r = acc1[c0][j] + bg + fd;
      Abuf[row * FPAD + gcol] = bf16r(r >= 0.f ? r : SLOPE * r);
    }
  }
  // no barrier: Abuf rows are wave-private

  f32x4 acc2[2];
#pragma unroll
  for (int c0 = 0; c0 < 2; ++c0) acc2[c0] = (f32x4){0.f, 0.f, 0.f, 0.f};
#pragma unroll
  for (int ks = 0; ks < 4; ++ks) {
    short8 a = *(const short8*)&Abuf[arow * FPAD + ks * 32 + koff];
#pragma unroll
    for (int c0 = 0; c0 < 2; ++c0) {
      short8 b = *(const short8*)(Wapp_t + (size_t)(c0 * 16 + cl) * HF + ks * 32 + koff);
      acc2[c0] = __builtin_amdgcn_mfma_f32_16x16x32_bf16(a, b, acc2[c0], 0, 0, 0);
    }
  }
#pragma unroll
  for (int c0 = 0; c0 < 2; ++c0) {
    int gcol = c0 * 16 + cl;
    float ba = b_apply[gcol];
#pragma unroll
    for (int j = 0; j < 4; ++j) {
      int grow = n0 + rbase + j;
      if (grow < NN) out[(size_t)grow * OUTD + gcol] = acc2[c0][j] + ba;
    }
  }
}

extern "C" void kernel_launch(void* const* d_in, const int* in_sizes, int n_in,
                              void* d_out, int out_size, void* d_ws, size_t ws_size,
                              hipStream_t stream)
{
  const float* feat_src    = (const float*)d_in[0];
  const float* feat_edge   = (const float*)d_in[1];
  const int*   src_idx     = (const int*)d_in[2];
  const int*   dst_idx     = (const int*)d_in[3];
  const float* W_src       = (const float*)d_in[4];
  const float* W_attn_src  = (const float*)d_in[5];
  const float* W_attn_dst  = (const float*)d_in[6];
  const float* W_attn_edge = (const float*)d_in[7];
  const float* scale       = (const float*)d_in[8];
  const float* offset      = (const float*)d_in[9];
  const float* W_agg       = (const float*)d_in[10];
  const float* b_agg       = (const float*)d_in[11];
  const float* W_dst       = (const float*)d_in[12];
  const float* b_dst       = (const float*)d_in[13];
  const float* W_apply     = (const float*)d_in[14];
  const float* b_apply     = (const float*)d_in[15];
  float* out = (float*)d_out;

  char* ws = (char*)d_ws;
  size_t off = 0;
  auto take = [&](size_t bytes) {
    size_t o = off;
    off = (off + bytes + 255) & ~(size_t)255;
    return o;
  };
  size_t fcs_off    = take((size_t)NN * HF * 2);      // bf16
  size_t fcd_off    = take((size_t)NN * HF * 2);      // bf16 (bias folded)
  size_t asrc_off   = take((size_t)NN * 4 * 4);
  size_t adst_off   = take((size_t)NN * 4 * 4);
  size_t bt_off     = take((size_t)NCOL * DD * 2);
  size_t wagg_off   = take((size_t)HF * HF * 2);
  size_t wapp_off   = take((size_t)OUTD * HF * 2);
  size_t cnt_off    = take((size_t)NN * 4);           // zeroed
  size_t offs_off   = take((size_t)(NN + 1) * 4);
  size_t bsum_off   = take((size_t)NB_SCAN * 4);
  size_t boff_off   = take((size_t)NB_SCAN * 4);
  size_t rank_off   = take((size_t)NE * 4);
  size_t ae_off     = take((size_t)NE * 8);           // fp16x4 per edge
  size_t sorted_off = take((size_t)NE * 16);
  size_t hout_off   = take((size_t)NN * HF * 2);      // bf16
  if (ws_size < off) return;

  unsigned short* fcs    = (unsigned short*)(ws + fcs_off);
  unsigned short* fcd    = (unsigned short*)(ws + fcd_off);
  float*          asrc   = (float*)(ws + asrc_off);
  float*          adst   = (float*)(ws + adst_off);
  unsigned short* Btt    = (unsigned short*)(ws + bt_off);
  unsigned short* Wagg_t = (unsigned short*)(ws + wagg_off);
  unsigned short* Wapp_t = (unsigned short*)(ws + wapp_off);
  int*            cnt    = (int*)(ws + cnt_off);
  int*            offs   = (int*)(ws + offs_off);
  int*            bsum   = (int*)(ws + bsum_off);
  int*            boff   = (int*)(ws + boff_off);
  int*            rank   = (int*)(ws + rank_off);
  uint2*          aebuf  = (uint2*)(ws + ae_off);
  int4*           sorted = (int4*)(ws + sorted_off);
  unsigned short* h_out  = (unsigned short*)(ws + hout_off);

  hipMemsetAsync(ws + cnt_off, 0, (size_t)NN * 4, stream);

  bt_prep_kernel<<<NCOL, 256, 0, stream>>>(W_src, W_dst, W_attn_src, W_attn_dst, Btt);
  wfin_prep_kernel<<<160, 128, 0, stream>>>(W_agg, W_apply, Wagg_t, Wapp_t);

  edge_pre_kernel<<<(NE + 255) / 256, 256, 0, stream>>>(
      feat_edge, W_attn_edge, dst_idx, cnt, rank, aebuf);

  scan_block_kernel<<<NB_SCAN, 256, 0, stream>>>(cnt, offs, bsum);
  scan_bsum_kernel<<<1, 256, 0, stream>>>(bsum, boff);
  scan_final_kernel<<<NB_SCAN, 256, 0, stream>>>(offs, boff);

  mfma_proj_kernel<<<(NN + BM - 1) / BM, 512, 0, stream>>>(
      feat_src, Btt, b_dst, fcs, fcd, asrc, adst);

  scatter_rec_kernel<<<(NE + 255) / 256, 256, 0, stream>>>(
      src_idx, dst_idx, asrc, adst, offs, rank, aebuf, sorted);

  agg_fused_kernel<<<NN, 64, 0, stream>>>(offs, sorted, fcs, h_out);

  node_final_mfma_kernel<<<(NN + NFB - 1) / NFB, 256, 0, stream>>>(
      h_out, scale, offset, Wagg_t, b_agg, fcd, Wapp_t, b_apply, out);
}

// Round 18
// 149.848 us; speedup vs baseline: 1.3391x; 1.1428x over previous
//
#include <hip/hip_runtime.h>
#include <hip/hip_fp16.h>

#define NN 50000
#define NE 800000
#define DD 256
#define DE_DIM 16
#define HH 4
#define FF 32
#define HF 128
#define OUTD 32
#define SLOPE 0.2f
#define NB_SCAN ((NN + 255) / 256)   // 196

// MFMA proj tiling
#define BM 64
#define NCOL 272
#define APAD 264
#define BTPAD 40
#define TILE_S8 1088
#define NMFMA 782                    // ceil(NN/BM)
#define NEDGE 1564                   // edge blocks (512 edges each)
// node_final MFMA tiling
#define NFB 64
#define FPAD 136

typedef short short8 __attribute__((ext_vector_type(8)));
typedef float f32x4 __attribute__((ext_vector_type(4)));
typedef unsigned short us4 __attribute__((ext_vector_type(4)));

// fp32 -> bf16 bits, round-to-nearest-even
__device__ __forceinline__ unsigned short bf16r(float x) {
  unsigned u = __float_as_uint(x);
  u += 0x7FFFu + ((u >> 16) & 1u);
  return (unsigned short)(u >> 16);
}
__device__ __forceinline__ float bfdec(unsigned short u) {
  return __uint_as_float(((unsigned)u) << 16);
}

// ---- Prep (merged): Btt panel + transposed W_agg/W_apply ----
__global__ __launch_bounds__(256) void prep_kernel(
    const float* __restrict__ Wsrc, const float* __restrict__ Wdst,
    const float* __restrict__ Wasrc, const float* __restrict__ Wadst,
    const float* __restrict__ W_agg, const float* __restrict__ W_apply,
    unsigned short* __restrict__ Btt,
    unsigned short* __restrict__ Wagg_t, unsigned short* __restrict__ Wapp_t)
{
  int bid = blockIdx.x;
  if (bid < NCOL) {
    int c = bid, k = threadIdx.x;
    float v = 0.f;
    if (c < 128)      v = Wsrc[(size_t)k * HF + c];
    else if (c < 256) v = Wdst[(size_t)k * HF + (c - 128)];
    else if (c < 260) v = Wasrc[(size_t)k * HH + (c - 256)];
    else if (c < 264) v = Wadst[(size_t)k * HH + (c - 260)];
    int kk = k >> 5, k5 = k & 31;
    Btt[(size_t)kk * (NCOL * 32) + c * 32 + k5] = bf16r(v);
  } else {
    int c = bid - NCOL, k = threadIdx.x;
    if (k >= 128) return;
    if (c < 128) Wagg_t[(size_t)c * HF + k] = bf16r(W_agg[(size_t)k * HF + c]);
    else         Wapp_t[(size_t)(c - 128) * HF + k] = bf16r(W_apply[(size_t)k * OUTD + (c - 128)]);
  }
}

// ---- Fused K1: blocks routed to {MFMA proj} or {edge prepass} ----
// bid%3==0 -> mfma tile bid/3 (782 tiles); else edge chunk of 512 edges.
// Independent work; co-residency overlaps matrix/LDS pipes with HBM stream.
__global__ __launch_bounds__(512) void fused_k1_kernel(
    const float* __restrict__ feat, const unsigned short* __restrict__ Btt,
    const float* __restrict__ bdst,
    unsigned short* __restrict__ fcs, unsigned short* __restrict__ fcd,
    float* __restrict__ asrc, float* __restrict__ adst,
    const float* __restrict__ feat_edge, const float* __restrict__ Wae,
    const int* __restrict__ dst_idx, int* __restrict__ cnt,
    int* __restrict__ rank, uint2* __restrict__ aebuf)
{
  __shared__ unsigned short Albuf[BM * APAD];
  __shared__ unsigned short Btbuf[2][NCOL * BTPAD];
  const int bid = blockIdx.x;
  const int tid = threadIdx.x;

  if (bid % 3 != 0) {
    // ---------------- edge prepass path ----------------
    int eid = bid - bid / 3 - 1;
    int e = eid * 512 + tid;
    if (e >= NE) return;
    float ae[HH] = {0.f, 0.f, 0.f, 0.f};
    const float4* fe4 = (const float4*)(feat_edge + (size_t)e * DE_DIM);
#pragma unroll
    for (int q = 0; q < 4; ++q) {
      float4 x = fe4[q];
      const float xs[4] = {x.x, x.y, x.z, x.w};
#pragma unroll
      for (int kk = 0; kk < 4; ++kk) {
        int k = q * 4 + kk;
#pragma unroll
        for (int h = 0; h < HH; ++h) ae[h] += xs[kk] * Wae[k * HH + h];
      }
    }
    __half2 a01 = __floats2half2_rn(ae[0], ae[1]);
    __half2 a23 = __floats2half2_rn(ae[2], ae[3]);
    uint2 u; u.x = *(unsigned*)&a01; u.y = *(unsigned*)&a23;
    aebuf[e] = u;
    rank[e] = atomicAdd(&cnt[dst_idx[e]], 1);
    return;
  }

  // ---------------- MFMA projection path ----------------
  const int wave = tid >> 6, lane = tid & 63;
  const int m0 = (bid / 3) * BM;

  for (int i = tid; i < BM * 64; i += 512) {
    int r = i >> 6, c4 = i & 63;
    int gr = m0 + r; if (gr >= NN) gr = NN - 1;
    float4 v = *(const float4*)(feat + (size_t)gr * DD + c4 * 4);
    us4 b; b.x = bf16r(v.x); b.y = bf16r(v.y); b.z = bf16r(v.z); b.w = bf16r(v.w);
    *(us4*)&Albuf[r * APAD + c4 * 4] = b;
  }

  const int ch0 = tid, ch1 = tid + 512, ch2 = tid + 1024;
  const short8* Bs8 = (const short8*)Btt;
  short8 st0, st1, st2;

  st0 = Bs8[ch0]; st1 = Bs8[ch1];
  if (ch2 < TILE_S8) st2 = Bs8[ch2];
  {
    int c, q;
    c = ch0 >> 2; q = ch0 & 3; *(short8*)&Btbuf[0][c * BTPAD + q * 8] = st0;
    c = ch1 >> 2; q = ch1 & 3; *(short8*)&Btbuf[0][c * BTPAD + q * 8] = st1;
    if (ch2 < TILE_S8) { c = ch2 >> 2; q = ch2 & 3; *(short8*)&Btbuf[0][c * BTPAD + q * 8] = st2; }
  }
  __syncthreads();

  const int r = wave >> 1, p = wave & 1;
  const int arow = r * 16 + (lane & 15);
  const int koff = (lane >> 4) * 8;
  const int cl = lane & 15;

  f32x4 acc[9];
#pragma unroll
  for (int t = 0; t < 9; ++t) acc[t] = (f32x4){0.f, 0.f, 0.f, 0.f};

  for (int kk = 0; kk < 8; ++kk) {
    const int cur = kk & 1;
    if (kk < 7) {
      const short8* src = Bs8 + (size_t)(kk + 1) * TILE_S8;
      st0 = src[ch0]; st1 = src[ch1];
      if (ch2 < TILE_S8) st2 = src[ch2];
    }
    short8 a = *(const short8*)&Albuf[arow * APAD + kk * 32 + koff];
#pragma unroll
    for (int t = 0; t < 9; ++t) {
      int c0 = p + 2 * t;
      if (c0 < 17) {
        short8 b = *(const short8*)&Btbuf[cur][(c0 * 16 + cl) * BTPAD + koff];
        acc[t] = __builtin_amdgcn_mfma_f32_16x16x32_bf16(a, b, acc[t], 0, 0, 0);
      }
    }
    if (kk < 7) {
      int c, q; const int nb = cur ^ 1;
      c = ch0 >> 2; q = ch0 & 3; *(short8*)&Btbuf[nb][c * BTPAD + q * 8] = st0;
      c = ch1 >> 2; q = ch1 & 3; *(short8*)&Btbuf[nb][c * BTPAD + q * 8] = st1;
      if (ch2 < TILE_S8) { c = ch2 >> 2; q = ch2 & 3; *(short8*)&Btbuf[nb][c * BTPAD + q * 8] = st2; }
    }
    __syncthreads();
  }

  const int rbase = m0 + r * 16 + (lane >> 4) * 4;
#pragma unroll
  for (int t = 0; t < 9; ++t) {
    int c0 = p + 2 * t;
    if (c0 >= 17) break;
    int gcol = c0 * 16 + cl;
#pragma unroll
    for (int j = 0; j < 4; ++j) {
      int grow = rbase + j;
      if (grow >= NN) continue;
      float v = acc[t][j];
      if (gcol < 128)      fcs[(size_t)grow * HF + gcol] = bf16r(v);
      else if (gcol < 256) fcd[(size_t)grow * HF + (gcol - 128)] = bf16r(v + bdst[gcol - 128]);
      else if (gcol < 260) asrc[(size_t)grow * HH + (gcol - 256)] = v;
      else if (gcol < 264) adst[(size_t)grow * HH + (gcol - 260)] = v;
    }
  }
}

// ---- CSR scan ----
__global__ __launch_bounds__(256) void scan_block_kernel(
    const int* __restrict__ cnt, int* __restrict__ offs, int* __restrict__ bsum)
{
  __shared__ int tmp[256];
  int t = threadIdx.x;
  int i = blockIdx.x * 256 + t;
  int v = (i < NN) ? cnt[i] : 0;
  tmp[t] = v;
  __syncthreads();
  for (int ofs = 1; ofs < 256; ofs <<= 1) {
    int add = (t >= ofs) ? tmp[t - ofs] : 0;
    __syncthreads();
    tmp[t] += add;
    __syncthreads();
  }
  if (i < NN) offs[i] = tmp[t] - v;
  if (t == 255) bsum[blockIdx.x] = tmp[255];
}

__global__ __launch_bounds__(256) void scan_bsum_kernel(
    const int* __restrict__ bsum, int* __restrict__ boff)
{
  __shared__ int tmp[256];
  int t = threadIdx.x;
  int v = (t < NB_SCAN) ? bsum[t] : 0;
  tmp[t] = v;
  __syncthreads();
  for (int ofs = 1; ofs < 256; ofs <<= 1) {
    int add = (t >= ofs) ? tmp[t - ofs] : 0;
    __syncthreads();
    tmp[t] += add;
    __syncthreads();
  }
  if (t < NB_SCAN) boff[t] = tmp[t] - v;
}

__global__ __launch_bounds__(256) void scan_final_kernel(
    int* __restrict__ offs, const int* __restrict__ boff)
{
  int i = blockIdx.x * 256 + threadIdx.x;
  if (i < NN) offs[i] += boff[blockIdx.x];
  if (i == 0) offs[NN] = NE;
}

// ---- scatter record: streamed reads + L2-resident gathers; only the
// 16B record store is random ----
__global__ __launch_bounds__(256) void scatter_rec_kernel(
    const int* __restrict__ src_idx, const int* __restrict__ dst_idx,
    const float* __restrict__ asrc, const float* __restrict__ adst,
    const int* __restrict__ offs, const int* __restrict__ rank,
    const uint2* __restrict__ aebuf, int4* __restrict__ sorted)
{
  int e = blockIdx.x * 256 + threadIdx.x;
  if (e >= NE) return;
  int s = src_idx[e], d = dst_idx[e];

  uint2 u = aebuf[e];
  __half2 a01 = *(__half2*)&u.x;
  __half2 a23 = *(__half2*)&u.y;
  float ae[4];
  ae[0] = __low2float(a01); ae[1] = __high2float(a01);
  ae[2] = __low2float(a23); ae[3] = __high2float(a23);

  float as[4], ad[4];
  *(float4*)as = *(const float4*)(asrc + (size_t)s * 4);
  *(float4*)ad = *(const float4*)(adst + (size_t)d * 4);

  float ev[4];
#pragma unroll
  for (int h = 0; h < HH; ++h) {
    float v = as[h] + ad[h] + ae[h];
    ev[h] = v >= 0.f ? v : SLOPE * v;
  }
  __half2 p01 = __floats2half2_rn(ev[0], ev[1]);
  __half2 p23 = __floats2half2_rn(ev[2], ev[3]);
  int4 rec;
  rec.x = s;
  rec.y = *(int*)&p01;
  rec.z = *(int*)&p23;
  rec.w = 0;
  sorted[offs[d] + rank[e]] = rec;
}

// ---- fused softmax+agg: one wave per dst, no max pass (R12-verified) ----
__global__ __launch_bounds__(64) void agg_fused_kernel(
    const int* __restrict__ offs, const int4* __restrict__ sorted,
    const unsigned short* __restrict__ fcs, unsigned short* __restrict__ h_out)
{
  const int d = blockIdx.x;
  const int t = threadIdx.x;        // 0..63
  const int fpair = t << 1;
  const int h = t >> 4;
  const int beg = offs[d], end = offs[d + 1];
  const bool hiw = (h & 1);
  const bool hi2 = (h & 2);

  float ssum = 0.f, accx = 0.f, accy = 0.f;

  auto dec = [&](int4 r) -> float {
    int ew = hi2 ? r.z : r.y;
    __half2 hp = *(__half2*)&ew;
    return hiw ? __high2float(hp) : __low2float(hp);
  };

  int p = beg;
  for (; p + 4 <= end; p += 4) {
    int4 r0 = sorted[p + 0];
    int4 r1 = sorted[p + 1];
    int4 r2 = sorted[p + 2];
    int4 r3 = sorted[p + 3];
    unsigned f0 = *(const unsigned*)&fcs[(size_t)r0.x * HF + fpair];
    unsigned f1 = *(const unsigned*)&fcs[(size_t)r1.x * HF + fpair];
    unsigned f2 = *(const unsigned*)&fcs[(size_t)r2.x * HF + fpair];
    unsigned f3 = *(const unsigned*)&fcs[(size_t)r3.x * HF + fpair];
    float z0 = __expf(dec(r0));
    float z1 = __expf(dec(r1));
    float z2 = __expf(dec(r2));
    float z3 = __expf(dec(r3));
    ssum += (z0 + z1) + (z2 + z3);
    accx += bfdec((unsigned short)(f0 & 0xffff)) * z0
          + bfdec((unsigned short)(f1 & 0xffff)) * z1
          + bfdec((unsigned short)(f2 & 0xffff)) * z2
          + bfdec((unsigned short)(f3 & 0xffff)) * z3;
    accy += bfdec((unsigned short)(f0 >> 16)) * z0
          + bfdec((unsigned short)(f1 >> 16)) * z1
          + bfdec((unsigned short)(f2 >> 16)) * z2
          + bfdec((unsigned short)(f3 >> 16)) * z3;
  }
  for (; p < end; ++p) {
    int4 r0 = sorted[p];
    unsigned f0 = *(const unsigned*)&fcs[(size_t)r0.x * HF + fpair];
    float z = __expf(dec(r0));
    ssum += z;
    accx += bfdec((unsigned short)(f0 & 0xffff)) * z;
    accy += bfdec((unsigned short)(f0 >> 16)) * z;
  }
  float inv = (end > beg) ? 1.f / ssum : 0.f;
  ushort2 st;
  st.x = bf16r(accx * inv);
  st.y = bf16r(accy * inv);
  *(ushort2*)&h_out[(size_t)d * HF + fpair] = st;
}

// ---- Kernel 5: shuffle-free LN + MFMA(W_agg) + residual + MFMA(W_apply) ----
__global__ __launch_bounds__(256) void node_final_mfma_kernel(
    const unsigned short* __restrict__ h_in, const float* __restrict__ scale,
    const float* __restrict__ offset,
    const unsigned short* __restrict__ Wagg_t, const float* __restrict__ b_agg,
    const unsigned short* __restrict__ fcd,
    const unsigned short* __restrict__ Wapp_t, const float* __restrict__ b_apply,
    float* __restrict__ out)
{
  __shared__ unsigned short Abuf[NFB * FPAD];     // 17408 B (also holds A2)
  __shared__ unsigned short Bagg[HF * FPAD];      // 34816 B
  const int tid = threadIdx.x;
  const int wave = tid >> 6, lane = tid & 63;
  const int n0 = blockIdx.x * NFB;

  for (int i = tid; i < HF * 16; i += 256) {
    int c = i >> 4, q = i & 15;
    *(short8*)&Bagg[c * FPAD + q * 8] = *(const short8*)(Wagg_t + (size_t)c * HF + q * 8);
  }

  {
    const int r = tid >> 2, h = tid & 3;
    int node = n0 + r; if (node >= NN) node = NN - 1;
    const short8* hp = (const short8*)(h_in + (size_t)node * HF + h * 32);
    short8 v0 = hp[0], v1 = hp[1], v2 = hp[2], v3 = hp[3];

    float x[32];
#pragma unroll
    for (int j = 0; j < 8; ++j) {
      x[j]      = bfdec((unsigned short)v0[j]);
      x[8 + j]  = bfdec((unsigned short)v1[j]);
      x[16 + j] = bfdec((unsigned short)v2[j]);
      x[24 + j] = bfdec((unsigned short)v3[j]);
    }
    float sum = 0.f;
#pragma unroll
    for (int j = 0; j < 32; ++j) sum += x[j];
    float mean = sum * (1.f / 32.f);
    float sq = 0.f;
#pragma unroll
    for (int j = 0; j < 32; ++j) { float dv = x[j] - mean; sq += dv * dv; }
    float rsig = rsqrtf(sq * (1.f / 32.f) + 1e-9f);

#pragma unroll
    for (int c = 0; c < 4; ++c) {
      float4 s0 = *(const float4*)&scale[h * 32 + c * 8];
      float4 s1 = *(const float4*)&scale[h * 32 + c * 8 + 4];
      float4 o0 = *(const float4*)&offset[h * 32 + c * 8];
      float4 o1 = *(const float4*)&offset[h * 32 + c * 8 + 4];
      const float ss[8] = {s0.x, s0.y, s0.z, s0.w, s1.x, s1.y, s1.z, s1.w};
      const float oo[8] = {o0.x, o0.y, o0.z, o0.w, o1.x, o1.y, o1.z, o1.w};
      short8 w;
#pragma unroll
      for (int j = 0; j < 8; ++j)
        w[j] = (short)bf16r((x[c * 8 + j] - mean) * ss[j] * rsig + oo[j]);
      *(short8*)&Abuf[r * FPAD + h * 32 + c * 8] = w;
    }
  }
  __syncthreads();

  const int arow = wave * 16 + (lane & 15);
  const int koff = (lane >> 4) * 8;
  const int rbase = wave * 16 + (lane >> 4) * 4;
  const int cl = lane & 15;

  f32x4 acc1[8];
#pragma unroll
  for (int c0 = 0; c0 < 8; ++c0) acc1[c0] = (f32x4){0.f, 0.f, 0.f, 0.f};
#pragma unroll
  for (int ks = 0; ks < 4; ++ks) {
    short8 a = *(const short8*)&Abuf[arow * FPAD + ks * 32 + koff];
#pragma unroll
    for (int c0 = 0; c0 < 8; ++c0) {
      short8 b = *(const short8*)&Bagg[(c0 * 16 + cl) * FPAD + ks * 32 + koff];
      acc1[c0] = __builtin_amdgcn_mfma_f32_16x16x32_bf16(a, b, acc1[c0], 0, 0, 0);
    }
  }

#pragma unroll
  for (int c0 = 0; c0 < 8; ++c0) {
    int gcol = c0 * 16 + cl;
    float bg = b_agg[gcol];
#pragma unroll
    for (int j = 0; j < 4; ++j) {
      int row = rbase + j;
      int grow = n0 + row;
      float fd = (grow < NN) ? bfdec(fcd[(size_t)grow * HF + gcol]) : 0.f;
      float r = acc1[c0][j] + bg + fd;
      Abuf[row * FPAD + gcol] = bf16r(r >= 0.f ? r : SLOPE * r);
    }
  }
  // no barrier: Abuf rows are wave-private

  f32x4 acc2[2];
#pragma unroll
  for (int c0 = 0; c0 < 2; ++c0) acc2[c0] = (f32x4){0.f, 0.f, 0.f, 0.f};
#pragma unroll
  for (int ks = 0; ks < 4; ++ks) {
    short8 a = *(const short8*)&Abuf[arow * FPAD + ks * 32 + koff];
#pragma unroll
    for (int c0 = 0; c0 < 2; ++c0) {
      short8 b = *(const short8*)(Wapp_t + (size_t)(c0 * 16 + cl) * HF + ks * 32 + koff);
      acc2[c0] = __builtin_amdgcn_mfma_f32_16x16x32_bf16(a, b, acc2[c0], 0, 0, 0);
    }
  }
#pragma unroll
  for (int c0 = 0; c0 < 2; ++c0) {
    int gcol = c0 * 16 + cl;
    float ba = b_apply[gcol];
#pragma unroll
    for (int j = 0; j < 4; ++j) {
      int grow = n0 + rbase + j;
      if (grow < NN) out[(size_t)grow * OUTD + gcol] = acc2[c0][j] + ba;
    }
  }
}

extern "C" void kernel_launch(void* const* d_in, const int* in_sizes, int n_in,
                              void* d_out, int out_size, void* d_ws, size_t ws_size,
                              hipStream_t stream)
{
  const float* feat_src    = (const float*)d_in[0];
  const float* feat_edge   = (const float*)d_in[1];
  const int*   src_idx     = (const int*)d_in[2];
  const int*   dst_idx     = (const int*)d_in[3];
  const float* W_src       = (const float*)d_in[4];
  const float* W_attn_src  = (const float*)d_in[5];
  const float* W_attn_dst  = (const float*)d_in[6];
  const float* W_attn_edge = (const float*)d_in[7];
  const float* scale       = (const float*)d_in[8];
  const float* offset      = (const float*)d_in[9];
  const float* W_agg       = (const float*)d_in[10];
  const float* b_agg       = (const float*)d_in[11];
  const float* W_dst       = (const float*)d_in[12];
  const float* b_dst       = (const float*)d_in[13];
  const float* W_apply     = (const float*)d_in[14];
  const float* b_apply     = (const float*)d_in[15];
  float* out = (float*)d_out;

  char* ws = (char*)d_ws;
  size_t off = 0;
  auto take = [&](size_t bytes) {
    size_t o = off;
    off = (off + bytes + 255) & ~(size_t)255;
    return o;
  };
  size_t fcs_off    = take((size_t)NN * HF * 2);      // bf16
  size_t fcd_off    = take((size_t)NN * HF * 2);      // bf16 (bias folded)
  size_t asrc_off   = take((size_t)NN * 4 * 4);
  size_t adst_off   = take((size_t)NN * 4 * 4);
  size_t bt_off     = take((size_t)NCOL * DD * 2);
  size_t wagg_off   = take((size_t)HF * HF * 2);
  size_t wapp_off   = take((size_t)OUTD * HF * 2);
  size_t cnt_off    = take((size_t)NN * 4);           // zeroed
  size_t offs_off   = take((size_t)(NN + 1) * 4);
  size_t bsum_off   = take((size_t)NB_SCAN * 4);
  size_t boff_off   = take((size_t)NB_SCAN * 4);
  size_t rank_off   = take((size_t)NE * 4);
  size_t ae_off     = take((size_t)NE * 8);           // fp16x4 per edge
  size_t sorted_off = take((size_t)NE * 16);
  size_t hout_off   = take((size_t)NN * HF * 2);      // bf16
  if (ws_size < off) return;

  unsigned short* fcs    = (unsigned short*)(ws + fcs_off);
  unsigned short* fcd    = (unsigned short*)(ws + fcd_off);
  float*          asrc   = (float*)(ws + asrc_off);
  float*          adst   = (float*)(ws + adst_off);
  unsigned short* Btt    = (unsigned short*)(ws + bt_off);
  unsigned short* Wagg_t = (unsigned short*)(ws + wagg_off);
  unsigned short* Wapp_t = (unsigned short*)(ws + wapp_off);
  int*            cnt    = (int*)(ws + cnt_off);
  int*            offs   = (int*)(ws + offs_off);
  int*            bsum   = (int*)(ws + bsum_off);
  int*            boff   = (int*)(ws + boff_off);
  int*            rank   = (int*)(ws + rank_off);
  uint2*          aebuf  = (uint2*)(ws + ae_off);
  int4*           sorted = (int4*)(ws + sorted_off);
  unsigned short* h_out  = (unsigned short*)(ws + hout_off);

  hipMemsetAsync(ws + cnt_off, 0, (size_t)NN * 4, stream);

  prep_kernel<<<NCOL + 160, 256, 0, stream>>>(
      W_src, W_dst, W_attn_src, W_attn_dst, W_agg, W_apply,
      Btt, Wagg_t, Wapp_t);

  fused_k1_kernel<<<NMFMA + NEDGE, 512, 0, stream>>>(
      feat_src, Btt, b_dst, fcs, fcd, asrc, adst,
      feat_edge, W_attn_edge, dst_idx, cnt, rank, aebuf);

  scan_block_kernel<<<NB_SCAN, 256, 0, stream>>>(cnt, offs, bsum);
  scan_bsum_kernel<<<1, 256, 0, stream>>>(bsum, boff);
  scan_final_kernel<<<NB_SCAN, 256, 0, stream>>>(offs, boff);

  scatter_rec_kernel<<<(NE + 255) / 256, 256, 0, stream>>>(
      src_idx, dst_idx, asrc, adst, offs, rank, aebuf, sorted);

  agg_fused_kernel<<<NN, 64, 0, stream>>>(offs, sorted, fcs, h_out);

  node_final_mfma_kernel<<<(NN + NFB - 1) / NFB, 256, 0, stream>>>(
      h_out, scale, offset, Wagg_t, b_agg, fcd, Wapp_t, b_apply, out);
}

// Round 19
// 146.011 us; speedup vs baseline: 1.3743x; 1.0263x over previous
//
#include <hip/hip_runtime.h>
#include <hip/hip_fp16.h>

#define NN 50000
#define NE 800000
#define DD 256
#define DE_DIM 16
#define HH 4
#define FF 32
#define HF 128
#define OUTD 32
#define SLOPE 0.2f
#define NB_SCAN ((NN + 255) / 256)   // 196

// MFMA proj tiling
#define BM 64
#define NCOL 272
#define APAD 264
#define BTPAD 40
#define TILE_S8 1088
#define NMFMA 782                    // ceil(NN/BM)
#define NEDGEB 391                   // edge blocks (2048 edges each, 4x512)
// node_final MFMA tiling
#define NFB 64
#define FPAD 136

typedef short short8 __attribute__((ext_vector_type(8)));
typedef float f32x4 __attribute__((ext_vector_type(4)));
typedef unsigned short us4 __attribute__((ext_vector_type(4)));

// fp32 -> bf16 bits, round-to-nearest-even
__device__ __forceinline__ unsigned short bf16r(float x) {
  unsigned u = __float_as_uint(x);
  u += 0x7FFFu + ((u >> 16) & 1u);
  return (unsigned short)(u >> 16);
}
__device__ __forceinline__ float bfdec(unsigned short u) {
  return __uint_as_float(((unsigned)u) << 16);
}

// ---- Prep (merged): Btt panel + transposed W_agg/W_apply ----
__global__ __launch_bounds__(256) void prep_kernel(
    const float* __restrict__ Wsrc, const float* __restrict__ Wdst,
    const float* __restrict__ Wasrc, const float* __restrict__ Wadst,
    const float* __restrict__ W_agg, const float* __restrict__ W_apply,
    unsigned short* __restrict__ Btt,
    unsigned short* __restrict__ Wagg_t, unsigned short* __restrict__ Wapp_t)
{
  int bid = blockIdx.x;
  if (bid < NCOL) {
    int c = bid, k = threadIdx.x;
    float v = 0.f;
    if (c < 128)      v = Wsrc[(size_t)k * HF + c];
    else if (c < 256) v = Wdst[(size_t)k * HF + (c - 128)];
    else if (c < 260) v = Wasrc[(size_t)k * HH + (c - 256)];
    else if (c < 264) v = Wadst[(size_t)k * HH + (c - 260)];
    int kk = k >> 5, k5 = k & 31;
    Btt[(size_t)kk * (NCOL * 32) + c * 32 + k5] = bf16r(v);
  } else {
    int c = bid - NCOL, k = threadIdx.x;
    if (k >= 128) return;
    if (c < 128) Wagg_t[(size_t)c * HF + k] = bf16r(W_agg[(size_t)k * HF + c]);
    else         Wapp_t[(size_t)(c - 128) * HF + k] = bf16r(W_apply[(size_t)k * OUTD + (c - 128)]);
  }
}

// ---- Fused K1: blocks routed to {MFMA proj} or {edge prepass} ----
// bid%3==2 -> edge block (2048 edges, 4x512); else mfma tile (bid/3)*2+(bid%3).
// 391 edge blocks (vs 1564 in R18) so LDS-hogging edge blocks waste fewer
// CU block slots; both types co-resident from t=0.
__global__ __launch_bounds__(512) void fused_k1_kernel(
    const float* __restrict__ feat, const unsigned short* __restrict__ Btt,
    const float* __restrict__ bdst,
    unsigned short* __restrict__ fcs, unsigned short* __restrict__ fcd,
    float* __restrict__ asrc, float* __restrict__ adst,
    const float* __restrict__ feat_edge, const float* __restrict__ Wae,
    const int* __restrict__ dst_idx, int* __restrict__ cnt,
    int* __restrict__ rank, uint2* __restrict__ aebuf)
{
  __shared__ unsigned short Albuf[BM * APAD];
  __shared__ unsigned short Btbuf[2][NCOL * BTPAD];
  const int bid = blockIdx.x;
  const int tid = threadIdx.x;
  const int m3 = bid % 3;

  if (m3 == 2) {
    // ---------------- edge prepass path (2048 edges per block) ----------------
    const int eb = bid / 3;
#pragma unroll
    for (int c4 = 0; c4 < 4; ++c4) {
      int e = eb * 2048 + c4 * 512 + tid;
      if (e >= NE) break;
      float ae[HH] = {0.f, 0.f, 0.f, 0.f};
      const float4* fe4 = (const float4*)(feat_edge + (size_t)e * DE_DIM);
#pragma unroll
      for (int q = 0; q < 4; ++q) {
        float4 x = fe4[q];
        const float xs[4] = {x.x, x.y, x.z, x.w};
#pragma unroll
        for (int kk = 0; kk < 4; ++kk) {
          int k = q * 4 + kk;
#pragma unroll
          for (int h = 0; h < HH; ++h) ae[h] += xs[kk] * Wae[k * HH + h];
        }
      }
      __half2 a01 = __floats2half2_rn(ae[0], ae[1]);
      __half2 a23 = __floats2half2_rn(ae[2], ae[3]);
      uint2 u; u.x = *(unsigned*)&a01; u.y = *(unsigned*)&a23;
      aebuf[e] = u;
      rank[e] = atomicAdd(&cnt[dst_idx[e]], 1);
    }
    return;
  }

  // ---------------- MFMA projection path ----------------
  const int wave = tid >> 6, lane = tid & 63;
  const int m0 = ((bid / 3) * 2 + m3) * BM;

  for (int i = tid; i < BM * 64; i += 512) {
    int r = i >> 6, c4 = i & 63;
    int gr = m0 + r; if (gr >= NN) gr = NN - 1;
    float4 v = *(const float4*)(feat + (size_t)gr * DD + c4 * 4);
    us4 b; b.x = bf16r(v.x); b.y = bf16r(v.y); b.z = bf16r(v.z); b.w = bf16r(v.w);
    *(us4*)&Albuf[r * APAD + c4 * 4] = b;
  }

  const int ch0 = tid, ch1 = tid + 512, ch2 = tid + 1024;
  const short8* Bs8 = (const short8*)Btt;
  short8 st0, st1, st2;

  st0 = Bs8[ch0]; st1 = Bs8[ch1];
  if (ch2 < TILE_S8) st2 = Bs8[ch2];
  {
    int c, q;
    c = ch0 >> 2; q = ch0 & 3; *(short8*)&Btbuf[0][c * BTPAD + q * 8] = st0;
    c = ch1 >> 2; q = ch1 & 3; *(short8*)&Btbuf[0][c * BTPAD + q * 8] = st1;
    if (ch2 < TILE_S8) { c = ch2 >> 2; q = ch2 & 3; *(short8*)&Btbuf[0][c * BTPAD + q * 8] = st2; }
  }
  __syncthreads();

  const int r = wave >> 1, p = wave & 1;
  const int arow = r * 16 + (lane & 15);
  const int koff = (lane >> 4) * 8;
  const int cl = lane & 15;

  f32x4 acc[9];
#pragma unroll
  for (int t = 0; t < 9; ++t) acc[t] = (f32x4){0.f, 0.f, 0.f, 0.f};

  for (int kk = 0; kk < 8; ++kk) {
    const int cur = kk & 1;
    if (kk < 7) {
      const short8* src = Bs8 + (size_t)(kk + 1) * TILE_S8;
      st0 = src[ch0]; st1 = src[ch1];
      if (ch2 < TILE_S8) st2 = src[ch2];
    }
    short8 a = *(const short8*)&Albuf[arow * APAD + kk * 32 + koff];
#pragma unroll
    for (int t = 0; t < 9; ++t) {
      int c0 = p + 2 * t;
      if (c0 < 17) {
        short8 b = *(const short8*)&Btbuf[cur][(c0 * 16 + cl) * BTPAD + koff];
        acc[t] = __builtin_amdgcn_mfma_f32_16x16x32_bf16(a, b, acc[t], 0, 0, 0);
      }
    }
    if (kk < 7) {
      int c, q; const int nb = cur ^ 1;
      c = ch0 >> 2; q = ch0 & 3; *(short8*)&Btbuf[nb][c * BTPAD + q * 8] = st0;
      c = ch1 >> 2; q = ch1 & 3; *(short8*)&Btbuf[nb][c * BTPAD + q * 8] = st1;
      if (ch2 < TILE_S8) { c = ch2 >> 2; q = ch2 & 3; *(short8*)&Btbuf[nb][c * BTPAD + q * 8] = st2; }
    }
    __syncthreads();
  }

  const int rbase = m0 + r * 16 + (lane >> 4) * 4;
#pragma unroll
  for (int t = 0; t < 9; ++t) {
    int c0 = p + 2 * t;
    if (c0 >= 17) break;
    int gcol = c0 * 16 + cl;
#pragma unroll
    for (int j = 0; j < 4; ++j) {
      int grow = rbase + j;
      if (grow >= NN) continue;
      float v = acc[t][j];
      if (gcol < 128)      fcs[(size_t)grow * HF + gcol] = bf16r(v);
      else if (gcol < 256) fcd[(size_t)grow * HF + (gcol - 128)] = bf16r(v + bdst[gcol - 128]);
      else if (gcol < 260) asrc[(size_t)grow * HH + (gcol - 256)] = v;
      else if (gcol < 264) adst[(size_t)grow * HH + (gcol - 260)] = v;
    }
  }
}

// ---- CSR scan ----
__global__ __launch_bounds__(256) void scan_block_kernel(
    const int* __restrict__ cnt, int* __restrict__ offs, int* __restrict__ bsum)
{
  __shared__ int tmp[256];
  int t = threadIdx.x;
  int i = blockIdx.x * 256 + t;
  int v = (i < NN) ? cnt[i] : 0;
  tmp[t] = v;
  __syncthreads();
  for (int ofs = 1; ofs < 256; ofs <<= 1) {
    int add = (t >= ofs) ? tmp[t - ofs] : 0;
    __syncthreads();
    tmp[t] += add;
    __syncthreads();
  }
  if (i < NN) offs[i] = tmp[t] - v;
  if (t == 255) bsum[blockIdx.x] = tmp[255];
}

__global__ __launch_bounds__(256) void scan_bsum_kernel(
    const int* __restrict__ bsum, int* __restrict__ boff)
{
  __shared__ int tmp[256];
  int t = threadIdx.x;
  int v = (t < NB_SCAN) ? bsum[t] : 0;
  tmp[t] = v;
  __syncthreads();
  for (int ofs = 1; ofs < 256; ofs <<= 1) {
    int add = (t >= ofs) ? tmp[t - ofs] : 0;
    __syncthreads();
    tmp[t] += add;
    __syncthreads();
  }
  if (t < NB_SCAN) boff[t] = tmp[t] - v;
}

__global__ __launch_bounds__(256) void scan_final_kernel(
    int* __restrict__ offs, const int* __restrict__ boff)
{
  int i = blockIdx.x * 256 + threadIdx.x;
  if (i < NN) offs[i] += boff[blockIdx.x];
  if (i == 0) offs[NN] = NE;
}

// ---- scatter record: streamed reads + L2-resident gathers; only the
// 16B record store is random ----
__global__ __launch_bounds__(256) void scatter_rec_kernel(
    const int* __restrict__ src_idx, const int* __restrict__ dst_idx,
    const float* __restrict__ asrc, const float* __restrict__ adst,
    const int* __restrict__ offs, const int* __restrict__ rank,
    const uint2* __restrict__ aebuf, int4* __restrict__ sorted)
{
  int e = blockIdx.x * 256 + threadIdx.x;
  if (e >= NE) return;
  int s = src_idx[e], d = dst_idx[e];

  uint2 u = aebuf[e];
  __half2 a01 = *(__half2*)&u.x;
  __half2 a23 = *(__half2*)&u.y;
  float ae[4];
  ae[0] = __low2float(a01); ae[1] = __high2float(a01);
  ae[2] = __low2float(a23); ae[3] = __high2float(a23);

  float as[4], ad[4];
  *(float4*)as = *(const float4*)(asrc + (size_t)s * 4);
  *(float4*)ad = *(const float4*)(adst + (size_t)d * 4);

  float ev[4];
#pragma unroll
  for (int h = 0; h < HH; ++h) {
    float v = as[h] + ad[h] + ae[h];
    ev[h] = v >= 0.f ? v : SLOPE * v;
  }
  __half2 p01 = __floats2half2_rn(ev[0], ev[1]);
  __half2 p23 = __floats2half2_rn(ev[2], ev[3]);
  int4 rec;
  rec.x = s;
  rec.y = *(int*)&p01;
  rec.z = *(int*)&p23;
  rec.w = 0;
  sorted[offs[d] + rank[e]] = rec;
}

// ---- fused softmax+agg: one wave per dst, no max pass (R12-verified) ----
__global__ __launch_bounds__(64) void agg_fused_kernel(
    const int* __restrict__ offs, const int4* __restrict__ sorted,
    const unsigned short* __restrict__ fcs, unsigned short* __restrict__ h_out)
{
  const int d = blockIdx.x;
  const int t = threadIdx.x;        // 0..63
  const int fpair = t << 1;
  const int h = t >> 4;
  const int beg = offs[d], end = offs[d + 1];
  const bool hiw = (h & 1);
  const bool hi2 = (h & 2);

  float ssum = 0.f, accx = 0.f, accy = 0.f;

  auto dec = [&](int4 r) -> float {
    int ew = hi2 ? r.z : r.y;
    __half2 hp = *(__half2*)&ew;
    return hiw ? __high2float(hp) : __low2float(hp);
  };

  int p = beg;
  for (; p + 4 <= end; p += 4) {
    int4 r0 = sorted[p + 0];
    int4 r1 = sorted[p + 1];
    int4 r2 = sorted[p + 2];
    int4 r3 = sorted[p + 3];
    unsigned f0 = *(const unsigned*)&fcs[(size_t)r0.x * HF + fpair];
    unsigned f1 = *(const unsigned*)&fcs[(size_t)r1.x * HF + fpair];
    unsigned f2 = *(const unsigned*)&fcs[(size_t)r2.x * HF + fpair];
    unsigned f3 = *(const unsigned*)&fcs[(size_t)r3.x * HF + fpair];
    float z0 = __expf(dec(r0));
    float z1 = __expf(dec(r1));
    float z2 = __expf(dec(r2));
    float z3 = __expf(dec(r3));
    ssum += (z0 + z1) + (z2 + z3);
    accx += bfdec((unsigned short)(f0 & 0xffff)) * z0
          + bfdec((unsigned short)(f1 & 0xffff)) * z1
          + bfdec((unsigned short)(f2 & 0xffff)) * z2
          + bfdec((unsigned short)(f3 & 0xffff)) * z3;
    accy += bfdec((unsigned short)(f0 >> 16)) * z0
          + bfdec((unsigned short)(f1 >> 16)) * z1
          + bfdec((unsigned short)(f2 >> 16)) * z2
          + bfdec((unsigned short)(f3 >> 16)) * z3;
  }
  for (; p < end; ++p) {
    int4 r0 = sorted[p];
    unsigned f0 = *(const unsigned*)&fcs[(size_t)r0.x * HF + fpair];
    float z = __expf(dec(r0));
    ssum += z;
    accx += bfdec((unsigned short)(f0 & 0xffff)) * z;
    accy += bfdec((unsigned short)(f0 >> 16)) * z;
  }
  float inv = (end > beg) ? 1.f / ssum : 0.f;
  ushort2 st;
  st.x = bf16r(accx * inv);
  st.y = bf16r(accy * inv);
  *(ushort2*)&h_out[(size_t)d * HF + fpair] = st;
}

// ---- Kernel 5: shuffle-free LN + MFMA(W_agg) + residual + MFMA(W_apply) ----
__global__ __launch_bounds__(256) void node_final_mfma_kernel(
    const unsigned short* __restrict__ h_in, const float* __restrict__ scale,
    const float* __restrict__ offset,
    const unsigned short* __restrict__ Wagg_t, const float* __restrict__ b_agg,
    const unsigned short* __restrict__ fcd,
    const unsigned short* __restrict__ Wapp_t, const float* __restrict__ b_apply,
    float* __restrict__ out)
{
  __shared__ unsigned short Abuf[NFB * FPAD];     // 17408 B (also holds A2)
  __shared__ unsigned short Bagg[HF * FPAD];      // 34816 B
  const int tid = threadIdx.x;
  const int wave = tid >> 6, lane = tid & 63;
  const int n0 = blockIdx.x * NFB;

  for (int i = tid; i < HF * 16; i += 256) {
    int c = i >> 4, q = i & 15;
    *(short8*)&Bagg[c * FPAD + q * 8] = *(const short8*)(Wagg_t + (size_t)c * HF + q * 8);
  }

  {
    const int r = tid >> 2, h = tid & 3;
    int node = n0 + r; if (node >= NN) node = NN - 1;
    const short8* hp = (const short8*)(h_in + (size_t)node * HF + h * 32);
    short8 v0 = hp[0], v1 = hp[1], v2 = hp[2], v3 = hp[3];

    float x[32];
#pragma unroll
    for (int j = 0; j < 8; ++j) {
      x[j]      = bfdec((unsigned short)v0[j]);
      x[8 + j]  = bfdec((unsigned short)v1[j]);
      x[16 + j] = bfdec((unsigned short)v2[j]);
      x[24 + j] = bfdec((unsigned short)v3[j]);
    }
    float sum = 0.f;
#pragma unroll
    for (int j = 0; j < 32; ++j) sum += x[j];
    float mean = sum * (1.f / 32.f);
    float sq = 0.f;
#pragma unroll
    for (int j = 0; j < 32; ++j) { float dv = x[j] - mean; sq += dv * dv; }
    float rsig = rsqrtf(sq * (1.f / 32.f) + 1e-9f);

#pragma unroll
    for (int c = 0; c < 4; ++c) {
      float4 s0 = *(const float4*)&scale[h * 32 + c * 8];
      float4 s1 = *(const float4*)&scale[h * 32 + c * 8 + 4];
      float4 o0 = *(const float4*)&offset[h * 32 + c * 8];
      float4 o1 = *(const float4*)&offset[h * 32 + c * 8 + 4];
      const float ss[8] = {s0.x, s0.y, s0.z, s0.w, s1.x, s1.y, s1.z, s1.w};
      const float oo[8] = {o0.x, o0.y, o0.z, o0.w, o1.x, o1.y, o1.z, o1.w};
      short8 w;
#pragma unroll
      for (int j = 0; j < 8; ++j)
        w[j] = (short)bf16r((x[c * 8 + j] - mean) * ss[j] * rsig + oo[j]);
      *(short8*)&Abuf[r * FPAD + h * 32 + c * 8] = w;
    }
  }
  __syncthreads();

  const int arow = wave * 16 + (lane & 15);
  const int koff = (lane >> 4) * 8;
  const int rbase = wave * 16 + (lane >> 4) * 4;
  const int cl = lane & 15;

  f32x4 acc1[8];
#pragma unroll
  for (int c0 = 0; c0 < 8; ++c0) acc1[c0] = (f32x4){0.f, 0.f, 0.f, 0.f};
#pragma unroll
  for (int ks = 0; ks < 4; ++ks) {
    short8 a = *(const short8*)&Abuf[arow * FPAD + ks * 32 + koff];
#pragma unroll
    for (int c0 = 0; c0 < 8; ++c0) {
      short8 b = *(const short8*)&Bagg[(c0 * 16 + cl) * FPAD + ks * 32 + koff];
      acc1[c0] = __builtin_amdgcn_mfma_f32_16x16x32_bf16(a, b, acc1[c0], 0, 0, 0);
    }
  }

#pragma unroll
  for (int c0 = 0; c0 < 8; ++c0) {
    int gcol = c0 * 16 + cl;
    float bg = b_agg[gcol];
#pragma unroll
    for (int j = 0; j < 4; ++j) {
      int row = rbase + j;
      int grow = n0 + row;
      float fd = (grow < NN) ? bfdec(fcd[(size_t)grow * HF + gcol]) : 0.f;
      float r = acc1[c0][j] + bg + fd;
      Abuf[row * FPAD + gcol] = bf16r(r >= 0.f ? r : SLOPE * r);
    }
  }
  // no barrier: Abuf rows are wave-private

  f32x4 acc2[2];
#pragma unroll
  for (int c0 = 0; c0 < 2; ++c0) acc2[c0] = (f32x4){0.f, 0.f, 0.f, 0.f};
#pragma unroll
  for (int ks = 0; ks < 4; ++ks) {
    short8 a = *(const short8*)&Abuf[arow * FPAD + ks * 32 + koff];
#pragma unroll
    for (int c0 = 0; c0 < 2; ++c0) {
      short8 b = *(const short8*)(Wapp_t + (size_t)(c0 * 16 + cl) * HF + ks * 32 + koff);
      acc2[c0] = __builtin_amdgcn_mfma_f32_16x16x32_bf16(a, b, acc2[c0], 0, 0, 0);
    }
  }
#pragma unroll
  for (int c0 = 0; c0 < 2; ++c0) {
    int gcol = c0 * 16 + cl;
    float ba = b_apply[gcol];
#pragma unroll
    for (int j = 0; j < 4; ++j) {
      int grow = n0 + rbase + j;
      if (grow < NN) out[(size_t)grow * OUTD + gcol] = acc2[c0][j] + ba;
    }
  }
}

extern "C" void kernel_launch(void* const* d_in, const int* in_sizes, int n_in,
                              void* d_out, int out_size, void* d_ws, size_t ws_size,
                              hipStream_t stream)
{
  const float* feat_src    = (const float*)d_in[0];
  const float* feat_edge   = (const float*)d_in[1];
  const int*   src_idx     = (const int*)d_in[2];
  const int*   dst_idx     = (const int*)d_in[3];
  const float* W_src       = (const float*)d_in[4];
  const float* W_attn_src  = (const float*)d_in[5];
  const float* W_attn_dst  = (const float*)d_in[6];
  const float* W_attn_edge = (const float*)d_in[7];
  const float* scale       = (const float*)d_in[8];
  const float* offset      = (const float*)d_in[9];
  const float* W_agg       = (const float*)d_in[10];
  const float* b_agg       = (const float*)d_in[11];
  const float* W_dst       = (const float*)d_in[12];
  const float* b_dst       = (const float*)d_in[13];
  const float* W_apply     = (const float*)d_in[14];
  const float* b_apply     = (const float*)d_in[15];
  float* out = (float*)d_out;

  char* ws = (char*)d_ws;
  size_t off = 0;
  auto take = [&](size_t bytes) {
    size_t o = off;
    off = (off + bytes + 255) & ~(size_t)255;
    return o;
  };
  size_t fcs_off    = take((size_t)NN * HF * 2);      // bf16
  size_t fcd_off    = take((size_t)NN * HF * 2);      // bf16 (bias folded)
  size_t asrc_off   = take((size_t)NN * 4 * 4);
  size_t adst_off   = take((size_t)NN * 4 * 4);
  size_t bt_off     = take((size_t)NCOL * DD * 2);
  size_t wagg_off   = take((size_t)HF * HF * 2);
  size_t wapp_off   = take((size_t)OUTD * HF * 2);
  size_t cnt_off    = take((size_t)NN * 4);           // zeroed
  size_t offs_off   = take((size_t)(NN + 1) * 4);
  size_t bsum_off   = take((size_t)NB_SCAN * 4);
  size_t boff_off   = take((size_t)NB_SCAN * 4);
  size_t rank_off   = take((size_t)NE * 4);
  size_t ae_off     = take((size_t)NE * 8);           // fp16x4 per edge
  size_t sorted_off = take((size_t)NE * 16);
  size_t hout_off   = take((size_t)NN * HF * 2);      // bf16
  if (ws_size < off) return;

  unsigned short* fcs    = (unsigned short*)(ws + fcs_off);
  unsigned short* fcd    = (unsigned short*)(ws + fcd_off);
  float*          asrc   = (float*)(ws + asrc_off);
  float*          adst   = (float*)(ws + adst_off);
  unsigned short* Btt    = (unsigned short*)(ws + bt_off);
  unsigned short* Wagg_t = (unsigned short*)(ws + wagg_off);
  unsigned short* Wapp_t = (unsigned short*)(ws + wapp_off);
  int*            cnt    = (int*)(ws + cnt_off);
  int*            offs   = (int*)(ws + offs_off);
  int*            bsum   = (int*)(ws + bsum_off);
  int*            boff   = (int*)(ws + boff_off);
  int*            rank   = (int*)(ws + rank_off);
  uint2*          aebuf  = (uint2*)(ws + ae_off);
  int4*           sorted = (int4*)(ws + sorted_off);
  unsigned short* h_out  = (unsigned short*)(ws + hout_off);

  hipMemsetAsync(ws + cnt_off, 0, (size_t)NN * 4, stream);

  prep_kernel<<<NCOL + 160, 256, 0, stream>>>(
      W_src, W_dst, W_attn_src, W_attn_dst, W_agg, W_apply,
      Btt, Wagg_t, Wapp_t);

  fused_k1_kernel<<<NMFMA + NEDGEB, 512, 0, stream>>>(
      feat_src, Btt, b_dst, fcs, fcd, asrc, adst,
      feat_edge, W_attn_edge, dst_idx, cnt, rank, aebuf);

  scan_block_kernel<<<NB_SCAN, 256, 0, stream>>>(cnt, offs, bsum);
  scan_bsum_kernel<<<1, 256, 0, stream>>>(bsum, boff);
  scan_final_kernel<<<NB_SCAN, 256, 0, stream>>>(offs, boff);

  scatter_rec_kernel<<<(NE + 255) / 256, 256, 0, stream>>>(
      src_idx, dst_idx, asrc, adst, offs, rank, aebuf, sorted);

  agg_fused_kernel<<<NN, 64, 0, stream>>>(offs, sorted, fcs, h_out);

  node_final_mfma_kernel<<<(NN + NFB - 1) / NFB, 256, 0, stream>>>(
      h_out, scale, offset, Wagg_t, b_agg, fcd, Wapp_t, b_apply, out);
}

// Round 21
// 145.517 us; speedup vs baseline: 1.3789x; 1.0034x over previous
//
#include <hip/hip_runtime.h>
#include <hip/hip_fp16.h>

#define NN 50000
#define NE 800000
#define DD 256
#define DE_DIM 16
#define HH 4
#define FF 32
#define HF 128
#define OUTD 32
#define SLOPE 0.2f
#define NB_SCAN ((NN + 255) / 256)   // 196

// MFMA proj tiling
#define BM 64
#define NCOL 272
#define APAD 264
#define BTPAD 40
#define TILE_S8 1088
#define NMFMA 782                    // ceil(NN/BM)
#define NEDGEB 391                   // edge blocks (2048 edges each, 4x512)
// node_final MFMA tiling
#define NFB 64
#define FPAD 136

typedef short short8 __attribute__((ext_vector_type(8)));
typedef float f32x4 __attribute__((ext_vector_type(4)));
typedef unsigned short us4 __attribute__((ext_vector_type(4)));

// fp32 -> bf16 bits, round-to-nearest-even
__device__ __forceinline__ unsigned short bf16r(float x) {
  unsigned u = __float_as_uint(x);
  u += 0x7FFFu + ((u >> 16) & 1u);
  return (unsigned short)(u >> 16);
}
__device__ __forceinline__ float bfdec(unsigned short u) {
  return __uint_as_float(((unsigned)u) << 16);
}

// ---- Prep (merged): Btt panel + transposed W_agg/W_apply ----
__global__ __launch_bounds__(256) void prep_kernel(
    const float* __restrict__ Wsrc, const float* __restrict__ Wdst,
    const float* __restrict__ Wasrc, const float* __restrict__ Wadst,
    const float* __restrict__ W_agg, const float* __restrict__ W_apply,
    unsigned short* __restrict__ Btt,
    unsigned short* __restrict__ Wagg_t, unsigned short* __restrict__ Wapp_t)
{
  int bid = blockIdx.x;
  if (bid < NCOL) {
    int c = bid, k = threadIdx.x;
    float v = 0.f;
    if (c < 128)      v = Wsrc[(size_t)k * HF + c];
    else if (c < 256) v = Wdst[(size_t)k * HF + (c - 128)];
    else if (c < 260) v = Wasrc[(size_t)k * HH + (c - 256)];
    else if (c < 264) v = Wadst[(size_t)k * HH + (c - 260)];
    int kk = k >> 5, k5 = k & 31;
    Btt[(size_t)kk * (NCOL * 32) + c * 32 + k5] = bf16r(v);
  } else {
    int c = bid - NCOL, k = threadIdx.x;
    if (k >= 128) return;
    if (c < 128) Wagg_t[(size_t)c * HF + k] = bf16r(W_agg[(size_t)k * HF + c]);
    else         Wapp_t[(size_t)(c - 128) * HF + k] = bf16r(W_apply[(size_t)k * OUTD + (c - 128)]);
  }
}

// ---- Fused K1: blocks routed to {MFMA proj} or {edge prepass} ----
// bid%3==2 -> edge block (2048 edges, 4x512); else mfma tile (bid/3)*2+(bid%3).
__global__ __launch_bounds__(512) void fused_k1_kernel(
    const float* __restrict__ feat, const unsigned short* __restrict__ Btt,
    const float* __restrict__ bdst,
    unsigned short* __restrict__ fcs, unsigned short* __restrict__ fcd,
    float* __restrict__ asrc, float* __restrict__ adst,
    const float* __restrict__ feat_edge, const float* __restrict__ Wae,
    const int* __restrict__ dst_idx, int* __restrict__ cnt,
    int* __restrict__ rank, uint2* __restrict__ aebuf)
{
  __shared__ unsigned short Albuf[BM * APAD];
  __shared__ unsigned short Btbuf[2][NCOL * BTPAD];
  const int bid = blockIdx.x;
  const int tid = threadIdx.x;
  const int m3 = bid % 3;

  if (m3 == 2) {
    // ---------------- edge prepass path (2048 edges per block) ----------------
    const int eb = bid / 3;
#pragma unroll
    for (int c4 = 0; c4 < 4; ++c4) {
      int e = eb * 2048 + c4 * 512 + tid;
      if (e >= NE) break;
      float ae[HH] = {0.f, 0.f, 0.f, 0.f};
      const float4* fe4 = (const float4*)(feat_edge + (size_t)e * DE_DIM);
#pragma unroll
      for (int q = 0; q < 4; ++q) {
        float4 x = fe4[q];
        const float xs[4] = {x.x, x.y, x.z, x.w};
#pragma unroll
        for (int kk = 0; kk < 4; ++kk) {
          int k = q * 4 + kk;
#pragma unroll
          for (int h = 0; h < HH; ++h) ae[h] += xs[kk] * Wae[k * HH + h];
        }
      }
      __half2 a01 = __floats2half2_rn(ae[0], ae[1]);
      __half2 a23 = __floats2half2_rn(ae[2], ae[3]);
      uint2 u; u.x = *(unsigned*)&a01; u.y = *(unsigned*)&a23;
      aebuf[e] = u;
      rank[e] = atomicAdd(&cnt[dst_idx[e]], 1);
    }
    return;
  }

  // ---------------- MFMA projection path ----------------
  const int wave = tid >> 6, lane = tid & 63;
  const int m0 = ((bid / 3) * 2 + m3) * BM;

  for (int i = tid; i < BM * 64; i += 512) {
    int r = i >> 6, c4 = i & 63;
    int gr = m0 + r; if (gr >= NN) gr = NN - 1;
    float4 v = *(const float4*)(feat + (size_t)gr * DD + c4 * 4);
    us4 b; b.x = bf16r(v.x); b.y = bf16r(v.y); b.z = bf16r(v.z); b.w = bf16r(v.w);
    *(us4*)&Albuf[r * APAD + c4 * 4] = b;
  }

  const int ch0 = tid, ch1 = tid + 512, ch2 = tid + 1024;
  const short8* Bs8 = (const short8*)Btt;
  short8 st0, st1, st2;

  st0 = Bs8[ch0]; st1 = Bs8[ch1];
  if (ch2 < TILE_S8) st2 = Bs8[ch2];
  {
    int c, q;
    c = ch0 >> 2; q = ch0 & 3; *(short8*)&Btbuf[0][c * BTPAD + q * 8] = st0;
    c = ch1 >> 2; q = ch1 & 3; *(short8*)&Btbuf[0][c * BTPAD + q * 8] = st1;
    if (ch2 < TILE_S8) { c = ch2 >> 2; q = ch2 & 3; *(short8*)&Btbuf[0][c * BTPAD + q * 8] = st2; }
  }
  __syncthreads();

  const int r = wave >> 1, p = wave & 1;
  const int arow = r * 16 + (lane & 15);
  const int koff = (lane >> 4) * 8;
  const int cl = lane & 15;

  f32x4 acc[9];
#pragma unroll
  for (int t = 0; t < 9; ++t) acc[t] = (f32x4){0.f, 0.f, 0.f, 0.f};

  for (int kk = 0; kk < 8; ++kk) {
    const int cur = kk & 1;
    if (kk < 7) {
      const short8* src = Bs8 + (size_t)(kk + 1) * TILE_S8;
      st0 = src[ch0]; st1 = src[ch1];
      if (ch2 < TILE_S8) st2 = src[ch2];
    }
    short8 a = *(const short8*)&Albuf[arow * APAD + kk * 32 + koff];
#pragma unroll
    for (int t = 0; t < 9; ++t) {
      int c0 = p + 2 * t;
      if (c0 < 17) {
        short8 b = *(const short8*)&Btbuf[cur][(c0 * 16 + cl) * BTPAD + koff];
        acc[t] = __builtin_amdgcn_mfma_f32_16x16x32_bf16(a, b, acc[t], 0, 0, 0);
      }
    }
    if (kk < 7) {
      int c, q; const int nb = cur ^ 1;
      c = ch0 >> 2; q = ch0 & 3; *(short8*)&Btbuf[nb][c * BTPAD + q * 8] = st0;
      c = ch1 >> 2; q = ch1 & 3; *(short8*)&Btbuf[nb][c * BTPAD + q * 8] = st1;
      if (ch2 < TILE_S8) { c = ch2 >> 2; q = ch2 & 3; *(short8*)&Btbuf[nb][c * BTPAD + q * 8] = st2; }
    }
    __syncthreads();
  }

  const int rbase = m0 + r * 16 + (lane >> 4) * 4;
#pragma unroll
  for (int t = 0; t < 9; ++t) {
    int c0 = p + 2 * t;
    if (c0 >= 17) break;
    int gcol = c0 * 16 + cl;
#pragma unroll
    for (int j = 0; j < 4; ++j) {
      int grow = rbase + j;
      if (grow >= NN) continue;
      float v = acc[t][j];
      if (gcol < 128)      fcs[(size_t)grow * HF + gcol] = bf16r(v);
      else if (gcol < 256) fcd[(size_t)grow * HF + (gcol - 128)] = bf16r(v + bdst[gcol - 128]);
      else if (gcol < 260) asrc[(size_t)grow * HH + (gcol - 256)] = v;
      else if (gcol < 264) adst[(size_t)grow * HH + (gcol - 260)] = v;
    }
  }
}

// ---- CSR scan ----
__global__ __launch_bounds__(256) void scan_block_kernel(
    const int* __restrict__ cnt, int* __restrict__ offs, int* __restrict__ bsum)
{
  __shared__ int tmp[256];
  int t = threadIdx.x;
  int i = blockIdx.x * 256 + t;
  int v = (i < NN) ? cnt[i] : 0;
  tmp[t] = v;
  __syncthreads();
  for (int ofs = 1; ofs < 256; ofs <<= 1) {
    int add = (t >= ofs) ? tmp[t - ofs] : 0;
    __syncthreads();
    tmp[t] += add;
    __syncthreads();
  }
  if (i < NN) offs[i] = tmp[t] - v;
  if (t == 255) bsum[blockIdx.x] = tmp[255];
}

__global__ __launch_bounds__(256) void scan_bsum_kernel(
    const int* __restrict__ bsum, int* __restrict__ boff)
{
  __shared__ int tmp[256];
  int t = threadIdx.x;
  int v = (t < NB_SCAN) ? bsum[t] : 0;
  tmp[t] = v;
  __syncthreads();
  for (int ofs = 1; ofs < 256; ofs <<= 1) {
    int add = (t >= ofs) ? tmp[t - ofs] : 0;
    __syncthreads();
    tmp[t] += add;
    __syncthreads();
  }
  if (t < NB_SCAN) boff[t] = tmp[t] - v;
}

__global__ __launch_bounds__(256) void scan_final_kernel(
    int* __restrict__ offs, const int* __restrict__ boff)
{
  int i = blockIdx.x * 256 + threadIdx.x;
  if (i < NN) offs[i] += boff[blockIdx.x];
  if (i == 0) offs[NN] = NE;
}

// ---- scatter record: streamed reads + L2-resident gathers; only the
// 16B record store is random ----
__global__ __launch_bounds__(256) void scatter_rec_kernel(
    const int* __restrict__ src_idx, const int* __restrict__ dst_idx,
    const float* __restrict__ asrc, const float* __restrict__ adst,
    const int* __restrict__ offs, const int* __restrict__ rank,
    const uint2* __restrict__ aebuf, int4* __restrict__ sorted)
{
  int e = blockIdx.x * 256 + threadIdx.x;
  if (e >= NE) return;
  int s = src_idx[e], d = dst_idx[e];

  uint2 u = aebuf[e];
  __half2 a01 = *(__half2*)&u.x;
  __half2 a23 = *(__half2*)&u.y;
  float ae[4];
  ae[0] = __low2float(a01); ae[1] = __high2float(a01);
  ae[2] = __low2float(a23); ae[3] = __high2float(a23);

  float as[4], ad[4];
  *(float4*)as = *(const float4*)(asrc + (size_t)s * 4);
  *(float4*)ad = *(const float4*)(adst + (size_t)d * 4);

  float ev[4];
#pragma unroll
  for (int h = 0; h < HH; ++h) {
    float v = as[h] + ad[h] + ae[h];
    ev[h] = v >= 0.f ? v : SLOPE * v;
  }
  __half2 p01 = __floats2half2_rn(ev[0], ev[1]);
  __half2 p23 = __floats2half2_rn(ev[2], ev[3]);
  int4 rec;
  rec.x = s;
  rec.y = *(int*)&p01;
  rec.z = *(int*)&p23;
  rec.w = 0;
  sorted[offs[d] + rank[e]] = rec;
}

// ---- fused softmax+agg: one wave per dst, no max pass (R12-verified) ----
__global__ __launch_bounds__(64) void agg_fused_kernel(
    const int* __restrict__ offs, const int4* __restrict__ sorted,
    const unsigned short* __restrict__ fcs, unsigned short* __restrict__ h_out)
{
  const int d = blockIdx.x;
  const int t = threadIdx.x;        // 0..63
  const int fpair = t << 1;
  const int h = t >> 4;
  const int beg = offs[d], end = offs[d + 1];
  const bool hiw = (h & 1);
  const bool hi2 = (h & 2);

  float ssum = 0.f, accx = 0.f, accy = 0.f;

  auto dec = [&](int4 r) -> float {
    int ew = hi2 ? r.z : r.y;
    __half2 hp = *(__half2*)&ew;
    return hiw ? __high2float(hp) : __low2float(hp);
  };

  int p = beg;
  for (; p + 4 <= end; p += 4) {
    int4 r0 = sorted[p + 0];
    int4 r1 = sorted[p + 1];
    int4 r2 = sorted[p + 2];
    int4 r3 = sorted[p + 3];
    unsigned f0 = *(const unsigned*)&fcs[(size_t)r0.x * HF + fpair];
    unsigned f1 = *(const unsigned*)&fcs[(size_t)r1.x * HF + fpair];
    unsigned f2 = *(const unsigned*)&fcs[(size_t)r2.x * HF + fpair];
    unsigned f3 = *(const unsigned*)&fcs[(size_t)r3.x * HF + fpair];
    float z0 = __expf(dec(r0));
    float z1 = __expf(dec(r1));
    float z2 = __expf(dec(r2));
    float z3 = __expf(dec(r3));
    ssum += (z0 + z1) + (z2 + z3);
    accx += bfdec((unsigned short)(f0 & 0xffff)) * z0
          + bfdec((unsigned short)(f1 & 0xffff)) * z1
          + bfdec((unsigned short)(f2 & 0xffff)) * z2
          + bfdec((unsigned short)(f3 & 0xffff)) * z3;
    accy += bfdec((unsigned short)(f0 >> 16)) * z0
          + bfdec((unsigned short)(f1 >> 16)) * z1
          + bfdec((unsigned short)(f2 >> 16)) * z2
          + bfdec((unsigned short)(f3 >> 16)) * z3;
  }
  for (; p < end; ++p) {
    int4 r0 = sorted[p];
    unsigned f0 = *(const unsigned*)&fcs[(size_t)r0.x * HF + fpair];
    float z = __expf(dec(r0));
    ssum += z;
    accx += bfdec((unsigned short)(f0 & 0xffff)) * z;
    accy += bfdec((unsigned short)(f0 >> 16)) * z;
  }
  float inv = (end > beg) ? 1.f / ssum : 0.f;
  ushort2 st;
  st.x = bf16r(accx * inv);
  st.y = bf16r(accy * inv);
  *(ushort2*)&h_out[(size_t)d * HF + fpair] = st;
}

// ---- Kernel 5: shuffle-free LN + MFMA(W_agg) + residual + MFMA(W_apply) ----
__global__ __launch_bounds__(256) void node_final_mfma_kernel(
    const unsigned short* __restrict__ h_in, const float* __restrict__ scale,
    const float* __restrict__ offset,
    const unsigned short* __restrict__ Wagg_t, const float* __restrict__ b_agg,
    const unsigned short* __restrict__ fcd,
    const unsigned short* __restrict__ Wapp_t, const float* __restrict__ b_apply,
    float* __restrict__ out)
{
  __shared__ unsigned short Abuf[NFB * FPAD];     // 17408 B (also holds A2)
  __shared__ unsigned short Bagg[HF * FPAD];      // 34816 B
  const int tid = threadIdx.x;
  const int wave = tid >> 6, lane = tid & 63;
  const int n0 = blockIdx.x * NFB;

  for (int i = tid; i < HF * 16; i += 256) {
    int c = i >> 4, q = i & 15;
    *(short8*)&Bagg[c * FPAD + q * 8] = *(const short8*)(Wagg_t + (size_t)c * HF + q * 8);
  }

  {
    const int r = tid >> 2, h = tid & 3;
    int node = n0 + r; if (node >= NN) node = NN - 1;
    const short8* hp = (const short8*)(h_in + (size_t)node * HF + h * 32);
    short8 v0 = hp[0], v1 = hp[1], v2 = hp[2], v3 = hp[3];

    float x[32];
#pragma unroll
    for (int j = 0; j < 8; ++j) {
      x[j]      = bfdec((unsigned short)v0[j]);
      x[8 + j]  = bfdec((unsigned short)v1[j]);
      x[16 + j] = bfdec((unsigned short)v2[j]);
      x[24 + j] = bfdec((unsigned short)v3[j]);
    }
    float sum = 0.f;
#pragma unroll
    for (int j = 0; j < 32; ++j) sum += x[j];
    float mean = sum * (1.f / 32.f);
    float sq = 0.f;
#pragma unroll
    for (int j = 0; j < 32; ++j) { float dv = x[j] - mean; sq += dv * dv; }
    float rsig = rsqrtf(sq * (1.f / 32.f) + 1e-9f);

#pragma unroll
    for (int c = 0; c < 4; ++c) {
      float4 s0 = *(const float4*)&scale[h * 32 + c * 8];
      float4 s1 = *(const float4*)&scale[h * 32 + c * 8 + 4];
      float4 o0 = *(const float4*)&offset[h * 32 + c * 8];
      float4 o1 = *(const float4*)&offset[h * 32 + c * 8 + 4];
      const float ss[8] = {s0.x, s0.y, s0.z, s0.w, s1.x, s1.y, s1.z, s1.w};
      const float oo[8] = {o0.x, o0.y, o0.z, o0.w, o1.x, o1.y, o1.z, o1.w};
      short8 w;
#pragma unroll
      for (int j = 0; j < 8; ++j)
        w[j] = (short)bf16r((x[c * 8 + j] - mean) * ss[j] * rsig + oo[j]);
      *(short8*)&Abuf[r * FPAD + h * 32 + c * 8] = w;
    }
  }
  __syncthreads();

  const int arow = wave * 16 + (lane & 15);
  const int koff = (lane >> 4) * 8;
  const int rbase = wave * 16 + (lane >> 4) * 4;
  const int cl = lane & 15;

  f32x4 acc1[8];
#pragma unroll
  for (int c0 = 0; c0 < 8; ++c0) acc1[c0] = (f32x4){0.f, 0.f, 0.f, 0.f};
#pragma unroll
  for (int ks = 0; ks < 4; ++ks) {
    short8 a = *(const short8*)&Abuf[arow * FPAD + ks * 32 + koff];
#pragma unroll
    for (int c0 = 0; c0 < 8; ++c0) {
      short8 b = *(const short8*)&Bagg[(c0 * 16 + cl) * FPAD + ks * 32 + koff];
      acc1[c0] = __builtin_amdgcn_mfma_f32_16x16x32_bf16(a, b, acc1[c0], 0, 0, 0);
    }
  }

#pragma unroll
  for (int c0 = 0; c0 < 8; ++c0) {
    int gcol = c0 * 16 + cl;
    float bg = b_agg[gcol];
#pragma unroll
    for (int j = 0; j < 4; ++j) {
      int row = rbase + j;
      int grow = n0 + row;
      float fd = (grow < NN) ? bfdec(fcd[(size_t)grow * HF + gcol]) : 0.f;
      float r = acc1[c0][j] + bg + fd;
      Abuf[row * FPAD + gcol] = bf16r(r >= 0.f ? r : SLOPE * r);
    }
  }
  // no barrier: Abuf rows are wave-private

  f32x4 acc2[2];
#pragma unroll
  for (int c0 = 0; c0 < 2; ++c0) acc2[c0] = (f32x4){0.f, 0.f, 0.f, 0.f};
#pragma unroll
  for (int ks = 0; ks < 4; ++ks) {
    short8 a = *(const short8*)&Abuf[arow * FPAD + ks * 32 + koff];
#pragma unroll
    for (int c0 = 0; c0 < 2; ++c0) {
      short8 b = *(const short8*)(Wapp_t + (size_t)(c0 * 16 + cl) * HF + ks * 32 + koff);
      acc2[c0] = __builtin_amdgcn_mfma_f32_16x16x32_bf16(a, b, acc2[c0], 0, 0, 0);
    }
  }
#pragma unroll
  for (int c0 = 0; c0 < 2; ++c0) {
    int gcol = c0 * 16 + cl;
    float ba = b_apply[gcol];
#pragma unroll
    for (int j = 0; j < 4; ++j) {
      int grow = n0 + rbase + j;
      if (grow < NN) out[(size_t)grow * OUTD + gcol] = acc2[c0][j] + ba;
    }
  }
}

extern "C" void kernel_launch(void* const* d_in, const int* in_sizes, int n_in,
                              void* d_out, int out_size, void* d_ws, size_t ws_size,
                              hipStream_t stream)
{
  const float* feat_src    = (const float*)d_in[0];
  const float* feat_edge   = (const float*)d_in[1];
  const int*   src_idx     = (const int*)d_in[2];
  const int*   dst_idx     = (const int*)d_in[3];
  const float* W_src       = (const float*)d_in[4];
  const float* W_attn_src  = (const float*)d_in[5];
  const float* W_attn_dst  = (const float*)d_in[6];
  const float* W_attn_edge = (const float*)d_in[7];
  const float* scale       = (const float*)d_in[8];
  const float* offset      = (const float*)d_in[9];
  const float* W_agg       = (const float*)d_in[10];
  const float* b_agg       = (const float*)d_in[11];
  const float* W_dst       = (const float*)d_in[12];
  const float* b_dst       = (const float*)d_in[13];
  const float* W_apply     = (const float*)d_in[14];
  const float* b_apply     = (const float*)d_in[15];
  float* out = (float*)d_out;

  char* ws = (char*)d_ws;
  size_t off = 0;
  auto take = [&](size_t bytes) {
    size_t o = off;
    off = (off + bytes + 255) & ~(size_t)255;
    return o;
  };
  size_t fcs_off    = take((size_t)NN * HF * 2);      // bf16
  size_t fcd_off    = take((size_t)NN * HF * 2);      // bf16 (bias folded)
  size_t asrc_off   = take((size_t)NN * 4 * 4);
  size_t adst_off   = take((size_t)NN * 4 * 4);
  size_t bt_off     = take((size_t)NCOL * DD * 2);
  size_t wagg_off   = take((size_t)HF * HF * 2);
  size_t wapp_off   = take((size_t)OUTD * HF * 2);
  size_t cnt_off    = take((size_t)NN * 4);           // zeroed
  size_t offs_off   = take((size_t)(NN + 1) * 4);
  size_t bsum_off   = take((size_t)NB_SCAN * 4);
  size_t boff_off   = take((size_t)NB_SCAN * 4);
  size_t rank_off   = take((size_t)NE * 4);
  size_t ae_off     = take((size_t)NE * 8);           // fp16x4 per edge
  size_t sorted_off = take((size_t)NE * 16);
  size_t hout_off   = take((size_t)NN * HF * 2);      // bf16
  if (ws_size < off) return;

  unsigned short* fcs    = (unsigned short*)(ws + fcs_off);
  unsigned short* fcd    = (unsigned short*)(ws + fcd_off);
  float*          asrc   = (float*)(ws + asrc_off);
  float*          adst   = (float*)(ws + adst_off);
  unsigned short* Btt    = (unsigned short*)(ws + bt_off);
  unsigned short* Wagg_t = (unsigned short*)(ws + wagg_off);
  unsigned short* Wapp_t = (unsigned short*)(ws + wapp_off);
  int*            cnt    = (int*)(ws + cnt_off);
  int*            offs   = (int*)(ws + offs_off);
  int*            bsum   = (int*)(ws + bsum_off);
  int*            boff   = (int*)(ws + boff_off);
  int*            rank   = (int*)(ws + rank_off);
  uint2*          aebuf  = (uint2*)(ws + ae_off);
  int4*           sorted = (int4*)(ws + sorted_off);
  unsigned short* h_out  = (unsigned short*)(ws + hout_off);

  hipMemsetAsync(ws + cnt_off, 0, (size_t)NN * 4, stream);

  prep_kernel<<<NCOL + 160, 256, 0, stream>>>(
      W_src, W_dst, W_attn_src, W_attn_dst, W_agg, W_apply,
      Btt, Wagg_t, Wapp_t);

  fused_k1_kernel<<<NMFMA + NEDGEB, 512, 0, stream>>>(
      feat_src, Btt, b_dst, fcs, fcd, asrc, adst,
      feat_edge, W_attn_edge, dst_idx, cnt, rank, aebuf);

  scan_block_kernel<<<NB_SCAN, 256, 0, stream>>>(cnt, offs, bsum);
  scan_bsum_kernel<<<1, 256, 0, stream>>>(bsum, boff);
  scan_final_kernel<<<NB_SCAN, 256, 0, stream>>>(offs, boff);

  scatter_rec_kernel<<<(NE + 255) / 256, 256, 0, stream>>>(
      src_idx, dst_idx, asrc, adst, offs, rank, aebuf, sorted);

  agg_fused_kernel<<<NN, 64, 0, stream>>>(offs, sorted, fcs, h_out);

  node_final_mfma_kernel<<<(NN + NFB - 1) / NFB, 256, 0, stream>>>(
      h_out, scale, offset, Wagg_t, b_agg, fcd, Wapp_t, b_apply, out);
}

// Round 22
// 145.389 us; speedup vs baseline: 1.3801x; 1.0009x over previous
//
#include <hip/hip_runtime.h>
#include <hip/hip_fp16.h>

#define NN 50000
#define NE 800000
#define DD 256
#define DE_DIM 16
#define HH 4
#define FF 32
#define HF 128
#define OUTD 32
#define SLOPE 0.2f
#define NB_SCAN ((NN + 255) / 256)   // 196

// MFMA proj tiling
#define BM 64
#define NCOL 272
#define ATPAD 40          // A K-step tile row stride (bf16)
#define BTPAD 40
#define TILE_S8 1088
#define NMFMA 782                    // ceil(NN/BM)
#define NEDGEB 391                   // edge blocks (2048 edges each, 4x512)
// node_final MFMA tiling
#define NFB 64
#define FPAD 136

typedef short short8 __attribute__((ext_vector_type(8)));
typedef float f32x4 __attribute__((ext_vector_type(4)));
typedef unsigned short us4 __attribute__((ext_vector_type(4)));

// fp32 -> bf16 bits, round-to-nearest-even
__device__ __forceinline__ unsigned short bf16r(float x) {
  unsigned u = __float_as_uint(x);
  u += 0x7FFFu + ((u >> 16) & 1u);
  return (unsigned short)(u >> 16);
}
__device__ __forceinline__ float bfdec(unsigned short u) {
  return __uint_as_float(((unsigned)u) << 16);
}

// ---- Prep (merged): Btt panel + transposed W_agg/W_apply ----
__global__ __launch_bounds__(256) void prep_kernel(
    const float* __restrict__ Wsrc, const float* __restrict__ Wdst,
    const float* __restrict__ Wasrc, const float* __restrict__ Wadst,
    const float* __restrict__ W_agg, const float* __restrict__ W_apply,
    unsigned short* __restrict__ Btt,
    unsigned short* __restrict__ Wagg_t, unsigned short* __restrict__ Wapp_t)
{
  int bid = blockIdx.x;
  if (bid < NCOL) {
    int c = bid, k = threadIdx.x;
    float v = 0.f;
    if (c < 128)      v = Wsrc[(size_t)k * HF + c];
    else if (c < 256) v = Wdst[(size_t)k * HF + (c - 128)];
    else if (c < 260) v = Wasrc[(size_t)k * HH + (c - 256)];
    else if (c < 264) v = Wadst[(size_t)k * HH + (c - 260)];
    int kk = k >> 5, k5 = k & 31;
    Btt[(size_t)kk * (NCOL * 32) + c * 32 + k5] = bf16r(v);
  } else {
    int c = bid - NCOL, k = threadIdx.x;
    if (k >= 128) return;
    if (c < 128) Wagg_t[(size_t)c * HF + k] = bf16r(W_agg[(size_t)k * HF + c]);
    else         Wapp_t[(size_t)(c - 128) * HF + k] = bf16r(W_apply[(size_t)k * OUTD + (c - 128)]);
  }
}

// ---- Fused K1: blocks routed to {MFMA proj} or {edge prepass} ----
// LDS 53760B (A per-K-step dbuf 10.2KB + B dbuf 43.5KB) -> 3 blocks/CU.
__global__ __launch_bounds__(512) void fused_k1_kernel(
    const float* __restrict__ feat, const unsigned short* __restrict__ Btt,
    const float* __restrict__ bdst,
    unsigned short* __restrict__ fcs, unsigned short* __restrict__ fcd,
    float* __restrict__ asrc, float* __restrict__ adst,
    const float* __restrict__ feat_edge, const float* __restrict__ Wae,
    const int* __restrict__ dst_idx, int* __restrict__ cnt,
    int* __restrict__ rank, uint2* __restrict__ aebuf)
{
  __shared__ unsigned short Abuf2[2][BM * ATPAD];      // 2 x 5120 B
  __shared__ unsigned short Btbuf[2][NCOL * BTPAD];    // 2 x 21760 B
  const int bid = blockIdx.x;
  const int tid = threadIdx.x;
  const int m3 = bid % 3;

  if (m3 == 2) {
    // ---------------- edge prepass path (2048 edges per block) ----------------
    const int eb = bid / 3;
#pragma unroll
    for (int c4 = 0; c4 < 4; ++c4) {
      int e = eb * 2048 + c4 * 512 + tid;
      if (e >= NE) break;
      float ae[HH] = {0.f, 0.f, 0.f, 0.f};
      const float4* fe4 = (const float4*)(feat_edge + (size_t)e * DE_DIM);
#pragma unroll
      for (int q = 0; q < 4; ++q) {
        float4 x = fe4[q];
        const float xs[4] = {x.x, x.y, x.z, x.w};
#pragma unroll
        for (int kk = 0; kk < 4; ++kk) {
          int k = q * 4 + kk;
#pragma unroll
          for (int h = 0; h < HH; ++h) ae[h] += xs[kk] * Wae[k * HH + h];
        }
      }
      __half2 a01 = __floats2half2_rn(ae[0], ae[1]);
      __half2 a23 = __floats2half2_rn(ae[2], ae[3]);
      uint2 u; u.x = *(unsigned*)&a01; u.y = *(unsigned*)&a23;
      aebuf[e] = u;
      rank[e] = atomicAdd(&cnt[dst_idx[e]], 1);
    }
    return;
  }

  // ---------------- MFMA projection path ----------------
  const int wave = tid >> 6, lane = tid & 63;
  const int m0 = ((bid / 3) * 2 + m3) * BM;

  // A staging ownership: thread tid -> row tid>>3, float4 chunk tid&7
  const int sar = tid >> 3, sac = tid & 7;
  int sgr = m0 + sar; if (sgr >= NN) sgr = NN - 1;
  const float* arow_p = feat + (size_t)sgr * DD + sac * 4;

  // B staging chunk ownership
  const int ch0 = tid, ch1 = tid + 512, ch2 = tid + 1024;
  const short8* Bs8 = (const short8*)Btt;
  short8 st0, st1, st2;
  float4 stA;

  // prologue: tile 0 -> buf 0
  stA = *(const float4*)(arow_p);
  st0 = Bs8[ch0]; st1 = Bs8[ch1];
  if (ch2 < TILE_S8) st2 = Bs8[ch2];
  {
    us4 ab; ab.x = bf16r(stA.x); ab.y = bf16r(stA.y); ab.z = bf16r(stA.z); ab.w = bf16r(stA.w);
    *(us4*)&Abuf2[0][sar * ATPAD + sac * 4] = ab;
    int c, q;
    c = ch0 >> 2; q = ch0 & 3; *(short8*)&Btbuf[0][c * BTPAD + q * 8] = st0;
    c = ch1 >> 2; q = ch1 & 3; *(short8*)&Btbuf[0][c * BTPAD + q * 8] = st1;
    if (ch2 < TILE_S8) { c = ch2 >> 2; q = ch2 & 3; *(short8*)&Btbuf[0][c * BTPAD + q * 8] = st2; }
  }
  __syncthreads();

  const int r = wave >> 1, p = wave & 1;
  const int arow = r * 16 + (lane & 15);
  const int koff = (lane >> 4) * 8;
  const int cl = lane & 15;

  f32x4 acc[9];
#pragma unroll
  for (int t = 0; t < 9; ++t) acc[t] = (f32x4){0.f, 0.f, 0.f, 0.f};

  for (int kk = 0; kk < 8; ++kk) {
    const int cur = kk & 1;
    if (kk < 7) {                      // issue next tile's loads early
      stA = *(const float4*)(arow_p + (kk + 1) * 32);
      const short8* src = Bs8 + (size_t)(kk + 1) * TILE_S8;
      st0 = src[ch0]; st1 = src[ch1];
      if (ch2 < TILE_S8) st2 = src[ch2];
    }
    short8 a = *(const short8*)&Abuf2[cur][arow * ATPAD + koff];
#pragma unroll
    for (int t = 0; t < 9; ++t) {
      int c0 = p + 2 * t;
      if (c0 < 17) {
        short8 b = *(const short8*)&Btbuf[cur][(c0 * 16 + cl) * BTPAD + koff];
        acc[t] = __builtin_amdgcn_mfma_f32_16x16x32_bf16(a, b, acc[t], 0, 0, 0);
      }
    }
    if (kk < 7) {                      // write-late into the other buffer
      const int nb = cur ^ 1;
      us4 ab; ab.x = bf16r(stA.x); ab.y = bf16r(stA.y); ab.z = bf16r(stA.z); ab.w = bf16r(stA.w);
      *(us4*)&Abuf2[nb][sar * ATPAD + sac * 4] = ab;
      int c, q;
      c = ch0 >> 2; q = ch0 & 3; *(short8*)&Btbuf[nb][c * BTPAD + q * 8] = st0;
      c = ch1 >> 2; q = ch1 & 3; *(short8*)&Btbuf[nb][c * BTPAD + q * 8] = st1;
      if (ch2 < TILE_S8) { c = ch2 >> 2; q = ch2 & 3; *(short8*)&Btbuf[nb][c * BTPAD + q * 8] = st2; }
    }
    __syncthreads();
  }

  const int rbase = m0 + r * 16 + (lane >> 4) * 4;
#pragma unroll
  for (int t = 0; t < 9; ++t) {
    int c0 = p + 2 * t;
    if (c0 >= 17) break;
    int gcol = c0 * 16 + cl;
#pragma unroll
    for (int j = 0; j < 4; ++j) {
      int grow = rbase + j;
      if (grow >= NN) continue;
      float v = acc[t][j];
      if (gcol < 128)      fcs[(size_t)grow * HF + gcol] = bf16r(v);
      else if (gcol < 256) fcd[(size_t)grow * HF + (gcol - 128)] = bf16r(v + bdst[gcol - 128]);
      else if (gcol < 260) asrc[(size_t)grow * HH + (gcol - 256)] = v;
      else if (gcol < 264) adst[(size_t)grow * HH + (gcol - 260)] = v;
    }
  }
}

// ---- CSR scan ----
__global__ __launch_bounds__(256) void scan_block_kernel(
    const int* __restrict__ cnt, int* __restrict__ offs, int* __restrict__ bsum)
{
  __shared__ int tmp[256];
  int t = threadIdx.x;
  int i = blockIdx.x * 256 + t;
  int v = (i < NN) ? cnt[i] : 0;
  tmp[t] = v;
  __syncthreads();
  for (int ofs = 1; ofs < 256; ofs <<= 1) {
    int add = (t >= ofs) ? tmp[t - ofs] : 0;
    __syncthreads();
    tmp[t] += add;
    __syncthreads();
  }
  if (i < NN) offs[i] = tmp[t] - v;
  if (t == 255) bsum[blockIdx.x] = tmp[255];
}

__global__ __launch_bounds__(256) void scan_bsum_kernel(
    const int* __restrict__ bsum, int* __restrict__ boff)
{
  __shared__ int tmp[256];
  int t = threadIdx.x;
  int v = (t < NB_SCAN) ? bsum[t] : 0;
  tmp[t] = v;
  __syncthreads();
  for (int ofs = 1; ofs < 256; ofs <<= 1) {
    int add = (t >= ofs) ? tmp[t - ofs] : 0;
    __syncthreads();
    tmp[t] += add;
    __syncthreads();
  }
  if (t < NB_SCAN) boff[t] = tmp[t] - v;
}

__global__ __launch_bounds__(256) void scan_final_kernel(
    int* __restrict__ offs, const int* __restrict__ boff)
{
  int i = blockIdx.x * 256 + threadIdx.x;
  if (i < NN) offs[i] += boff[blockIdx.x];
  if (i == 0) offs[NN] = NE;
}

// ---- scatter record: streamed reads + L2-resident gathers; only the
// 16B record store is random ----
__global__ __launch_bounds__(256) void scatter_rec_kernel(
    const int* __restrict__ src_idx, const int* __restrict__ dst_idx,
    const float* __restrict__ asrc, const float* __restrict__ adst,
    const int* __restrict__ offs, const int* __restrict__ rank,
    const uint2* __restrict__ aebuf, int4* __restrict__ sorted)
{
  int e = blockIdx.x * 256 + threadIdx.x;
  if (e >= NE) return;
  int s = src_idx[e], d = dst_idx[e];

  uint2 u = aebuf[e];
  __half2 a01 = *(__half2*)&u.x;
  __half2 a23 = *(__half2*)&u.y;
  float ae[4];
  ae[0] = __low2float(a01); ae[1] = __high2float(a01);
  ae[2] = __low2float(a23); ae[3] = __high2float(a23);

  float as[4], ad[4];
  *(float4*)as = *(const float4*)(asrc + (size_t)s * 4);
  *(float4*)ad = *(const float4*)(adst + (size_t)d * 4);

  float ev[4];
#pragma unroll
  for (int h = 0; h < HH; ++h) {
    float v = as[h] + ad[h] + ae[h];
    ev[h] = v >= 0.f ? v : SLOPE * v;
  }
  __half2 p01 = __floats2half2_rn(ev[0], ev[1]);
  __half2 p23 = __floats2half2_rn(ev[2], ev[3]);
  int4 rec;
  rec.x = s;
  rec.y = *(int*)&p01;
  rec.z = *(int*)&p23;
  rec.w = 0;
  sorted[offs[d] + rank[e]] = rec;
}

// ---- fused softmax+agg: one wave per dst, no max pass (R12-verified) ----
__global__ __launch_bounds__(64) void agg_fused_kernel(
    const int* __restrict__ offs, const int4* __restrict__ sorted,
    const unsigned short* __restrict__ fcs, unsigned short* __restrict__ h_out)
{
  const int d = blockIdx.x;
  const int t = threadIdx.x;        // 0..63
  const int fpair = t << 1;
  const int h = t >> 4;
  const int beg = offs[d], end = offs[d + 1];
  const bool hiw = (h & 1);
  const bool hi2 = (h & 2);

  float ssum = 0.f, accx = 0.f, accy = 0.f;

  auto dec = [&](int4 r) -> float {
    int ew = hi2 ? r.z : r.y;
    __half2 hp = *(__half2*)&ew;
    return hiw ? __high2float(hp) : __low2float(hp);
  };

  int p = beg;
  for (; p + 4 <= end; p += 4) {
    int4 r0 = sorted[p + 0];
    int4 r1 = sorted[p + 1];
    int4 r2 = sorted[p + 2];
    int4 r3 = sorted[p + 3];
    unsigned f0 = *(const unsigned*)&fcs[(size_t)r0.x * HF + fpair];
    unsigned f1 = *(const unsigned*)&fcs[(size_t)r1.x * HF + fpair];
    unsigned f2 = *(const unsigned*)&fcs[(size_t)r2.x * HF + fpair];
    unsigned f3 = *(const unsigned*)&fcs[(size_t)r3.x * HF + fpair];
    float z0 = __expf(dec(r0));
    float z1 = __expf(dec(r1));
    float z2 = __expf(dec(r2));
    float z3 = __expf(dec(r3));
    ssum += (z0 + z1) + (z2 + z3);
    accx += bfdec((unsigned short)(f0 & 0xffff)) * z0
          + bfdec((unsigned short)(f1 & 0xffff)) * z1
          + bfdec((unsigned short)(f2 & 0xffff)) * z2
          + bfdec((unsigned short)(f3 & 0xffff)) * z3;
    accy += bfdec((unsigned short)(f0 >> 16)) * z0
          + bfdec((unsigned short)(f1 >> 16)) * z1
          + bfdec((unsigned short)(f2 >> 16)) * z2
          + bfdec((unsigned short)(f3 >> 16)) * z3;
  }
  for (; p < end; ++p) {
    int4 r0 = sorted[p];
    unsigned f0 = *(const unsigned*)&fcs[(size_t)r0.x * HF + fpair];
    float z = __expf(dec(r0));
    ssum += z;
    accx += bfdec((unsigned short)(f0 & 0xffff)) * z;
    accy += bfdec((unsigned short)(f0 >> 16)) * z;
  }
  float inv = (end > beg) ? 1.f / ssum : 0.f;
  ushort2 st;
  st.x = bf16r(accx * inv);
  st.y = bf16r(accy * inv);
  *(ushort2*)&h_out[(size_t)d * HF + fpair] = st;
}

// ---- Kernel 5: shuffle-free LN + MFMA(W_agg) + residual + MFMA(W_apply) ----
__global__ __launch_bounds__(256) void node_final_mfma_kernel(
    const unsigned short* __restrict__ h_in, const float* __restrict__ scale,
    const float* __restrict__ offset,
    const unsigned short* __restrict__ Wagg_t, const float* __restrict__ b_agg,
    const unsigned short* __restrict__ fcd,
    const unsigned short* __restrict__ Wapp_t, const float* __restrict__ b_apply,
    float* __restrict__ out)
{
  __shared__ unsigned short Abuf[NFB * FPAD];     // 17408 B (also holds A2)
  __shared__ unsigned short Bagg[HF * FPAD];      // 34816 B
  const int tid = threadIdx.x;
  const int wave = tid >> 6, lane = tid & 63;
  const int n0 = blockIdx.x * NFB;

  for (int i = tid; i < HF * 16; i += 256) {
    int c = i >> 4, q = i & 15;
    *(short8*)&Bagg[c * FPAD + q * 8] = *(const short8*)(Wagg_t + (size_t)c * HF + q * 8);
  }

  {
    const int r = tid >> 2, h = tid & 3;
    int node = n0 + r; if (node >= NN) node = NN - 1;
    const short8* hp = (const short8*)(h_in + (size_t)node * HF + h * 32);
    short8 v0 = hp[0], v1 = hp[1], v2 = hp[2], v3 = hp[3];

    float x[32];
#pragma unroll
    for (int j = 0; j < 8; ++j) {
      x[j]      = bfdec((unsigned short)v0[j]);
      x[8 + j]  = bfdec((unsigned short)v1[j]);
      x[16 + j] = bfdec((unsigned short)v2[j]);
      x[24 + j] = bfdec((unsigned short)v3[j]);
    }
    float sum = 0.f;
#pragma unroll
    for (int j = 0; j < 32; ++j) sum += x[j];
    float mean = sum * (1.f / 32.f);
    float sq = 0.f;
#pragma unroll
    for (int j = 0; j < 32; ++j) { float dv = x[j] - mean; sq += dv * dv; }
    float rsig = rsqrtf(sq * (1.f / 32.f) + 1e-9f);

#pragma unroll
    for (int c = 0; c < 4; ++c) {
      float4 s0 = *(const float4*)&scale[h * 32 + c * 8];
      float4 s1 = *(const float4*)&scale[h * 32 + c * 8 + 4];
      float4 o0 = *(const float4*)&offset[h * 32 + c * 8];
      float4 o1 = *(const float4*)&offset[h * 32 + c * 8 + 4];
      const float ss[8] = {s0.x, s0.y, s0.z, s0.w, s1.x, s1.y, s1.z, s1.w};
      const float oo[8] = {o0.x, o0.y, o0.z, o0.w, o1.x, o1.y, o1.z, o1.w};
      short8 w;
#pragma unroll
      for (int j = 0; j < 8; ++j)
        w[j] = (short)bf16r((x[c * 8 + j] - mean) * ss[j] * rsig + oo[j]);
      *(short8*)&Abuf[r * FPAD + h * 32 + c * 8] = w;
    }
  }
  __syncthreads();

  const int arow = wave * 16 + (lane & 15);
  const int koff = (lane >> 4) * 8;
  const int rbase = wave * 16 + (lane >> 4) * 4;
  const int cl = lane & 15;

  f32x4 acc1[8];
#pragma unroll
  for (int c0 = 0; c0 < 8; ++c0) acc1[c0] = (f32x4){0.f, 0.f, 0.f, 0.f};
#pragma unroll
  for (int ks = 0; ks < 4; ++ks) {
    short8 a = *(const short8*)&Abuf[arow * FPAD + ks * 32 + koff];
#pragma unroll
    for (int c0 = 0; c0 < 8; ++c0) {
      short8 b = *(const short8*)&Bagg[(c0 * 16 + cl) * FPAD + ks * 32 + koff];
      acc1[c0] = __builtin_amdgcn_mfma_f32_16x16x32_bf16(a, b, acc1[c0], 0, 0, 0);
    }
  }

#pragma unroll
  for (int c0 = 0; c0 < 8; ++c0) {
    int gcol = c0 * 16 + cl;
    float bg = b_agg[gcol];
#pragma unroll
    for (int j = 0; j < 4; ++j) {
      int row = rbase + j;
      int grow = n0 + row;
      float fd = (grow < NN) ? bfdec(fcd[(size_t)grow * HF + gcol]) : 0.f;
      float r = acc1[c0][j] + bg + fd;
      Abuf[row * FPAD + gcol] = bf16r(r >= 0.f ? r : SLOPE * r);
    }
  }
  // no barrier: Abuf rows are wave-private

  f32x4 acc2[2];
#pragma unroll
  for (int c0 = 0; c0 < 2; ++c0) acc2[c0] = (f32x4){0.f, 0.f, 0.f, 0.f};
#pragma unroll
  for (int ks = 0; ks < 4; ++ks) {
    short8 a = *(const short8*)&Abuf[arow * FPAD + ks * 32 + koff];
#pragma unroll
    for (int c0 = 0; c0 < 2; ++c0) {
      short8 b = *(const short8*)(Wapp_t + (size_t)(c0 * 16 + cl) * HF + ks * 32 + koff);
      acc2[c0] = __builtin_amdgcn_mfma_f32_16x16x32_bf16(a, b, acc2[c0], 0, 0, 0);
    }
  }
#pragma unroll
  for (int c0 = 0; c0 < 2; ++c0) {
    int gcol = c0 * 16 + cl;
    float ba = b_apply[gcol];
#pragma unroll
    for (int j = 0; j < 4; ++j) {
      int grow = n0 + rbase + j;
      if (grow < NN) out[(size_t)grow * OUTD + gcol] = acc2[c0][j] + ba;
    }
  }
}

extern "C" void kernel_launch(void* const* d_in, const int* in_sizes, int n_in,
                              void* d_out, int out_size, void* d_ws, size_t ws_size,
                              hipStream_t stream)
{
  const float* feat_src    = (const float*)d_in[0];
  const float* feat_edge   = (const float*)d_in[1];
  const int*   src_idx     = (const int*)d_in[2];
  const int*   dst_idx     = (const int*)d_in[3];
  const float* W_src       = (const float*)d_in[4];
  const float* W_attn_src  = (const float*)d_in[5];
  const float* W_attn_dst  = (const float*)d_in[6];
  const float* W_attn_edge = (const float*)d_in[7];
  const float* scale       = (const float*)d_in[8];
  const float* offset      = (const float*)d_in[9];
  const float* W_agg       = (const float*)d_in[10];
  const float* b_agg       = (const float*)d_in[11];
  const float* W_dst       = (const float*)d_in[12];
  const float* b_dst       = (const float*)d_in[13];
  const float* W_apply     = (const float*)d_in[14];
  const float* b_apply     = (const float*)d_in[15];
  float* out = (float*)d_out;

  char* ws = (char*)d_ws;
  size_t off = 0;
  auto take = [&](size_t bytes) {
    size_t o = off;
    off = (off + bytes + 255) & ~(size_t)255;
    return o;
  };
  size_t fcs_off    = take((size_t)NN * HF * 2);      // bf16
  size_t fcd_off    = take((size_t)NN * HF * 2);      // bf16 (bias folded)
  size_t asrc_off   = take((size_t)NN * 4 * 4);
  size_t adst_off   = take((size_t)NN * 4 * 4);
  size_t bt_off     = take((size_t)NCOL * DD * 2);
  size_t wagg_off   = take((size_t)HF * HF * 2);
  size_t wapp_off   = take((size_t)OUTD * HF * 2);
  size_t cnt_off    = take((size_t)NN * 4);           // zeroed
  size_t offs_off   = take((size_t)(NN + 1) * 4);
  size_t bsum_off   = take((size_t)NB_SCAN * 4);
  size_t boff_off   = take((size_t)NB_SCAN * 4);
  size_t rank_off   = take((size_t)NE * 4);
  size_t ae_off     = take((size_t)NE * 8);           // fp16x4 per edge
  size_t sorted_off = take((size_t)NE * 16);
  size_t hout_off   = take((size_t)NN * HF * 2);      // bf16
  if (ws_size < off) return;

  unsigned short* fcs    = (unsigned short*)(ws + fcs_off);
  unsigned short* fcd    = (unsigned short*)(ws + fcd_off);
  float*          asrc   = (float*)(ws + asrc_off);
  float*          adst   = (float*)(ws + adst_off);
  unsigned short* Btt    = (unsigned short*)(ws + bt_off);
  unsigned short* Wagg_t = (unsigned short*)(ws + wagg_off);
  unsigned short* Wapp_t = (unsigned short*)(ws + wapp_off);
  int*            cnt    = (int*)(ws + cnt_off);
  int*            offs   = (int*)(ws + offs_off);
  int*            bsum   = (int*)(ws + bsum_off);
  int*            boff   = (int*)(ws + boff_off);
  int*            rank   = (int*)(ws + rank_off);
  uint2*          aebuf  = (uint2*)(ws + ae_off);
  int4*           sorted = (int4*)(ws + sorted_off);
  unsigned short* h_out  = (unsigned short*)(ws + hout_off);

  hipMemsetAsync(ws + cnt_off, 0, (size_t)NN * 4, stream);

  prep_kernel<<<NCOL + 160, 256, 0, stream>>>(
      W_src, W_dst, W_attn_src, W_attn_dst, W_agg, W_apply,
      Btt, Wagg_t, Wapp_t);

  fused_k1_kernel<<<NMFMA + NEDGEB, 512, 0, stream>>>(
      feat_src, Btt, b_dst, fcs, fcd, asrc, adst,
      feat_edge, W_attn_edge, dst_idx, cnt, rank, aebuf);

  scan_block_kernel<<<NB_SCAN, 256, 0, stream>>>(cnt, offs, bsum);
  scan_bsum_kernel<<<1, 256, 0, stream>>>(bsum, boff);
  scan_final_kernel<<<NB_SCAN, 256, 0, stream>>>(offs, boff);

  scatter_rec_kernel<<<(NE + 255) / 256, 256, 0, stream>>>(
      src_idx, dst_idx, asrc, adst, offs, rank, aebuf, sorted);

  agg_fused_kernel<<<NN, 64, 0, stream>>>(offs, sorted, fcs, h_out);

  node_final_mfma_kernel<<<(NN + NFB - 1) / NFB, 256, 0, stream>>>(
      h_out, scale, offset, Wagg_t, b_agg, fcd, Wapp_t, b_apply, out);
}